// Round 12
// baseline (744.172 us; speedup 1.0000x reference)
//
#include <hip/hip_runtime.h>
#include <hip/hip_bf16.h>

#define N_NODES 50000
#define E_EDGES 300000
#define IN_F 512
#define H_F 256
#define OUT_F 256
#define K_CL 4096
#define KW (K_CL / 32)
#define PCH 128
#define THRESH 192
#define MAXH 1024
#define NSPL 32
#define NB2 ((N_NODES + 255) / 256)

typedef short bh8 __attribute__((ext_vector_type(8)));
typedef float f4 __attribute__((ext_vector_type(4)));
typedef unsigned short u16;

__device__ __forceinline__ unsigned fkey(float f) {
    unsigned u = __float_as_uint(f);
    return (u & 0x80000000u) ? ~u : (u | 0x80000000u);
}

__device__ __forceinline__ u16 f2bf(float f) {
    __hip_bfloat16 b = __float2bfloat16(f);
    return *reinterpret_cast<u16*>(&b);
}

// ---------------- init ----------------
__global__ __launch_bounds__(256) void init_nodes(int* cntD, int* degS,
                                                  unsigned long long* best_enc,
                                                  int* bgnode, int* heavycnt,
                                                  unsigned long long* bestpack) {
    int i = blockIdx.x * blockDim.x + threadIdx.x;
    if (i < N_NODES) { cntD[i] = 0; degS[i] = 0; best_enc[i] = 0ULL; }
    if (i == 0) { *heavycnt = 0; *bgnode = 0x7FFFFFFF; *bestpack = 0ULL; }
}

__global__ __launch_bounds__(256) void deg_edges(const int* __restrict__ src,
                                                 const int* __restrict__ dst,
                                                 int* cntD, int* degS) {
    int e = blockIdx.x * blockDim.x + threadIdx.x;
    if (e >= E_EDGES) return;
    atomicAdd(&cntD[dst[e]], 1);
    atomicAdd(&degS[src[e]], 1);
}

__global__ __launch_bounds__(256) void make_dinv(const int* __restrict__ cntD, float* dinv) {
    int i = blockIdx.x * blockDim.x + threadIdx.x;
    if (i < N_NODES) dinv[i] = rsqrtf((float)cntD[i] + 1.0f);
}

// ---- fp32 GEMM (score path): 64x128 tile, dbuf LDS, glds B, T14 A-staging ----
#define SBM 64
#define SBN 128
#define SBK 16
#define SAPAD 4
__global__ __launch_bounds__(256) void gemm_f32s(const float* __restrict__ A,
                                                 const float* __restrict__ B,
                                                 float* __restrict__ C,
                                                 int M, int Nc, int Kd) {
    __shared__ float As[2][SBK][SBM + SAPAD];
    __shared__ float Bs[2][SBK][SBN];
    int tid = threadIdx.x;
    int tx = tid & 15;
    int ty = tid >> 4;
    int lane = tid & 63;
    int wave = tid >> 6;
    int row0 = blockIdx.y * SBM, col0 = blockIdx.x * SBN;
    float acc[4][8] = {};

    int ar = tid >> 2;
    int akq = tid & 3;
    float4 ra;   // single in-flight A fragment (4 VGPRs held across compute)

    auto stage_B = [&](int k0, int bb) {
        #pragma unroll
        for (int u = 0; u < 2; ++u) {
            int chunk = wave * 2 + u;
            int krow = chunk * 2 + (lane >> 5);
            const float* gsrc = &B[(long)(k0 + krow) * Nc + col0 + (lane & 31) * 4];
            __builtin_amdgcn_global_load_lds(
                (const __attribute__((address_space(1))) void*)gsrc,
                (__attribute__((address_space(3))) void*)&Bs[bb][chunk * 2][0],
                16, 0, 0);
        }
    };
    auto stage_A_load = [&](int k0) {
        int gr = row0 + ar;
        float4 v = {0.f, 0.f, 0.f, 0.f};
        if (gr < M) v = *(const float4*)&A[(long)gr * Kd + k0 + akq * 4];
        ra = v;
    };
    auto stage_A_write = [&](int bb) {
        As[bb][akq * 4 + 0][ar] = ra.x;
        As[bb][akq * 4 + 1][ar] = ra.y;
        As[bb][akq * 4 + 2][ar] = ra.z;
        As[bb][akq * 4 + 3][ar] = ra.w;
    };
    auto compute = [&](int bb) {
        #pragma unroll
        for (int k = 0; k < SBK; ++k) {
            float4 a0 = *(const float4*)&As[bb][k][ty * 4];
            float4 b0 = *(const float4*)&Bs[bb][k][tx * 4];
            float4 b1 = *(const float4*)&Bs[bb][k][tx * 4 + 64];
            float av[4] = {a0.x, a0.y, a0.z, a0.w};
            float bv[8] = {b0.x, b0.y, b0.z, b0.w, b1.x, b1.y, b1.z, b1.w};
            #pragma unroll
            for (int i = 0; i < 4; ++i)
                #pragma unroll
                for (int j = 0; j < 8; ++j)
                    acc[i][j] += av[i] * bv[j];
        }
    };

    stage_B(0, 0);
    stage_A_load(0);
    stage_A_write(0);
    __syncthreads();
    int nt = Kd / SBK;
    for (int t = 0; t < nt; ++t) {
        int cb = t & 1;
        if (t + 1 < nt) {
            stage_B(SBK * (t + 1), cb ^ 1);   // async into LDS
            stage_A_load(SBK * (t + 1));      // issue loads; wait deferred (T14)
        }
        compute(cb);
        if (t + 1 < nt) stage_A_write(cb ^ 1);  // vmcnt wait lands post-compute
        __syncthreads();
    }

    #pragma unroll
    for (int i = 0; i < 4; ++i) {
        int gr = row0 + ty * 4 + i;
        if (gr >= M) continue;
        float4 o0 = {acc[i][0], acc[i][1], acc[i][2], acc[i][3]};
        float4 o1 = {acc[i][4], acc[i][5], acc[i][6], acc[i][7]};
        *(float4*)&C[(long)gr * Nc + col0 + tx * 4] = o0;
        *(float4*)&C[(long)gr * Nc + col0 + 64 + tx * 4] = o1;
    }
}

// ---- pack two 256x256 fp32 weights into MFMA-fragment-ordered bf16 (one launch) ----
__global__ __launch_bounds__(256) void pack_W2(const float* __restrict__ Wa, u16* Bpa,
                                               const float* __restrict__ Wb, u16* Bpb) {
    int k = blockIdx.x & 255;
    const float* W = (blockIdx.x < 256) ? Wa : Wb;
    u16* Bp = (blockIdx.x < 256) ? Bpa : Bpb;
    int col = threadIdx.x;
    int kb = k >> 5, g = (k >> 3) & 3, j = k & 7;
    Bp[(((long)(kb * 4 + g) * 256) + col) * 8 + j] = f2bf(W[(long)k * 256 + col]);
}

// ---- bf16 MFMA GEMM: C(Mx256) = A(Mx256) @ Bp(packed) ----
// A either pre-converted bf16 (Ab) or fp32 with per-row 1/cnt scale (Af32 + cnt).
__global__ __launch_bounds__(256) void gemm_mfma(const u16* __restrict__ Ab,
                                                 const float* __restrict__ Af32,
                                                 const int* __restrict__ cnt,
                                                 const u16* __restrict__ Bp,
                                                 float* __restrict__ C,
                                                 int M,
                                                 const int* __restrict__ cid,
                                                 const float* __restrict__ xp2,
                                                 const float* __restrict__ bskip) {
    int tid = threadIdx.x;
    int w = tid >> 6, l = tid & 63;
    int lo16 = l & 15, hi4 = l >> 4;
    int arow = blockIdx.x * 64 + w * 16 + lo16;
    f4 acc[16];
    #pragma unroll
    for (int n = 0; n < 16; ++n) acc[n] = (f4){0.f, 0.f, 0.f, 0.f};

    float s = 1.f;
    if (Af32 && arow < M) s = 1.f / fmaxf((float)cnt[arow], 1.f);

    #pragma unroll
    for (int kb = 0; kb < 8; ++kb) {
        bh8 a = {0, 0, 0, 0, 0, 0, 0, 0};
        if (arow < M) {
            if (Af32) {
                float4 v0 = *(const float4*)&Af32[(long)arow * 256 + kb * 32 + hi4 * 8];
                float4 v1 = *(const float4*)&Af32[(long)arow * 256 + kb * 32 + hi4 * 8 + 4];
                u16 tmp[8] = {f2bf(v0.x * s), f2bf(v0.y * s), f2bf(v0.z * s), f2bf(v0.w * s),
                              f2bf(v1.x * s), f2bf(v1.y * s), f2bf(v1.z * s), f2bf(v1.w * s)};
                a = *(const bh8*)tmp;
            } else {
                a = *(const bh8*)&Ab[(long)arow * 256 + kb * 32 + hi4 * 8];
            }
        }
        const u16* bbase = &Bp[(((long)(kb * 4 + hi4)) * 256 + lo16) * 8];
        #pragma unroll
        for (int n = 0; n < 16; ++n) {
            bh8 b = *(const bh8*)&bbase[(long)n * 128];
            acc[n] = __builtin_amdgcn_mfma_f32_16x16x32_bf16(a, b, acc[n], 0, 0, 0);
        }
    }

    int orow0 = blockIdx.x * 64 + w * 16 + hi4 * 4;
    #pragma unroll
    for (int r = 0; r < 4; ++r) {
        int gr = orow0 + r;
        if (gr >= M) continue;
        long rb = (long)gr * 256;
        const float* xrow = cid ? (xp2 + (long)cid[gr] * 256) : nullptr;
        #pragma unroll
        for (int n = 0; n < 16; ++n) {
            int gc = n * 16 + lo16;
            float v = acc[n][r];
            if (cid) v += xrow[gc] + bskip[gc];
            C[rb + gc] = v;
        }
    }
}

// --------- coalesced two-level exclusive scan (n <= 256*256) ---------
__global__ __launch_bounds__(256) void scan_l1(const int* __restrict__ cnt,
                                               int* bsum, int n) {
    __shared__ int s[256];
    int t = threadIdx.x;
    int i = blockIdx.x * 256 + t;
    s[t] = (i < n) ? cnt[i] : 0;
    __syncthreads();
    for (int off = 128; off > 0; off >>= 1) {
        if (t < off) s[t] += s[t + off];
        __syncthreads();
    }
    if (t == 0) bsum[blockIdx.x] = s[0];
}

__global__ __launch_bounds__(256) void scan_l2(const int* __restrict__ bsum,
                                               int* bstart, int nb) {
    __shared__ int s[256];
    int t = threadIdx.x;
    int v = (t < nb) ? bsum[t] : 0;
    s[t] = v;
    __syncthreads();
    for (int off = 1; off < 256; off <<= 1) {
        int a = (t >= off) ? s[t - off] : 0;
        __syncthreads();
        s[t] += a;
        __syncthreads();
    }
    if (t < nb) bstart[t] = s[t] - v;
}

__global__ __launch_bounds__(256) void scan_l3(const int* __restrict__ cnt,
                                               const int* __restrict__ bstart,
                                               int* start, int* cur, int n) {
    __shared__ int s[256];
    int t = threadIdx.x;
    int i = blockIdx.x * 256 + t;
    int v = (i < n) ? cnt[i] : 0;
    s[t] = v;
    __syncthreads();
    for (int off = 1; off < 256; off <<= 1) {
        int a = (t >= off) ? s[t - off] : 0;
        __syncthreads();
        s[t] += a;
        __syncthreads();
    }
    int st = bstart[blockIdx.x] + s[t] - v;
    if (i < n) { start[i] = st; cur[i] = st; }
    if (i == n - 1) start[n] = st + v;
}

__global__ __launch_bounds__(256) void csr_scatter(const int* __restrict__ src,
                                                   const int* __restrict__ dst,
                                                   int* cur, int* csr) {
    int e = blockIdx.x * blockDim.x + threadIdx.x;
    if (e >= E_EDGES) return;
    int d = dst[e];
    int p = atomicAdd(&cur[d], 1);
    csr[p] = src[e];
}

// ---------------- fused conv1 aggregation + relu + score + bf16 emit ----------------
__global__ __launch_bounds__(256) void agg_fused(const float* __restrict__ h,
                                                 const float* __restrict__ dinv,
                                                 const int* __restrict__ rowptr,
                                                 const int* __restrict__ csr,
                                                 const float* __restrict__ b1,
                                                 const float* __restrict__ w_score,
                                                 float* x1, u16* x1b, float* raw) {
    __shared__ int s_src[128];
    __shared__ float s_cf[128];
    __shared__ float red[256];
    int i = blockIdx.x, j = threadIdx.x;
    float di_ = dinv[i];
    float acc = di_ * di_ * h[(long)i * H_F + j];
    int p0 = rowptr[i], p1 = rowptr[i + 1];
    for (int base = p0; base < p1; base += 128) {
        int m = p1 - base; if (m > 128) m = 128;
        if (j < m) { int s = csr[base + j]; s_src[j] = s; s_cf[j] = dinv[s]; }
        __syncthreads();
        #pragma unroll 4
        for (int t = 0; t < m; ++t)
            acc += (s_cf[t] * di_) * h[(long)s_src[t] * H_F + j];
        __syncthreads();
    }
    float v = fmaxf(acc + b1[j], 0.f);
    x1[(long)i * H_F + j] = v;
    x1b[(long)i * H_F + j] = f2bf(v);
    red[j] = v * w_score[j];
    __syncthreads();
    for (int off = 128; off > 0; off >>= 1) {
        if (j < off) red[j] += red[j + off];
        __syncthreads();
    }
    if (j == 0) raw[i] = red[0];
}

// ---------------- top-K select (single block radix) ----------------
__global__ __launch_bounds__(1024) void topk_select(const float* __restrict__ raw,
                                                    unsigned* outT, int* outNeedEq) {
    __shared__ unsigned hist[256];
    __shared__ unsigned sh_prefix;
    __shared__ int sh_k;
    int tid = threadIdx.x;
    if (tid == 0) { sh_prefix = 0; sh_k = K_CL; }
    __syncthreads();
    for (int byte = 3; byte >= 0; --byte) {
        if (tid < 256) hist[tid] = 0;
        __syncthreads();
        unsigned prefix = sh_prefix;
        unsigned known_mask = (byte == 3) ? 0u : (0xFFFFFFFFu << ((byte + 1) * 8));
        for (int i = tid; i < N_NODES; i += 1024) {
            unsigned key = fkey(raw[i]);
            if ((key & known_mask) == prefix)
                atomicAdd(&hist[(key >> (byte * 8)) & 255], 1u);
        }
        __syncthreads();
        if (tid == 0) {
            int kk = sh_k;
            int cum = 0;
            int v = 255;
            for (; v > 0; --v) {
                int c = (int)hist[v];
                if (cum + c >= kk) break;
                cum += c;
            }
            sh_prefix = prefix | ((unsigned)v << (byte * 8));
            sh_k = kk - cum;
        }
        __syncthreads();
    }
    if (tid == 0) { *outT = sh_prefix; *outNeedEq = sh_k; }
}

// ---------------- multi-block compaction: count -> scan -> assign ----------------
__global__ __launch_bounds__(256) void topk_count(const float* __restrict__ raw,
                                                  const unsigned* pT,
                                                  int* bGt, int* bEq) {
    __shared__ int sg[256], se[256];
    unsigned T = *pT;
    int t = threadIdx.x;
    int i = blockIdx.x * 256 + t;
    int gt = 0, eq = 0;
    if (i < N_NODES) {
        unsigned k = fkey(raw[i]);
        gt = k > T; eq = (k == T);
    }
    sg[t] = gt; se[t] = eq;
    __syncthreads();
    for (int off = 128; off > 0; off >>= 1) {
        if (t < off) { sg[t] += sg[t + off]; se[t] += se[t + off]; }
        __syncthreads();
    }
    if (t == 0) { bGt[blockIdx.x] = sg[0]; bEq[blockIdx.x] = se[0]; }
}

__global__ __launch_bounds__(256) void scan_blocks(const int* __restrict__ bGt,
                                                   const int* __restrict__ bEq,
                                                   int* gtStart, int* eqStart) {
    __shared__ int sg[256], se[256];
    int t = threadIdx.x;
    int vg = (t < NB2) ? bGt[t] : 0;
    int ve = (t < NB2) ? bEq[t] : 0;
    sg[t] = vg; se[t] = ve;
    __syncthreads();
    for (int off = 1; off < 256; off <<= 1) {
        int a = (t >= off) ? sg[t - off] : 0;
        int b = (t >= off) ? se[t - off] : 0;
        __syncthreads();
        sg[t] += a; se[t] += b;
        __syncthreads();
    }
    if (t < NB2) { gtStart[t] = sg[t] - vg; eqStart[t] = se[t] - ve; }
    if (t == 255) gtStart[NB2] = sg[255];   // totalGt
}

__global__ __launch_bounds__(256) void topk_assign(const float* __restrict__ raw,
                                                   const unsigned* pT, const int* pNeedEq,
                                                   const int* __restrict__ degS,
                                                   const int* __restrict__ gtStart,
                                                   const int* __restrict__ eqStart,
                                                   int* keep, int* cid,
                                                   unsigned long long* bestpack) {
    __shared__ int sg[256], se[256];
    unsigned T = *pT;
    int needEq = *pNeedEq;
    int totalGt = gtStart[NB2];
    int b = blockIdx.x, t = threadIdx.x;
    int i = b * 256 + t;
    int gt = 0, eq = 0;
    unsigned k = 0;
    if (i < N_NODES) {
        k = fkey(raw[i]);
        gt = k > T; eq = (k == T);
    }
    sg[t] = gt; se[t] = eq;
    __syncthreads();
    for (int off = 1; off < 256; off <<= 1) {
        int a = (t >= off) ? sg[t - off] : 0;
        int c = (t >= off) ? se[t - off] : 0;
        __syncthreads();
        sg[t] += a; se[t] += c;
        __syncthreads();
    }
    int eg = sg[t] - gt, ee = se[t] - eq;
    int kp = 0;
    unsigned long long p = 0ULL;
    if (i < N_NODES) {
        int c = -1;
        if (gt) { kp = 1; c = gtStart[b] + eg; }
        else if (eq) {
            int r = eqStart[b] + ee;
            if (r < needEq) { kp = 1; c = totalGt + r; }
        }
        keep[i] = kp; cid[i] = c;
        if (kp) p = ((unsigned long long)(unsigned)degS[i] << 32) | k;
    }
    #pragma unroll
    for (int o = 32; o > 0; o >>= 1) {
        unsigned long long q = __shfl_xor((long long)p, o, 64);
        if (q > p) p = q;
    }
    if ((t & 63) == 0 && p) atomicMax(bestpack, p);
}

__global__ __launch_bounds__(256) void bg_node(const int* __restrict__ keep,
                                               const int* __restrict__ degS,
                                               const float* __restrict__ raw,
                                               const unsigned long long* bestpack, int* bgnode) {
    int i = blockIdx.x * blockDim.x + threadIdx.x;
    if (i < N_NODES && keep[i]) {
        unsigned long long p = ((unsigned long long)(unsigned)degS[i] << 32) | fkey(raw[i]);
        if (p == *bestpack) atomicMin(bgnode, i);
    }
}

// ---------------- neighbor attachment ----------------
__global__ __launch_bounds__(256) void neigh_edges(const int* __restrict__ src,
                                                   const int* __restrict__ dst,
                                                   const int* __restrict__ keep,
                                                   const int* __restrict__ degS,
                                                   unsigned long long* best_enc) {
    int e = blockIdx.x * blockDim.x + threadIdx.x;
    if (e >= 2 * E_EDGES) return;
    int s, t;
    if (e < E_EDGES) { s = src[e]; t = dst[e]; }
    else { s = dst[e - E_EDGES]; t = src[e - E_EDGES]; }
    if (!keep[s] && keep[t]) {
        unsigned long long enc =
            (unsigned long long)((long long)degS[t] * N_NODES + (N_NODES - 1 - t)) + 1ULL;
        atomicMax(&best_enc[s], enc);
    }
}

__global__ __launch_bounds__(256) void resolve_cid(const int* __restrict__ keep,
                                                   const unsigned long long* __restrict__ best_enc,
                                                   const int* __restrict__ bgnode, int* cid) {
    int i = blockIdx.x * blockDim.x + threadIdx.x;
    if (i >= N_NODES) return;
    if (keep[i]) return;
    unsigned long long v = best_enc[i];
    if (v > 0ULL) {
        long long enc = (long long)(v - 1ULL);
        int t = (N_NODES - 1) - (int)(enc % N_NODES);
        cid[i] = cid[t];
    } else {
        cid[i] = cid[*bgnode];
    }
}

// ---------------- LDS-aggregated counting sort by cluster ----------------
#define NPB 1024
__global__ __launch_bounds__(256) void ccount2(const int* __restrict__ cid, int* ccnt) {
    __shared__ int hist[K_CL];
    for (int t = threadIdx.x; t < K_CL; t += 256) hist[t] = 0;
    __syncthreads();
    int base = blockIdx.x * NPB;
    #pragma unroll
    for (int u = 0; u < NPB / 256; ++u) {
        int idx = base + u * 256 + threadIdx.x;
        if (idx < N_NODES) atomicAdd(&hist[cid[idx]], 1);
    }
    __syncthreads();
    for (int t = threadIdx.x; t < K_CL; t += 256) {
        int hh = hist[t];
        if (hh) atomicAdd(&ccnt[t], hh);
    }
}

__global__ __launch_bounds__(256) void cscatter2(const int* __restrict__ cid,
                                                 int* ccur, int* clist) {
    __shared__ int hist[K_CL];
    for (int t = threadIdx.x; t < K_CL; t += 256) hist[t] = 0;
    __syncthreads();
    int base = blockIdx.x * NPB;
    int myc[NPB / 256], myr[NPB / 256];
    #pragma unroll
    for (int u = 0; u < NPB / 256; ++u) {
        int idx = base + u * 256 + threadIdx.x;
        if (idx < N_NODES) { myc[u] = cid[idx]; myr[u] = atomicAdd(&hist[myc[u]], 1); }
        else myc[u] = -1;
    }
    __syncthreads();
    for (int t = threadIdx.x; t < K_CL; t += 256) {
        int hh = hist[t];
        if (hh) hist[t] = atomicAdd(&ccur[t], hh);
    }
    __syncthreads();
    #pragma unroll
    for (int u = 0; u < NPB / 256; ++u)
        if (myc[u] >= 0) clist[hist[myc[u]] + myr[u]] = base + u * 256 + threadIdx.x;
}

// ---------------- chunked segmented pooling ----------------
__global__ __launch_bounds__(256) void pool_chunk(const float* __restrict__ x1,
                                                  const float* __restrict__ raw,
                                                  const int* __restrict__ clist,
                                                  const int* __restrict__ cid,
                                                  float* xp) {
    __shared__ int s_node[PCH];
    __shared__ int s_c[PCH];
    __shared__ float s_g[PCH];
    int j = threadIdx.x;
    int base = blockIdx.x * PCH;
    int m = N_NODES - base; if (m > PCH) m = PCH;
    for (int t = j; t < m; t += 256) {
        int nd = clist[base + t];
        s_node[t] = nd;
        s_c[t] = cid[nd];
        s_g[t] = tanhf(raw[nd]);
    }
    __syncthreads();
    float acc = 0.f;
    int cprev = s_c[0];
    for (int t = 0; t < m; t += 4) {
        int mm = m - t; if (mm > 4) mm = 4;
        float v[4];
        #pragma unroll
        for (int u = 0; u < 4; ++u)
            if (u < mm) v[u] = x1[(long)s_node[t + u] * H_F + j];
        #pragma unroll
        for (int u = 0; u < 4; ++u) {
            if (u < mm) {
                int c = s_c[t + u];
                if (c != cprev) {
                    atomicAdd(&xp[(long)cprev * H_F + j], acc);
                    acc = 0.f;
                    cprev = c;
                }
                acc += s_g[t + u] * v[u];
            }
        }
    }
    atomicAdd(&xp[(long)cprev * H_F + j], acc);
}

// ---------------- bit-packed pooled adjacency ----------------
__global__ __launch_bounds__(256) void build_Abits(const int* __restrict__ src,
                                                   const int* __restrict__ dst,
                                                   const int* __restrict__ cid,
                                                   unsigned* Abits) {
    int e = blockIdx.x * blockDim.x + threadIdx.x;
    if (e >= E_EDGES) return;
    int cu = cid[src[e]], cv = cid[dst[e]];
    if (cu != cv) atomicOr(&Abits[(long)cv * KW + (cu >> 5)], 1u << (cu & 31));
}

// di, nnz, and heavy-row compaction
__global__ __launch_bounds__(256) void pop_di2(const unsigned* __restrict__ Abits, float* di,
                                               int* nnzA, int* heavy, int* heavycnt) {
    int i = blockIdx.x * blockDim.x + threadIdx.x;
    if (i >= K_CL) return;
    int c = 0;
    for (int w = 0; w < KW; ++w) c += __popc(Abits[(long)i * KW + w]);
    di[i] = rsqrtf((float)c + 1.0f);
    nnzA[i] = c;
    if (c > THRESH) {
        int p = atomicAdd(heavycnt, 1);
        if (p < MAXH) heavy[p] = i;
    }
}

// light rows (nnz<=THRESH)
__global__ __launch_bounds__(256) void spmm_light(const unsigned* __restrict__ Abits,
                                                  const float* __restrict__ xpW2,
                                                  const float* __restrict__ di,
                                                  const float* __restrict__ b2,
                                                  const int* __restrict__ nnzA,
                                                  float* xp2) {
    __shared__ unsigned s_row[KW];
    __shared__ float s_part[3][256];
    int cv = blockIdx.x;
    if (nnzA[cv] > THRESH) return;
    int tid = threadIdx.x;
    int w = tid >> 6, l = tid & 63;
    if (tid < KW) s_row[tid] = Abits[(long)cv * KW + tid];
    __syncthreads();
    float4 a0 = {0.f, 0.f, 0.f, 0.f}, a1 = {0.f, 0.f, 0.f, 0.f};
    const float4* Y4 = (const float4*)xpW2;
    for (int wi = w * 32; wi < w * 32 + 32; wi += 2) {
        unsigned w0 = s_row[wi], w1 = s_row[wi + 1];
        while (w0 | w1) {
            if (w0) {
                int b = __ffs(w0) - 1; w0 &= w0 - 1;
                int cu = wi * 32 + b;
                float d = di[cu];
                float4 y = Y4[(long)cu * 64 + l];
                a0.x += d * y.x; a0.y += d * y.y; a0.z += d * y.z; a0.w += d * y.w;
            }
            if (w1) {
                int b = __ffs(w1) - 1; w1 &= w1 - 1;
                int cu = (wi + 1) * 32 + b;
                float d = di[cu];
                float4 y = Y4[(long)cu * 64 + l];
                a1.x += d * y.x; a1.y += d * y.y; a1.z += d * y.z; a1.w += d * y.w;
            }
        }
    }
    float4 acc = {a0.x + a1.x, a0.y + a1.y, a0.z + a1.z, a0.w + a1.w};
    if (w > 0) *(float4*)&s_part[w - 1][l * 4] = acc;
    __syncthreads();
    if (w == 0) {
        #pragma unroll
        for (int ww = 0; ww < 3; ++ww) {
            float4 p = *(float4*)&s_part[ww][l * 4];
            acc.x += p.x; acc.y += p.y; acc.z += p.z; acc.w += p.w;
        }
        float dv = di[cv];
        float4 ys = Y4[(long)cv * 64 + l];
        float4 o;
        o.x = dv * (acc.x + dv * ys.x) + b2[l * 4 + 0];
        o.y = dv * (acc.y + dv * ys.y) + b2[l * 4 + 1];
        o.z = dv * (acc.z + dv * ys.z) + b2[l * 4 + 2];
        o.w = dv * (acc.w + dv * ys.w) + b2[l * 4 + 3];
        *(float4*)&xp2[(long)cv * H_F + l * 4] = o;
    }
}

// heavy rows: grid (MAXH, NSPL); block (hi, sp) handles 4 words (1 per wave)
__global__ __launch_bounds__(256) void spmm_heavy(const unsigned* __restrict__ Abits,
                                                  const float* __restrict__ xpW2,
                                                  const float* __restrict__ di,
                                                  const int* __restrict__ heavy,
                                                  const int* __restrict__ heavycnt,
                                                  float* Zacc) {
    __shared__ float s_part[3][256];
    int hi = blockIdx.x;
    int cnt = *heavycnt; if (cnt > MAXH) cnt = MAXH;
    if (hi >= cnt) return;
    int cv = heavy[hi];
    int sp = blockIdx.y;
    int tid = threadIdx.x;
    int w = tid >> 6, l = tid & 63;
    int wi = sp * (KW / NSPL) + w;
    unsigned word = Abits[(long)cv * KW + wi];
    float4 acc = {0.f, 0.f, 0.f, 0.f};
    const float4* Y4 = (const float4*)xpW2;
    while (word) {
        int b = __ffs(word) - 1; word &= word - 1;
        int cu = wi * 32 + b;
        float d = di[cu];
        float4 y = Y4[(long)cu * 64 + l];
        acc.x += d * y.x; acc.y += d * y.y; acc.z += d * y.z; acc.w += d * y.w;
    }
    if (w > 0) *(float4*)&s_part[w - 1][l * 4] = acc;
    __syncthreads();
    if (w == 0) {
        #pragma unroll
        for (int ww = 0; ww < 3; ++ww) {
            float4 p = *(float4*)&s_part[ww][l * 4];
            acc.x += p.x; acc.y += p.y; acc.z += p.z; acc.w += p.w;
        }
        float* zp = &Zacc[(long)cv * H_F + l * 4];
        atomicAdd(zp + 0, acc.x);
        atomicAdd(zp + 1, acc.y);
        atomicAdd(zp + 2, acc.z);
        atomicAdd(zp + 3, acc.w);
    }
}

__global__ __launch_bounds__(256) void heavy_epi(const float* __restrict__ Zacc,
                                                 const float* __restrict__ xpW2,
                                                 const float* __restrict__ di,
                                                 const float* __restrict__ b2,
                                                 const int* __restrict__ heavy,
                                                 const int* __restrict__ heavycnt,
                                                 float* xp2) {
    int hi = blockIdx.x;
    int cnt = *heavycnt; if (cnt > MAXH) cnt = MAXH;
    if (hi >= cnt) return;
    int cv = heavy[hi];
    int j = threadIdx.x;
    float dv = di[cv];
    xp2[(long)cv * H_F + j] =
        dv * (Zacc[(long)cv * H_F + j] + dv * xpW2[(long)cv * H_F + j]) + b2[j];
}

// ---------------- host launch ----------------
static inline size_t align256(size_t x) { return (x + 255) & ~(size_t)255; }

extern "C" void kernel_launch(void* const* d_in, const int* in_sizes, int n_in,
                              void* d_out, int out_size, void* d_ws, size_t ws_size,
                              hipStream_t stream) {
    const float* x      = (const float*)d_in[0];
    const int*   eidx   = (const int*)d_in[1];
    const float* W1     = (const float*)d_in[2];
    const float* b1     = (const float*)d_in[3];
    const float* W2     = (const float*)d_in[4];
    const float* b2     = (const float*)d_in[5];
    const float* wscore = (const float*)d_in[6];
    const float* Wskip  = (const float*)d_in[7];
    const float* bskip  = (const float*)d_in[8];
    float* out = (float*)d_out;

    const int* src = eidx;
    const int* dst = eidx + E_EDGES;

    char* ws = (char*)d_ws;
    size_t off = 0;
    auto alloc = [&](size_t bytes) { char* p = ws + off; off += align256(bytes); return p; };

    float* h     = (float*)alloc((size_t)N_NODES * H_F * 4);
    float* x1    = (float*)alloc((size_t)N_NODES * H_F * 4);
    u16*   x1b   = (u16*)alloc((size_t)N_NODES * H_F * 2);
    float* raw   = (float*)alloc((size_t)N_NODES * 4);
    float* dinv  = (float*)alloc((size_t)N_NODES * 4);
    int*   cntD  = (int*)alloc((size_t)N_NODES * 4);
    int*   degS  = (int*)alloc((size_t)N_NODES * 4);
    int*   keep  = (int*)alloc((size_t)N_NODES * 4);
    int*   cid   = (int*)alloc((size_t)N_NODES * 4);
    unsigned long long* best_enc = (unsigned long long*)alloc((size_t)N_NODES * 8);
    int*   rowptr= (int*)alloc((size_t)(N_NODES + 1) * 4);
    int*   cur   = (int*)alloc((size_t)N_NODES * 4);
    int*   csr   = (int*)alloc((size_t)E_EDGES * 4);
    int*   ccnt  = (int*)alloc((size_t)K_CL * 4);
    int*   cstart= (int*)alloc((size_t)(K_CL + 1) * 4);
    int*   ccur  = (int*)alloc((size_t)K_CL * 4);
    int*   clist = (int*)alloc((size_t)N_NODES * 4);
    int*   bGt   = (int*)alloc((size_t)NB2 * 4);
    int*   bEq   = (int*)alloc((size_t)NB2 * 4);
    int*   gtStart = (int*)alloc((size_t)(NB2 + 1) * 4);
    int*   eqStart = (int*)alloc((size_t)NB2 * 4);
    int*   bsum  = (int*)alloc((size_t)256 * 4);
    int*   bstart= (int*)alloc((size_t)256 * 4);
    char*  small = alloc(64);
    unsigned* selT = (unsigned*)(small + 0);
    int* needEq    = (int*)(small + 4);
    int* bgnode    = (int*)(small + 8);
    int* heavycnt  = (int*)(small + 12);
    unsigned long long* bestpack = (unsigned long long*)(small + 16);
    float* xp    = (float*)alloc((size_t)K_CL * H_F * 4);
    unsigned* Abits = (unsigned*)alloc((size_t)K_CL * KW * 4);
    float* di    = (float*)alloc((size_t)K_CL * 4);
    int*   nnzA  = (int*)alloc((size_t)K_CL * 4);
    int*   heavy = (int*)alloc((size_t)MAXH * 4);
    float* Zacc  = (float*)alloc((size_t)K_CL * H_F * 4);
    float* xpW2  = (float*)alloc((size_t)K_CL * H_F * 4);
    float* xp2   = (float*)alloc((size_t)K_CL * H_F * 4);
    u16*  BpS   = (u16*)alloc((size_t)H_F * OUT_F * 2);
    u16*  Bp2   = (u16*)alloc((size_t)H_F * H_F * 2);
    (void)ws_size; (void)n_in; (void)in_sizes; (void)out_size;

    int nb = NB2;
    int eb = (E_EDGES + 255) / 256;

    // degrees
    init_nodes<<<nb, 256, 0, stream>>>(cntD, degS, best_enc, bgnode, heavycnt, bestpack);
    deg_edges<<<eb, 256, 0, stream>>>(src, dst, cntD, degS);
    make_dinv<<<nb, 256, 0, stream>>>(cntD, dinv);

    // weight packing (both in one launch)
    pack_W2<<<512, 256, 0, stream>>>(Wskip, BpS, W2, Bp2);

    // h = x @ W1 (fp32 — score path must stay exact)
    {
        dim3 grid(H_F / SBN, (N_NODES + SBM - 1) / SBM);
        gemm_f32s<<<grid, 256, 0, stream>>>(x, W1, h, N_NODES, H_F, IN_F);
    }

    // CSR by dst: coalesced two-level scan + scatter, then fused aggregation
    scan_l1<<<NB2, 256, 0, stream>>>(cntD, bsum, N_NODES);
    scan_l2<<<1, 256, 0, stream>>>(bsum, bstart, NB2);
    scan_l3<<<NB2, 256, 0, stream>>>(cntD, bstart, rowptr, cur, N_NODES);
    csr_scatter<<<eb, 256, 0, stream>>>(src, dst, cur, csr);
    agg_fused<<<N_NODES, 256, 0, stream>>>(h, dinv, rowptr, csr, b1, wscore, x1, x1b, raw);

    // top-K: threshold -> multi-block coalesced count/scan/assign
    topk_select<<<1, 1024, 0, stream>>>(raw, selT, needEq);
    topk_count<<<NB2, 256, 0, stream>>>(raw, selT, bGt, bEq);
    scan_blocks<<<1, 256, 0, stream>>>(bGt, bEq, gtStart, eqStart);
    topk_assign<<<NB2, 256, 0, stream>>>(raw, selT, needEq, degS, gtStart, eqStart,
                                         keep, cid, bestpack);
    bg_node<<<nb, 256, 0, stream>>>(keep, degS, raw, bestpack, bgnode);

    // neighbor attachment
    neigh_edges<<<(2 * E_EDGES + 255) / 256, 256, 0, stream>>>(src, dst, keep, degS, best_enc);
    resolve_cid<<<nb, 256, 0, stream>>>(keep, best_enc, bgnode, cid);

    // LDS-aggregated counting sort by cluster, then chunked segmented pooling
    hipMemsetAsync(ccnt, 0, (size_t)K_CL * 4, stream);
    {
        int cb = (N_NODES + NPB - 1) / NPB;
        ccount2<<<cb, 256, 0, stream>>>(cid, ccnt);
        scan_l1<<<K_CL / 256, 256, 0, stream>>>(ccnt, bsum, K_CL);
        scan_l2<<<1, 256, 0, stream>>>(bsum, bstart, K_CL / 256);
        scan_l3<<<K_CL / 256, 256, 0, stream>>>(ccnt, bstart, cstart, ccur, K_CL);
        cscatter2<<<cb, 256, 0, stream>>>(cid, ccur, clist);
    }
    hipMemsetAsync(xp, 0, (size_t)K_CL * H_F * 4, stream);
    pool_chunk<<<(N_NODES + PCH - 1) / PCH, 256, 0, stream>>>(x1, raw, clist, cid, xp);

    // xpW2 = (xp/cnt) @ W2  (bf16 MFMA, in-kernel fp32->bf16 conversion)
    gemm_mfma<<<K_CL / 64, 256, 0, stream>>>(nullptr, xp, ccnt, Bp2, xpW2, K_CL,
                                             nullptr, nullptr, nullptr);

    // bit-packed pooled adjacency + split light/heavy normalized SpMM
    hipMemsetAsync(Abits, 0, (size_t)K_CL * KW * 4, stream);
    hipMemsetAsync(Zacc, 0, (size_t)K_CL * H_F * 4, stream);
    build_Abits<<<eb, 256, 0, stream>>>(src, dst, cid, Abits);
    pop_di2<<<(K_CL + 255) / 256, 256, 0, stream>>>(Abits, di, nnzA, heavy, heavycnt);
    spmm_light<<<K_CL, 256, 0, stream>>>(Abits, xpW2, di, b2, nnzA, xp2);
    {
        dim3 hgrid(MAXH, NSPL);
        spmm_heavy<<<hgrid, 256, 0, stream>>>(Abits, xpW2, di, heavy, heavycnt, Zacc);
    }
    heavy_epi<<<MAXH, 256, 0, stream>>>(Zacc, xpW2, di, b2, heavy, heavycnt, xp2);

    // out = x1@Wskip + xp2[cid] + b_skip  (bf16 MFMA, fused epilogue)
    gemm_mfma<<<(N_NODES + 63) / 64, 256, 0, stream>>>(x1b, nullptr, nullptr, BpS, out,
                                                       N_NODES, cid, xp2, bskip);
}

// Round 13
// 727.775 us; speedup vs baseline: 1.0225x; 1.0225x over previous
//
#include <hip/hip_runtime.h>
#include <hip/hip_bf16.h>

#define N_NODES 50000
#define E_EDGES 300000
#define IN_F 512
#define H_F 256
#define OUT_F 256
#define K_CL 4096
#define KW (K_CL / 32)
#define PCH 128
#define THRESH 192
#define MAXH 1024
#define NSPL 32
#define NB2 ((N_NODES + 255) / 256)

typedef short bh8 __attribute__((ext_vector_type(8)));
typedef float f4 __attribute__((ext_vector_type(4)));
typedef unsigned short u16;

__device__ __forceinline__ unsigned fkey(float f) {
    unsigned u = __float_as_uint(f);
    return (u & 0x80000000u) ? ~u : (u | 0x80000000u);
}

__device__ __forceinline__ u16 f2bf(float f) {
    __hip_bfloat16 b = __float2bfloat16(f);
    return *reinterpret_cast<u16*>(&b);
}

// ---------------- init ----------------
__global__ __launch_bounds__(256) void init_nodes(int* cntD, int* degS,
                                                  unsigned long long* best_enc,
                                                  int* bgnode, int* heavycnt,
                                                  unsigned long long* bestpack) {
    int i = blockIdx.x * blockDim.x + threadIdx.x;
    if (i < N_NODES) { cntD[i] = 0; degS[i] = 0; best_enc[i] = 0ULL; }
    if (i == 0) { *heavycnt = 0; *bgnode = 0x7FFFFFFF; *bestpack = 0ULL; }
}

__global__ __launch_bounds__(256) void deg_edges(const int* __restrict__ src,
                                                 const int* __restrict__ dst,
                                                 int* cntD, int* degS) {
    int e = blockIdx.x * blockDim.x + threadIdx.x;
    if (e >= E_EDGES) return;
    atomicAdd(&cntD[dst[e]], 1);
    atomicAdd(&degS[src[e]], 1);
}

// ---- fp32 GEMM (score path): 64x128 tile, dbuf LDS, glds B, immediate A staging ----
// NOTE: T14 reg-staged A tried 3x (r4/r6/r12) — always VGPR blowup + occupancy loss.
#define SBM 64
#define SBN 128
#define SBK 16
#define SAPAD 4
__global__ __launch_bounds__(256) void gemm_f32s(const float* __restrict__ A,
                                                 const float* __restrict__ B,
                                                 float* __restrict__ C,
                                                 int M, int Nc, int Kd) {
    __shared__ float As[2][SBK][SBM + SAPAD];
    __shared__ float Bs[2][SBK][SBN];
    int tid = threadIdx.x;
    int tx = tid & 15;
    int ty = tid >> 4;
    int lane = tid & 63;
    int wave = tid >> 6;
    int row0 = blockIdx.y * SBM, col0 = blockIdx.x * SBN;
    float acc[4][8] = {};

    int ar = tid >> 2;
    int akq = tid & 3;

    auto stage_B = [&](int k0, int bb) {
        #pragma unroll
        for (int u = 0; u < 2; ++u) {
            int chunk = wave * 2 + u;
            int krow = chunk * 2 + (lane >> 5);
            const float* gsrc = &B[(long)(k0 + krow) * Nc + col0 + (lane & 31) * 4];
            __builtin_amdgcn_global_load_lds(
                (const __attribute__((address_space(1))) void*)gsrc,
                (__attribute__((address_space(3))) void*)&Bs[bb][chunk * 2][0],
                16, 0, 0);
        }
    };
    auto stage_A = [&](int k0, int bb) {
        int gr = row0 + ar;
        float4 v = {0.f, 0.f, 0.f, 0.f};
        if (gr < M) v = *(const float4*)&A[(long)gr * Kd + k0 + akq * 4];
        As[bb][akq * 4 + 0][ar] = v.x;
        As[bb][akq * 4 + 1][ar] = v.y;
        As[bb][akq * 4 + 2][ar] = v.z;
        As[bb][akq * 4 + 3][ar] = v.w;
    };
    auto compute = [&](int bb) {
        #pragma unroll
        for (int k = 0; k < SBK; ++k) {
            float4 a0 = *(const float4*)&As[bb][k][ty * 4];
            float4 b0 = *(const float4*)&Bs[bb][k][tx * 4];
            float4 b1 = *(const float4*)&Bs[bb][k][tx * 4 + 64];
            float av[4] = {a0.x, a0.y, a0.z, a0.w};
            float bv[8] = {b0.x, b0.y, b0.z, b0.w, b1.x, b1.y, b1.z, b1.w};
            #pragma unroll
            for (int i = 0; i < 4; ++i)
                #pragma unroll
                for (int j = 0; j < 8; ++j)
                    acc[i][j] += av[i] * bv[j];
        }
    };

    stage_B(0, 0);
    stage_A(0, 0);
    __syncthreads();
    int nt = Kd / SBK;
    for (int t = 0; t < nt; ++t) {
        int cb = t & 1;
        if (t + 1 < nt) {
            stage_B(SBK * (t + 1), cb ^ 1);
            stage_A(SBK * (t + 1), cb ^ 1);
        }
        compute(cb);
        __syncthreads();
    }

    #pragma unroll
    for (int i = 0; i < 4; ++i) {
        int gr = row0 + ty * 4 + i;
        if (gr >= M) continue;
        float4 o0 = {acc[i][0], acc[i][1], acc[i][2], acc[i][3]};
        float4 o1 = {acc[i][4], acc[i][5], acc[i][6], acc[i][7]};
        *(float4*)&C[(long)gr * Nc + col0 + tx * 4] = o0;
        *(float4*)&C[(long)gr * Nc + col0 + 64 + tx * 4] = o1;
    }
}

// ---- pack two 256x256 fp32 weights into MFMA-fragment-ordered bf16 (one launch) ----
__global__ __launch_bounds__(256) void pack_W2(const float* __restrict__ Wa, u16* Bpa,
                                               const float* __restrict__ Wb, u16* Bpb) {
    int k = blockIdx.x & 255;
    const float* W = (blockIdx.x < 256) ? Wa : Wb;
    u16* Bp = (blockIdx.x < 256) ? Bpa : Bpb;
    int col = threadIdx.x;
    int kb = k >> 5, g = (k >> 3) & 3, j = k & 7;
    Bp[(((long)(kb * 4 + g) * 256) + col) * 8 + j] = f2bf(W[(long)k * 256 + col]);
}

// ---- bf16 MFMA GEMM: C(Mx256) = A(Mx256) @ Bp(packed) ----
__global__ __launch_bounds__(256) void gemm_mfma(const u16* __restrict__ Ab,
                                                 const float* __restrict__ Af32,
                                                 const int* __restrict__ cnt,
                                                 const u16* __restrict__ Bp,
                                                 float* __restrict__ C,
                                                 int M,
                                                 const int* __restrict__ cid,
                                                 const float* __restrict__ xp2,
                                                 const float* __restrict__ bskip) {
    int tid = threadIdx.x;
    int w = tid >> 6, l = tid & 63;
    int lo16 = l & 15, hi4 = l >> 4;
    int arow = blockIdx.x * 64 + w * 16 + lo16;
    f4 acc[16];
    #pragma unroll
    for (int n = 0; n < 16; ++n) acc[n] = (f4){0.f, 0.f, 0.f, 0.f};

    float s = 1.f;
    if (Af32 && arow < M) s = 1.f / fmaxf((float)cnt[arow], 1.f);

    #pragma unroll
    for (int kb = 0; kb < 8; ++kb) {
        bh8 a = {0, 0, 0, 0, 0, 0, 0, 0};
        if (arow < M) {
            if (Af32) {
                float4 v0 = *(const float4*)&Af32[(long)arow * 256 + kb * 32 + hi4 * 8];
                float4 v1 = *(const float4*)&Af32[(long)arow * 256 + kb * 32 + hi4 * 8 + 4];
                u16 tmp[8] = {f2bf(v0.x * s), f2bf(v0.y * s), f2bf(v0.z * s), f2bf(v0.w * s),
                              f2bf(v1.x * s), f2bf(v1.y * s), f2bf(v1.z * s), f2bf(v1.w * s)};
                a = *(const bh8*)tmp;
            } else {
                a = *(const bh8*)&Ab[(long)arow * 256 + kb * 32 + hi4 * 8];
            }
        }
        const u16* bbase = &Bp[(((long)(kb * 4 + hi4)) * 256 + lo16) * 8];
        #pragma unroll
        for (int n = 0; n < 16; ++n) {
            bh8 b = *(const bh8*)&bbase[(long)n * 128];
            acc[n] = __builtin_amdgcn_mfma_f32_16x16x32_bf16(a, b, acc[n], 0, 0, 0);
        }
    }

    int orow0 = blockIdx.x * 64 + w * 16 + hi4 * 4;
    #pragma unroll
    for (int r = 0; r < 4; ++r) {
        int gr = orow0 + r;
        if (gr >= M) continue;
        long rb = (long)gr * 256;
        const float* xrow = cid ? (xp2 + (long)cid[gr] * 256) : nullptr;
        #pragma unroll
        for (int n = 0; n < 16; ++n) {
            int gc = n * 16 + lo16;
            float v = acc[n][r];
            if (cid) v += xrow[gc] + bskip[gc];
            C[rb + gc] = v;
        }
    }
}

// --------- coalesced two-level exclusive scan (n <= 256*256) ---------
// scan_l1 optionally also emits dinv = rsqrt(cnt+1) (fuses make_dinv).
__global__ __launch_bounds__(256) void scan_l1(const int* __restrict__ cnt,
                                               int* bsum, int n, float* dinv) {
    __shared__ int s[256];
    int t = threadIdx.x;
    int i = blockIdx.x * 256 + t;
    int v = (i < n) ? cnt[i] : 0;
    if (dinv && i < n) dinv[i] = rsqrtf((float)v + 1.0f);
    s[t] = v;
    __syncthreads();
    for (int off = 128; off > 0; off >>= 1) {
        if (t < off) s[t] += s[t + off];
        __syncthreads();
    }
    if (t == 0) bsum[blockIdx.x] = s[0];
}

__global__ __launch_bounds__(256) void scan_l2(const int* __restrict__ bsum,
                                               int* bstart, int nb) {
    __shared__ int s[256];
    int t = threadIdx.x;
    int v = (t < nb) ? bsum[t] : 0;
    s[t] = v;
    __syncthreads();
    for (int off = 1; off < 256; off <<= 1) {
        int a = (t >= off) ? s[t - off] : 0;
        __syncthreads();
        s[t] += a;
        __syncthreads();
    }
    if (t < nb) bstart[t] = s[t] - v;
}

__global__ __launch_bounds__(256) void scan_l3(const int* __restrict__ cnt,
                                               const int* __restrict__ bstart,
                                               int* start, int* cur, int n) {
    __shared__ int s[256];
    int t = threadIdx.x;
    int i = blockIdx.x * 256 + t;
    int v = (i < n) ? cnt[i] : 0;
    s[t] = v;
    __syncthreads();
    for (int off = 1; off < 256; off <<= 1) {
        int a = (t >= off) ? s[t - off] : 0;
        __syncthreads();
        s[t] += a;
        __syncthreads();
    }
    int st = bstart[blockIdx.x] + s[t] - v;
    if (i < n) { start[i] = st; cur[i] = st; }
    if (i == n - 1) start[n] = st + v;
}

__global__ __launch_bounds__(256) void csr_scatter(const int* __restrict__ src,
                                                   const int* __restrict__ dst,
                                                   int* cur, int* csr) {
    int e = blockIdx.x * blockDim.x + threadIdx.x;
    if (e >= E_EDGES) return;
    int d = dst[e];
    int p = atomicAdd(&cur[d], 1);
    csr[p] = src[e];
}

// ---------------- fused conv1 aggregation + relu + score + bf16 emit ----------------
__global__ __launch_bounds__(256) void agg_fused(const float* __restrict__ h,
                                                 const float* __restrict__ dinv,
                                                 const int* __restrict__ rowptr,
                                                 const int* __restrict__ csr,
                                                 const float* __restrict__ b1,
                                                 const float* __restrict__ w_score,
                                                 float* x1, u16* x1b, float* raw) {
    __shared__ int s_src[128];
    __shared__ float s_cf[128];
    __shared__ float red[256];
    int i = blockIdx.x, j = threadIdx.x;
    float di_ = dinv[i];
    float acc = di_ * di_ * h[(long)i * H_F + j];
    int p0 = rowptr[i], p1 = rowptr[i + 1];
    for (int base = p0; base < p1; base += 128) {
        int m = p1 - base; if (m > 128) m = 128;
        if (j < m) { int s = csr[base + j]; s_src[j] = s; s_cf[j] = dinv[s]; }
        __syncthreads();
        #pragma unroll 4
        for (int t = 0; t < m; ++t)
            acc += (s_cf[t] * di_) * h[(long)s_src[t] * H_F + j];
        __syncthreads();
    }
    float v = fmaxf(acc + b1[j], 0.f);
    x1[(long)i * H_F + j] = v;
    x1b[(long)i * H_F + j] = f2bf(v);
    red[j] = v * w_score[j];
    __syncthreads();
    for (int off = 128; off > 0; off >>= 1) {
        if (j < off) red[j] += red[j + off];
        __syncthreads();
    }
    if (j == 0) raw[i] = red[0];
}

// ---------------- top-K select (single block radix) ----------------
__global__ __launch_bounds__(1024) void topk_select(const float* __restrict__ raw,
                                                    unsigned* outT, int* outNeedEq) {
    __shared__ unsigned hist[256];
    __shared__ unsigned sh_prefix;
    __shared__ int sh_k;
    int tid = threadIdx.x;
    if (tid == 0) { sh_prefix = 0; sh_k = K_CL; }
    __syncthreads();
    for (int byte = 3; byte >= 0; --byte) {
        if (tid < 256) hist[tid] = 0;
        __syncthreads();
        unsigned prefix = sh_prefix;
        unsigned known_mask = (byte == 3) ? 0u : (0xFFFFFFFFu << ((byte + 1) * 8));
        for (int i = tid; i < N_NODES; i += 1024) {
            unsigned key = fkey(raw[i]);
            if ((key & known_mask) == prefix)
                atomicAdd(&hist[(key >> (byte * 8)) & 255], 1u);
        }
        __syncthreads();
        if (tid == 0) {
            int kk = sh_k;
            int cum = 0;
            int v = 255;
            for (; v > 0; --v) {
                int c = (int)hist[v];
                if (cum + c >= kk) break;
                cum += c;
            }
            sh_prefix = prefix | ((unsigned)v << (byte * 8));
            sh_k = kk - cum;
        }
        __syncthreads();
    }
    if (tid == 0) { *outT = sh_prefix; *outNeedEq = sh_k; }
}

// ---------------- multi-block compaction: count -> scan -> assign ----------------
__global__ __launch_bounds__(256) void topk_count(const float* __restrict__ raw,
                                                  const unsigned* pT,
                                                  int* bGt, int* bEq) {
    __shared__ int sg[256], se[256];
    unsigned T = *pT;
    int t = threadIdx.x;
    int i = blockIdx.x * 256 + t;
    int gt = 0, eq = 0;
    if (i < N_NODES) {
        unsigned k = fkey(raw[i]);
        gt = k > T; eq = (k == T);
    }
    sg[t] = gt; se[t] = eq;
    __syncthreads();
    for (int off = 128; off > 0; off >>= 1) {
        if (t < off) { sg[t] += sg[t + off]; se[t] += se[t + off]; }
        __syncthreads();
    }
    if (t == 0) { bGt[blockIdx.x] = sg[0]; bEq[blockIdx.x] = se[0]; }
}

__global__ __launch_bounds__(256) void scan_blocks(const int* __restrict__ bGt,
                                                   const int* __restrict__ bEq,
                                                   int* gtStart, int* eqStart) {
    __shared__ int sg[256], se[256];
    int t = threadIdx.x;
    int vg = (t < NB2) ? bGt[t] : 0;
    int ve = (t < NB2) ? bEq[t] : 0;
    sg[t] = vg; se[t] = ve;
    __syncthreads();
    for (int off = 1; off < 256; off <<= 1) {
        int a = (t >= off) ? sg[t - off] : 0;
        int b = (t >= off) ? se[t - off] : 0;
        __syncthreads();
        sg[t] += a; se[t] += b;
        __syncthreads();
    }
    if (t < NB2) { gtStart[t] = sg[t] - vg; eqStart[t] = se[t] - ve; }
    if (t == 255) gtStart[NB2] = sg[255];   // totalGt
}

__global__ __launch_bounds__(256) void topk_assign(const float* __restrict__ raw,
                                                   const unsigned* pT, const int* pNeedEq,
                                                   const int* __restrict__ degS,
                                                   const int* __restrict__ gtStart,
                                                   const int* __restrict__ eqStart,
                                                   int* keep, int* cid,
                                                   unsigned long long* bestpack) {
    __shared__ int sg[256], se[256];
    unsigned T = *pT;
    int needEq = *pNeedEq;
    int totalGt = gtStart[NB2];
    int b = blockIdx.x, t = threadIdx.x;
    int i = b * 256 + t;
    int gt = 0, eq = 0;
    unsigned k = 0;
    if (i < N_NODES) {
        k = fkey(raw[i]);
        gt = k > T; eq = (k == T);
    }
    sg[t] = gt; se[t] = eq;
    __syncthreads();
    for (int off = 1; off < 256; off <<= 1) {
        int a = (t >= off) ? sg[t - off] : 0;
        int c = (t >= off) ? se[t - off] : 0;
        __syncthreads();
        sg[t] += a; se[t] += c;
        __syncthreads();
    }
    int eg = sg[t] - gt, ee = se[t] - eq;
    int kp = 0;
    unsigned long long p = 0ULL;
    if (i < N_NODES) {
        int c = -1;
        if (gt) { kp = 1; c = gtStart[b] + eg; }
        else if (eq) {
            int r = eqStart[b] + ee;
            if (r < needEq) { kp = 1; c = totalGt + r; }
        }
        keep[i] = kp; cid[i] = c;
        if (kp) p = ((unsigned long long)(unsigned)degS[i] << 32) | k;
    }
    #pragma unroll
    for (int o = 32; o > 0; o >>= 1) {
        unsigned long long q = __shfl_xor((long long)p, o, 64);
        if (q > p) p = q;
    }
    if ((t & 63) == 0 && p) atomicMax(bestpack, p);
}

__global__ __launch_bounds__(256) void bg_node(const int* __restrict__ keep,
                                               const int* __restrict__ degS,
                                               const float* __restrict__ raw,
                                               const unsigned long long* bestpack, int* bgnode) {
    int i = blockIdx.x * blockDim.x + threadIdx.x;
    if (i < N_NODES && keep[i]) {
        unsigned long long p = ((unsigned long long)(unsigned)degS[i] << 32) | fkey(raw[i]);
        if (p == *bestpack) atomicMin(bgnode, i);
    }
}

// ---------------- neighbor attachment ----------------
__global__ __launch_bounds__(256) void neigh_edges(const int* __restrict__ src,
                                                   const int* __restrict__ dst,
                                                   const int* __restrict__ keep,
                                                   const int* __restrict__ degS,
                                                   unsigned long long* best_enc) {
    int e = blockIdx.x * blockDim.x + threadIdx.x;
    if (e >= 2 * E_EDGES) return;
    int s, t;
    if (e < E_EDGES) { s = src[e]; t = dst[e]; }
    else { s = dst[e - E_EDGES]; t = src[e - E_EDGES]; }
    if (!keep[s] && keep[t]) {
        unsigned long long enc =
            (unsigned long long)((long long)degS[t] * N_NODES + (N_NODES - 1 - t)) + 1ULL;
        atomicMax(&best_enc[s], enc);
    }
}

__global__ __launch_bounds__(256) void resolve_cid(const int* __restrict__ keep,
                                                   const unsigned long long* __restrict__ best_enc,
                                                   const int* __restrict__ bgnode, int* cid) {
    int i = blockIdx.x * blockDim.x + threadIdx.x;
    if (i >= N_NODES) return;
    if (keep[i]) return;
    unsigned long long v = best_enc[i];
    if (v > 0ULL) {
        long long enc = (long long)(v - 1ULL);
        int t = (N_NODES - 1) - (int)(enc % N_NODES);
        cid[i] = cid[t];
    } else {
        cid[i] = cid[*bgnode];
    }
}

// ---------------- LDS-aggregated counting sort by cluster ----------------
#define NPB 1024
__global__ __launch_bounds__(256) void ccount2(const int* __restrict__ cid, int* ccnt) {
    __shared__ int hist[K_CL];
    for (int t = threadIdx.x; t < K_CL; t += 256) hist[t] = 0;
    __syncthreads();
    int base = blockIdx.x * NPB;
    #pragma unroll
    for (int u = 0; u < NPB / 256; ++u) {
        int idx = base + u * 256 + threadIdx.x;
        if (idx < N_NODES) atomicAdd(&hist[cid[idx]], 1);
    }
    __syncthreads();
    for (int t = threadIdx.x; t < K_CL; t += 256) {
        int hh = hist[t];
        if (hh) atomicAdd(&ccnt[t], hh);
    }
}

__global__ __launch_bounds__(256) void cscatter2(const int* __restrict__ cid,
                                                 int* ccur, int* clist) {
    __shared__ int hist[K_CL];
    for (int t = threadIdx.x; t < K_CL; t += 256) hist[t] = 0;
    __syncthreads();
    int base = blockIdx.x * NPB;
    int myc[NPB / 256], myr[NPB / 256];
    #pragma unroll
    for (int u = 0; u < NPB / 256; ++u) {
        int idx = base + u * 256 + threadIdx.x;
        if (idx < N_NODES) { myc[u] = cid[idx]; myr[u] = atomicAdd(&hist[myc[u]], 1); }
        else myc[u] = -1;
    }
    __syncthreads();
    for (int t = threadIdx.x; t < K_CL; t += 256) {
        int hh = hist[t];
        if (hh) hist[t] = atomicAdd(&ccur[t], hh);
    }
    __syncthreads();
    #pragma unroll
    for (int u = 0; u < NPB / 256; ++u)
        if (myc[u] >= 0) clist[hist[myc[u]] + myr[u]] = base + u * 256 + threadIdx.x;
}

// ---------------- chunked segmented pooling ----------------
__global__ __launch_bounds__(256) void pool_chunk(const float* __restrict__ x1,
                                                  const float* __restrict__ raw,
                                                  const int* __restrict__ clist,
                                                  const int* __restrict__ cid,
                                                  float* xp) {
    __shared__ int s_node[PCH];
    __shared__ int s_c[PCH];
    __shared__ float s_g[PCH];
    int j = threadIdx.x;
    int base = blockIdx.x * PCH;
    int m = N_NODES - base; if (m > PCH) m = PCH;
    for (int t = j; t < m; t += 256) {
        int nd = clist[base + t];
        s_node[t] = nd;
        s_c[t] = cid[nd];
        s_g[t] = tanhf(raw[nd]);
    }
    __syncthreads();
    float acc = 0.f;
    int cprev = s_c[0];
    for (int t = 0; t < m; t += 4) {
        int mm = m - t; if (mm > 4) mm = 4;
        float v[4];
        #pragma unroll
        for (int u = 0; u < 4; ++u)
            if (u < mm) v[u] = x1[(long)s_node[t + u] * H_F + j];
        #pragma unroll
        for (int u = 0; u < 4; ++u) {
            if (u < mm) {
                int c = s_c[t + u];
                if (c != cprev) {
                    atomicAdd(&xp[(long)cprev * H_F + j], acc);
                    acc = 0.f;
                    cprev = c;
                }
                acc += s_g[t + u] * v[u];
            }
        }
    }
    atomicAdd(&xp[(long)cprev * H_F + j], acc);
}

// ---------------- bit-packed pooled adjacency ----------------
__global__ __launch_bounds__(256) void build_Abits(const int* __restrict__ src,
                                                   const int* __restrict__ dst,
                                                   const int* __restrict__ cid,
                                                   unsigned* Abits) {
    int e = blockIdx.x * blockDim.x + threadIdx.x;
    if (e >= E_EDGES) return;
    int cu = cid[src[e]], cv = cid[dst[e]];
    if (cu != cv) atomicOr(&Abits[(long)cv * KW + (cu >> 5)], 1u << (cu & 31));
}

// di, nnz, and heavy-row compaction
__global__ __launch_bounds__(256) void pop_di2(const unsigned* __restrict__ Abits, float* di,
                                               int* nnzA, int* heavy, int* heavycnt) {
    int i = blockIdx.x * blockDim.x + threadIdx.x;
    if (i >= K_CL) return;
    int c = 0;
    for (int w = 0; w < KW; ++w) c += __popc(Abits[(long)i * KW + w]);
    di[i] = rsqrtf((float)c + 1.0f);
    nnzA[i] = c;
    if (c > THRESH) {
        int p = atomicAdd(heavycnt, 1);
        if (p < MAXH) heavy[p] = i;
    }
}

// light rows (nnz<=THRESH)
__global__ __launch_bounds__(256) void spmm_light(const unsigned* __restrict__ Abits,
                                                  const float* __restrict__ xpW2,
                                                  const float* __restrict__ di,
                                                  const float* __restrict__ b2,
                                                  const int* __restrict__ nnzA,
                                                  float* xp2) {
    __shared__ unsigned s_row[KW];
    __shared__ float s_part[3][256];
    int cv = blockIdx.x;
    if (nnzA[cv] > THRESH) return;
    int tid = threadIdx.x;
    int w = tid >> 6, l = tid & 63;
    if (tid < KW) s_row[tid] = Abits[(long)cv * KW + tid];
    __syncthreads();
    float4 a0 = {0.f, 0.f, 0.f, 0.f}, a1 = {0.f, 0.f, 0.f, 0.f};
    const float4* Y4 = (const float4*)xpW2;
    for (int wi = w * 32; wi < w * 32 + 32; wi += 2) {
        unsigned w0 = s_row[wi], w1 = s_row[wi + 1];
        while (w0 | w1) {
            if (w0) {
                int b = __ffs(w0) - 1; w0 &= w0 - 1;
                int cu = wi * 32 + b;
                float d = di[cu];
                float4 y = Y4[(long)cu * 64 + l];
                a0.x += d * y.x; a0.y += d * y.y; a0.z += d * y.z; a0.w += d * y.w;
            }
            if (w1) {
                int b = __ffs(w1) - 1; w1 &= w1 - 1;
                int cu = (wi + 1) * 32 + b;
                float d = di[cu];
                float4 y = Y4[(long)cu * 64 + l];
                a1.x += d * y.x; a1.y += d * y.y; a1.z += d * y.z; a1.w += d * y.w;
            }
        }
    }
    float4 acc = {a0.x + a1.x, a0.y + a1.y, a0.z + a1.z, a0.w + a1.w};
    if (w > 0) *(float4*)&s_part[w - 1][l * 4] = acc;
    __syncthreads();
    if (w == 0) {
        #pragma unroll
        for (int ww = 0; ww < 3; ++ww) {
            float4 p = *(float4*)&s_part[ww][l * 4];
            acc.x += p.x; acc.y += p.y; acc.z += p.z; acc.w += p.w;
        }
        float dv = di[cv];
        float4 ys = Y4[(long)cv * 64 + l];
        float4 o;
        o.x = dv * (acc.x + dv * ys.x) + b2[l * 4 + 0];
        o.y = dv * (acc.y + dv * ys.y) + b2[l * 4 + 1];
        o.z = dv * (acc.z + dv * ys.z) + b2[l * 4 + 2];
        o.w = dv * (acc.w + dv * ys.w) + b2[l * 4 + 3];
        *(float4*)&xp2[(long)cv * H_F + l * 4] = o;
    }
}

// heavy rows: grid (MAXH, NSPL); block (hi, sp) handles 4 words (1 per wave)
__global__ __launch_bounds__(256) void spmm_heavy(const unsigned* __restrict__ Abits,
                                                  const float* __restrict__ xpW2,
                                                  const float* __restrict__ di,
                                                  const int* __restrict__ heavy,
                                                  const int* __restrict__ heavycnt,
                                                  float* Zacc) {
    __shared__ float s_part[3][256];
    int hi = blockIdx.x;
    int cnt = *heavycnt; if (cnt > MAXH) cnt = MAXH;
    if (hi >= cnt) return;
    int cv = heavy[hi];
    int sp = blockIdx.y;
    int tid = threadIdx.x;
    int w = tid >> 6, l = tid & 63;
    int wi = sp * (KW / NSPL) + w;
    unsigned word = Abits[(long)cv * KW + wi];
    float4 acc = {0.f, 0.f, 0.f, 0.f};
    const float4* Y4 = (const float4*)xpW2;
    while (word) {
        int b = __ffs(word) - 1; word &= word - 1;
        int cu = wi * 32 + b;
        float d = di[cu];
        float4 y = Y4[(long)cu * 64 + l];
        acc.x += d * y.x; acc.y += d * y.y; acc.z += d * y.z; acc.w += d * y.w;
    }
    if (w > 0) *(float4*)&s_part[w - 1][l * 4] = acc;
    __syncthreads();
    if (w == 0) {
        #pragma unroll
        for (int ww = 0; ww < 3; ++ww) {
            float4 p = *(float4*)&s_part[ww][l * 4];
            acc.x += p.x; acc.y += p.y; acc.z += p.z; acc.w += p.w;
        }
        float* zp = &Zacc[(long)cv * H_F + l * 4];
        atomicAdd(zp + 0, acc.x);
        atomicAdd(zp + 1, acc.y);
        atomicAdd(zp + 2, acc.z);
        atomicAdd(zp + 3, acc.w);
    }
}

__global__ __launch_bounds__(256) void heavy_epi(const float* __restrict__ Zacc,
                                                 const float* __restrict__ xpW2,
                                                 const float* __restrict__ di,
                                                 const float* __restrict__ b2,
                                                 const int* __restrict__ heavy,
                                                 const int* __restrict__ heavycnt,
                                                 float* xp2) {
    int hi = blockIdx.x;
    int cnt = *heavycnt; if (cnt > MAXH) cnt = MAXH;
    if (hi >= cnt) return;
    int cv = heavy[hi];
    int j = threadIdx.x;
    float dv = di[cv];
    xp2[(long)cv * H_F + j] =
        dv * (Zacc[(long)cv * H_F + j] + dv * xpW2[(long)cv * H_F + j]) + b2[j];
}

// ---------------- host launch ----------------
static inline size_t align256(size_t x) { return (x + 255) & ~(size_t)255; }

extern "C" void kernel_launch(void* const* d_in, const int* in_sizes, int n_in,
                              void* d_out, int out_size, void* d_ws, size_t ws_size,
                              hipStream_t stream) {
    const float* x      = (const float*)d_in[0];
    const int*   eidx   = (const int*)d_in[1];
    const float* W1     = (const float*)d_in[2];
    const float* b1     = (const float*)d_in[3];
    const float* W2     = (const float*)d_in[4];
    const float* b2     = (const float*)d_in[5];
    const float* wscore = (const float*)d_in[6];
    const float* Wskip  = (const float*)d_in[7];
    const float* bskip  = (const float*)d_in[8];
    float* out = (float*)d_out;

    const int* src = eidx;
    const int* dst = eidx + E_EDGES;

    char* ws = (char*)d_ws;
    size_t off = 0;
    auto alloc = [&](size_t bytes) { char* p = ws + off; off += align256(bytes); return p; };

    float* h     = (float*)alloc((size_t)N_NODES * H_F * 4);
    float* x1    = (float*)alloc((size_t)N_NODES * H_F * 4);
    u16*   x1b   = (u16*)alloc((size_t)N_NODES * H_F * 2);
    float* raw   = (float*)alloc((size_t)N_NODES * 4);
    float* dinv  = (float*)alloc((size_t)N_NODES * 4);
    int*   cntD  = (int*)alloc((size_t)N_NODES * 4);
    int*   degS  = (int*)alloc((size_t)N_NODES * 4);
    int*   keep  = (int*)alloc((size_t)N_NODES * 4);
    int*   cid   = (int*)alloc((size_t)N_NODES * 4);
    unsigned long long* best_enc = (unsigned long long*)alloc((size_t)N_NODES * 8);
    int*   rowptr= (int*)alloc((size_t)(N_NODES + 1) * 4);
    int*   cur   = (int*)alloc((size_t)N_NODES * 4);
    int*   csr   = (int*)alloc((size_t)E_EDGES * 4);
    int*   ccnt  = (int*)alloc((size_t)K_CL * 4);
    int*   cstart= (int*)alloc((size_t)(K_CL + 1) * 4);
    int*   ccur  = (int*)alloc((size_t)K_CL * 4);
    int*   clist = (int*)alloc((size_t)N_NODES * 4);
    int*   bGt   = (int*)alloc((size_t)NB2 * 4);
    int*   bEq   = (int*)alloc((size_t)NB2 * 4);
    int*   gtStart = (int*)alloc((size_t)(NB2 + 1) * 4);
    int*   eqStart = (int*)alloc((size_t)NB2 * 4);
    int*   bsum  = (int*)alloc((size_t)256 * 4);
    int*   bstart= (int*)alloc((size_t)256 * 4);
    char*  small = alloc(64);
    unsigned* selT = (unsigned*)(small + 0);
    int* needEq    = (int*)(small + 4);
    int* bgnode    = (int*)(small + 8);
    int* heavycnt  = (int*)(small + 12);
    unsigned long long* bestpack = (unsigned long long*)(small + 16);
    float* xp    = (float*)alloc((size_t)K_CL * H_F * 4);
    unsigned* Abits = (unsigned*)alloc((size_t)K_CL * KW * 4);
    float* di    = (float*)alloc((size_t)K_CL * 4);
    int*   nnzA  = (int*)alloc((size_t)K_CL * 4);
    int*   heavy = (int*)alloc((size_t)MAXH * 4);
    float* Zacc  = (float*)alloc((size_t)K_CL * H_F * 4);
    float* xpW2  = (float*)alloc((size_t)K_CL * H_F * 4);
    float* xp2   = (float*)alloc((size_t)K_CL * H_F * 4);
    u16*  BpS   = (u16*)alloc((size_t)H_F * OUT_F * 2);
    u16*  Bp2   = (u16*)alloc((size_t)H_F * H_F * 2);
    (void)ws_size; (void)n_in; (void)in_sizes; (void)out_size;

    int nb = NB2;
    int eb = (E_EDGES + 255) / 256;

    // degrees
    init_nodes<<<nb, 256, 0, stream>>>(cntD, degS, best_enc, bgnode, heavycnt, bestpack);
    deg_edges<<<eb, 256, 0, stream>>>(src, dst, cntD, degS);

    // weight packing (both in one launch)
    pack_W2<<<512, 256, 0, stream>>>(Wskip, BpS, W2, Bp2);

    // h = x @ W1 (fp32 — score path must stay exact)
    {
        dim3 grid(H_F / SBN, (N_NODES + SBM - 1) / SBM);
        gemm_f32s<<<grid, 256, 0, stream>>>(x, W1, h, N_NODES, H_F, IN_F);
    }

    // CSR by dst: coalesced two-level scan (also emits dinv) + scatter, then aggregation
    scan_l1<<<NB2, 256, 0, stream>>>(cntD, bsum, N_NODES, dinv);
    scan_l2<<<1, 256, 0, stream>>>(bsum, bstart, NB2);
    scan_l3<<<NB2, 256, 0, stream>>>(cntD, bstart, rowptr, cur, N_NODES);
    csr_scatter<<<eb, 256, 0, stream>>>(src, dst, cur, csr);
    agg_fused<<<N_NODES, 256, 0, stream>>>(h, dinv, rowptr, csr, b1, wscore, x1, x1b, raw);

    // top-K: threshold -> multi-block coalesced count/scan/assign
    topk_select<<<1, 1024, 0, stream>>>(raw, selT, needEq);
    topk_count<<<NB2, 256, 0, stream>>>(raw, selT, bGt, bEq);
    scan_blocks<<<1, 256, 0, stream>>>(bGt, bEq, gtStart, eqStart);
    topk_assign<<<NB2, 256, 0, stream>>>(raw, selT, needEq, degS, gtStart, eqStart,
                                         keep, cid, bestpack);
    bg_node<<<nb, 256, 0, stream>>>(keep, degS, raw, bestpack, bgnode);

    // neighbor attachment
    neigh_edges<<<(2 * E_EDGES + 255) / 256, 256, 0, stream>>>(src, dst, keep, degS, best_enc);
    resolve_cid<<<nb, 256, 0, stream>>>(keep, best_enc, bgnode, cid);

    // LDS-aggregated counting sort by cluster, then chunked segmented pooling
    hipMemsetAsync(ccnt, 0, (size_t)K_CL * 4, stream);
    {
        int cb = (N_NODES + NPB - 1) / NPB;
        ccount2<<<cb, 256, 0, stream>>>(cid, ccnt);
        scan_l1<<<K_CL / 256, 256, 0, stream>>>(ccnt, bsum, K_CL, nullptr);
        scan_l2<<<1, 256, 0, stream>>>(bsum, bstart, K_CL / 256);
        scan_l3<<<K_CL / 256, 256, 0, stream>>>(ccnt, bstart, cstart, ccur, K_CL);
        cscatter2<<<cb, 256, 0, stream>>>(cid, ccur, clist);
    }
    hipMemsetAsync(xp, 0, (size_t)K_CL * H_F * 4, stream);
    pool_chunk<<<(N_NODES + PCH - 1) / PCH, 256, 0, stream>>>(x1, raw, clist, cid, xp);

    // xpW2 = (xp/cnt) @ W2  (bf16 MFMA, in-kernel fp32->bf16 conversion)
    gemm_mfma<<<K_CL / 64, 256, 0, stream>>>(nullptr, xp, ccnt, Bp2, xpW2, K_CL,
                                             nullptr, nullptr, nullptr);

    // bit-packed pooled adjacency + split light/heavy normalized SpMM
    hipMemsetAsync(Abits, 0, (size_t)K_CL * KW * 4, stream);
    hipMemsetAsync(Zacc, 0, (size_t)K_CL * H_F * 4, stream);
    build_Abits<<<eb, 256, 0, stream>>>(src, dst, cid, Abits);
    pop_di2<<<(K_CL + 255) / 256, 256, 0, stream>>>(Abits, di, nnzA, heavy, heavycnt);
    spmm_light<<<K_CL, 256, 0, stream>>>(Abits, xpW2, di, b2, nnzA, xp2);
    {
        dim3 hgrid(MAXH, NSPL);
        spmm_heavy<<<hgrid, 256, 0, stream>>>(Abits, xpW2, di, heavy, heavycnt, Zacc);
    }
    heavy_epi<<<MAXH, 256, 0, stream>>>(Zacc, xpW2, di, b2, heavy, heavycnt, xp2);

    // out = x1@Wskip + xp2[cid] + b_skip  (bf16 MFMA, fused epilogue)
    gemm_mfma<<<(N_NODES + 63) / 64, 256, 0, stream>>>(x1b, nullptr, nullptr, BpS, out,
                                                       N_NODES, cid, xp2, bskip);
}

// Round 14
// 721.318 us; speedup vs baseline: 1.0317x; 1.0090x over previous
//
#include <hip/hip_runtime.h>
#include <hip/hip_bf16.h>

#define N_NODES 50000
#define E_EDGES 300000
#define IN_F 512
#define H_F 256
#define OUT_F 256
#define K_CL 4096
#define KW (K_CL / 32)
#define PCH 128
#define THRESH 192
#define MAXH 1024
#define NSPL 32
#define NB2 ((N_NODES + 255) / 256)

typedef short bh8 __attribute__((ext_vector_type(8)));
typedef float f4 __attribute__((ext_vector_type(4)));
typedef unsigned short u16;

__device__ __forceinline__ unsigned fkey(float f) {
    unsigned u = __float_as_uint(f);
    return (u & 0x80000000u) ? ~u : (u | 0x80000000u);
}

__device__ __forceinline__ u16 f2bf(float f) {
    __hip_bfloat16 b = __float2bfloat16(f);
    return *reinterpret_cast<u16*>(&b);
}

// ---------------- init ----------------
__global__ __launch_bounds__(256) void init_nodes(int* cntD, int* degS,
                                                  unsigned long long* best_enc,
                                                  int* bgnode, int* heavycnt,
                                                  unsigned long long* bestpack) {
    int i = blockIdx.x * blockDim.x + threadIdx.x;
    if (i < N_NODES) { cntD[i] = 0; degS[i] = 0; best_enc[i] = 0ULL; }
    if (i == 0) { *heavycnt = 0; *bgnode = 0x7FFFFFFF; *bestpack = 0ULL; }
}

__global__ __launch_bounds__(256) void deg_edges(const int* __restrict__ src,
                                                 const int* __restrict__ dst,
                                                 int* cntD, int* degS) {
    int e = blockIdx.x * blockDim.x + threadIdx.x;
    if (e >= E_EDGES) return;
    atomicAdd(&cntD[dst[e]], 1);
    atomicAdd(&degS[src[e]], 1);
}

// ---- fp32 GEMM (score path): 64x128 tile, dbuf LDS, glds for BOTH A and B ----
// A staged row-major [m][k] via global_load_lds (per-lane global addr, linear LDS),
// with XOR bit-5 swizzle on byte offset keyed by (row>>2)&1 applied to BOTH the
// glds source column and the fragment-read column (involution -> conflict-free).
// FP accumulation order is k-ascending, identical to prior version (bit-identical h).
#define SBM 64
#define SBN 128
#define SBK 16
__global__ __launch_bounds__(256) void gemm_f32s(const float* __restrict__ A,
                                                 const float* __restrict__ B,
                                                 float* __restrict__ C,
                                                 int M, int Nc, int Kd) {
    __shared__ float As[2][SBM][SBK];   // linear (glds-written), swizzled columns
    __shared__ float Bs[2][SBK][SBN];
    int tid = threadIdx.x;
    int tx = tid & 15;
    int ty = tid >> 4;
    int lane = tid & 63;
    int wave = tid >> 6;
    int row0 = blockIdx.y * SBM, col0 = blockIdx.x * SBN;
    float acc[4][8] = {};

    // A staging geometry: wave stages rows [wave*16, wave*16+16)
    int arow = wave * 16 + (lane >> 2);                         // row within tile
    int acolf = ((((lane & 3) * 16) ^ (((lane >> 4) & 1) << 5)) >> 2);  // src col (floats)

    auto stage_B = [&](int k0, int bb) {
        #pragma unroll
        for (int u = 0; u < 2; ++u) {
            int chunk = wave * 2 + u;
            int krow = chunk * 2 + (lane >> 5);
            const float* gsrc = &B[(long)(k0 + krow) * Nc + col0 + (lane & 31) * 4];
            __builtin_amdgcn_global_load_lds(
                (const __attribute__((address_space(1))) void*)gsrc,
                (__attribute__((address_space(3))) void*)&Bs[bb][chunk * 2][0],
                16, 0, 0);
        }
    };
    auto stage_A = [&](int k0, int bb) {
        int gr = row0 + arow;
        if (gr > M - 1) gr = M - 1;        // clamp: OOB rows load harmless data
        const float* gsrc = &A[(long)gr * Kd + k0 + acolf];
        __builtin_amdgcn_global_load_lds(
            (const __attribute__((address_space(1))) void*)gsrc,
            (__attribute__((address_space(3))) void*)&As[bb][wave * 16][0],
            16, 0, 0);
    };
    auto compute = [&](int bb) {
        #pragma unroll
        for (int kq = 0; kq < 4; ++kq) {
            float4 af[4];
            #pragma unroll
            for (int i = 0; i < 4; ++i) {
                int row = ty * 4 + i;
                int cb = ((kq * 16 ^ (((row >> 2) & 1) << 5)) >> 2);
                af[i] = *(const float4*)&As[bb][row][cb];
            }
            #pragma unroll
            for (int kk = 0; kk < 4; ++kk) {
                int k = kq * 4 + kk;
                float4 b0 = *(const float4*)&Bs[bb][k][tx * 4];
                float4 b1 = *(const float4*)&Bs[bb][k][tx * 4 + 64];
                float bv[8] = {b0.x, b0.y, b0.z, b0.w, b1.x, b1.y, b1.z, b1.w};
                float av[4] = {af[0][kk], af[1][kk], af[2][kk], af[3][kk]};
                #pragma unroll
                for (int i = 0; i < 4; ++i)
                    #pragma unroll
                    for (int j = 0; j < 8; ++j)
                        acc[i][j] += av[i] * bv[j];
            }
        }
    };

    stage_B(0, 0);
    stage_A(0, 0);
    __syncthreads();
    int nt = Kd / SBK;
    for (int t = 0; t < nt; ++t) {
        int cb = t & 1;
        if (t + 1 < nt) {
            stage_B(SBK * (t + 1), cb ^ 1);   // all staging async -> drains at barrier
            stage_A(SBK * (t + 1), cb ^ 1);
        }
        compute(cb);
        __syncthreads();
    }

    #pragma unroll
    for (int i = 0; i < 4; ++i) {
        int gr = row0 + ty * 4 + i;
        if (gr >= M) continue;
        float4 o0 = {acc[i][0], acc[i][1], acc[i][2], acc[i][3]};
        float4 o1 = {acc[i][4], acc[i][5], acc[i][6], acc[i][7]};
        *(float4*)&C[(long)gr * Nc + col0 + tx * 4] = o0;
        *(float4*)&C[(long)gr * Nc + col0 + 64 + tx * 4] = o1;
    }
}

// ---- pack two 256x256 fp32 weights into MFMA-fragment-ordered bf16 (one launch) ----
__global__ __launch_bounds__(256) void pack_W2(const float* __restrict__ Wa, u16* Bpa,
                                               const float* __restrict__ Wb, u16* Bpb) {
    int k = blockIdx.x & 255;
    const float* W = (blockIdx.x < 256) ? Wa : Wb;
    u16* Bp = (blockIdx.x < 256) ? Bpa : Bpb;
    int col = threadIdx.x;
    int kb = k >> 5, g = (k >> 3) & 3, j = k & 7;
    Bp[(((long)(kb * 4 + g) * 256) + col) * 8 + j] = f2bf(W[(long)k * 256 + col]);
}

// ---- bf16 MFMA GEMM: C(Mx256) = A(Mx256) @ Bp(packed) ----
__global__ __launch_bounds__(256) void gemm_mfma(const u16* __restrict__ Ab,
                                                 const float* __restrict__ Af32,
                                                 const int* __restrict__ cnt,
                                                 const u16* __restrict__ Bp,
                                                 float* __restrict__ C,
                                                 int M,
                                                 const int* __restrict__ cid,
                                                 const float* __restrict__ xp2,
                                                 const float* __restrict__ bskip) {
    int tid = threadIdx.x;
    int w = tid >> 6, l = tid & 63;
    int lo16 = l & 15, hi4 = l >> 4;
    int arow = blockIdx.x * 64 + w * 16 + lo16;
    f4 acc[16];
    #pragma unroll
    for (int n = 0; n < 16; ++n) acc[n] = (f4){0.f, 0.f, 0.f, 0.f};

    float s = 1.f;
    if (Af32 && arow < M) s = 1.f / fmaxf((float)cnt[arow], 1.f);

    #pragma unroll
    for (int kb = 0; kb < 8; ++kb) {
        bh8 a = {0, 0, 0, 0, 0, 0, 0, 0};
        if (arow < M) {
            if (Af32) {
                float4 v0 = *(const float4*)&Af32[(long)arow * 256 + kb * 32 + hi4 * 8];
                float4 v1 = *(const float4*)&Af32[(long)arow * 256 + kb * 32 + hi4 * 8 + 4];
                u16 tmp[8] = {f2bf(v0.x * s), f2bf(v0.y * s), f2bf(v0.z * s), f2bf(v0.w * s),
                              f2bf(v1.x * s), f2bf(v1.y * s), f2bf(v1.z * s), f2bf(v1.w * s)};
                a = *(const bh8*)tmp;
            } else {
                a = *(const bh8*)&Ab[(long)arow * 256 + kb * 32 + hi4 * 8];
            }
        }
        const u16* bbase = &Bp[(((long)(kb * 4 + hi4)) * 256 + lo16) * 8];
        #pragma unroll
        for (int n = 0; n < 16; ++n) {
            bh8 b = *(const bh8*)&bbase[(long)n * 128];
            acc[n] = __builtin_amdgcn_mfma_f32_16x16x32_bf16(a, b, acc[n], 0, 0, 0);
        }
    }

    int orow0 = blockIdx.x * 64 + w * 16 + hi4 * 4;
    #pragma unroll
    for (int r = 0; r < 4; ++r) {
        int gr = orow0 + r;
        if (gr >= M) continue;
        long rb = (long)gr * 256;
        const float* xrow = cid ? (xp2 + (long)cid[gr] * 256) : nullptr;
        #pragma unroll
        for (int n = 0; n < 16; ++n) {
            int gc = n * 16 + lo16;
            float v = acc[n][r];
            if (cid) v += xrow[gc] + bskip[gc];
            C[rb + gc] = v;
        }
    }
}

// --------- coalesced two-level exclusive scan (n <= 256*256) ---------
__global__ __launch_bounds__(256) void scan_l1(const int* __restrict__ cnt,
                                               int* bsum, int n, float* dinv) {
    __shared__ int s[256];
    int t = threadIdx.x;
    int i = blockIdx.x * 256 + t;
    int v = (i < n) ? cnt[i] : 0;
    if (dinv && i < n) dinv[i] = rsqrtf((float)v + 1.0f);
    s[t] = v;
    __syncthreads();
    for (int off = 128; off > 0; off >>= 1) {
        if (t < off) s[t] += s[t + off];
        __syncthreads();
    }
    if (t == 0) bsum[blockIdx.x] = s[0];
}

__global__ __launch_bounds__(256) void scan_l2(const int* __restrict__ bsum,
                                               int* bstart, int nb) {
    __shared__ int s[256];
    int t = threadIdx.x;
    int v = (t < nb) ? bsum[t] : 0;
    s[t] = v;
    __syncthreads();
    for (int off = 1; off < 256; off <<= 1) {
        int a = (t >= off) ? s[t - off] : 0;
        __syncthreads();
        s[t] += a;
        __syncthreads();
    }
    if (t < nb) bstart[t] = s[t] - v;
}

__global__ __launch_bounds__(256) void scan_l3(const int* __restrict__ cnt,
                                               const int* __restrict__ bstart,
                                               int* start, int* cur, int n) {
    __shared__ int s[256];
    int t = threadIdx.x;
    int i = blockIdx.x * 256 + t;
    int v = (i < n) ? cnt[i] : 0;
    s[t] = v;
    __syncthreads();
    for (int off = 1; off < 256; off <<= 1) {
        int a = (t >= off) ? s[t - off] : 0;
        __syncthreads();
        s[t] += a;
        __syncthreads();
    }
    int st = bstart[blockIdx.x] + s[t] - v;
    if (i < n) { start[i] = st; cur[i] = st; }
    if (i == n - 1) start[n] = st + v;
}

__global__ __launch_bounds__(256) void csr_scatter(const int* __restrict__ src,
                                                   const int* __restrict__ dst,
                                                   int* cur, int* csr) {
    int e = blockIdx.x * blockDim.x + threadIdx.x;
    if (e >= E_EDGES) return;
    int d = dst[e];
    int p = atomicAdd(&cur[d], 1);
    csr[p] = src[e];
}

// ---------------- fused conv1 aggregation + relu + score + bf16 emit ----------------
__global__ __launch_bounds__(256) void agg_fused(const float* __restrict__ h,
                                                 const float* __restrict__ dinv,
                                                 const int* __restrict__ rowptr,
                                                 const int* __restrict__ csr,
                                                 const float* __restrict__ b1,
                                                 const float* __restrict__ w_score,
                                                 float* x1, u16* x1b, float* raw) {
    __shared__ int s_src[128];
    __shared__ float s_cf[128];
    __shared__ float red[256];
    int i = blockIdx.x, j = threadIdx.x;
    float di_ = dinv[i];
    float acc = di_ * di_ * h[(long)i * H_F + j];
    int p0 = rowptr[i], p1 = rowptr[i + 1];
    for (int base = p0; base < p1; base += 128) {
        int m = p1 - base; if (m > 128) m = 128;
        if (j < m) { int s = csr[base + j]; s_src[j] = s; s_cf[j] = dinv[s]; }
        __syncthreads();
        #pragma unroll 4
        for (int t = 0; t < m; ++t)
            acc += (s_cf[t] * di_) * h[(long)s_src[t] * H_F + j];
        __syncthreads();
    }
    float v = fmaxf(acc + b1[j], 0.f);
    x1[(long)i * H_F + j] = v;
    x1b[(long)i * H_F + j] = f2bf(v);
    red[j] = v * w_score[j];
    __syncthreads();
    for (int off = 128; off > 0; off >>= 1) {
        if (j < off) red[j] += red[j + off];
        __syncthreads();
    }
    if (j == 0) raw[i] = red[0];
}

// ---------------- top-K select (single block radix) ----------------
__global__ __launch_bounds__(1024) void topk_select(const float* __restrict__ raw,
                                                    unsigned* outT, int* outNeedEq) {
    __shared__ unsigned hist[256];
    __shared__ unsigned sh_prefix;
    __shared__ int sh_k;
    int tid = threadIdx.x;
    if (tid == 0) { sh_prefix = 0; sh_k = K_CL; }
    __syncthreads();
    for (int byte = 3; byte >= 0; --byte) {
        if (tid < 256) hist[tid] = 0;
        __syncthreads();
        unsigned prefix = sh_prefix;
        unsigned known_mask = (byte == 3) ? 0u : (0xFFFFFFFFu << ((byte + 1) * 8));
        for (int i = tid; i < N_NODES; i += 1024) {
            unsigned key = fkey(raw[i]);
            if ((key & known_mask) == prefix)
                atomicAdd(&hist[(key >> (byte * 8)) & 255], 1u);
        }
        __syncthreads();
        if (tid == 0) {
            int kk = sh_k;
            int cum = 0;
            int v = 255;
            for (; v > 0; --v) {
                int c = (int)hist[v];
                if (cum + c >= kk) break;
                cum += c;
            }
            sh_prefix = prefix | ((unsigned)v << (byte * 8));
            sh_k = kk - cum;
        }
        __syncthreads();
    }
    if (tid == 0) { *outT = sh_prefix; *outNeedEq = sh_k; }
}

// ---------------- multi-block compaction: count -> scan -> assign ----------------
__global__ __launch_bounds__(256) void topk_count(const float* __restrict__ raw,
                                                  const unsigned* pT,
                                                  int* bGt, int* bEq) {
    __shared__ int sg[256], se[256];
    unsigned T = *pT;
    int t = threadIdx.x;
    int i = blockIdx.x * 256 + t;
    int gt = 0, eq = 0;
    if (i < N_NODES) {
        unsigned k = fkey(raw[i]);
        gt = k > T; eq = (k == T);
    }
    sg[t] = gt; se[t] = eq;
    __syncthreads();
    for (int off = 128; off > 0; off >>= 1) {
        if (t < off) { sg[t] += sg[t + off]; se[t] += se[t + off]; }
        __syncthreads();
    }
    if (t == 0) { bGt[blockIdx.x] = sg[0]; bEq[blockIdx.x] = se[0]; }
}

__global__ __launch_bounds__(256) void scan_blocks(const int* __restrict__ bGt,
                                                   const int* __restrict__ bEq,
                                                   int* gtStart, int* eqStart) {
    __shared__ int sg[256], se[256];
    int t = threadIdx.x;
    int vg = (t < NB2) ? bGt[t] : 0;
    int ve = (t < NB2) ? bEq[t] : 0;
    sg[t] = vg; se[t] = ve;
    __syncthreads();
    for (int off = 1; off < 256; off <<= 1) {
        int a = (t >= off) ? sg[t - off] : 0;
        int b = (t >= off) ? se[t - off] : 0;
        __syncthreads();
        sg[t] += a; se[t] += b;
        __syncthreads();
    }
    if (t < NB2) { gtStart[t] = sg[t] - vg; eqStart[t] = se[t] - ve; }
    if (t == 255) gtStart[NB2] = sg[255];   // totalGt
}

__global__ __launch_bounds__(256) void topk_assign(const float* __restrict__ raw,
                                                   const unsigned* pT, const int* pNeedEq,
                                                   const int* __restrict__ degS,
                                                   const int* __restrict__ gtStart,
                                                   const int* __restrict__ eqStart,
                                                   int* keep, int* cid,
                                                   unsigned long long* bestpack) {
    __shared__ int sg[256], se[256];
    unsigned T = *pT;
    int needEq = *pNeedEq;
    int totalGt = gtStart[NB2];
    int b = blockIdx.x, t = threadIdx.x;
    int i = b * 256 + t;
    int gt = 0, eq = 0;
    unsigned k = 0;
    if (i < N_NODES) {
        k = fkey(raw[i]);
        gt = k > T; eq = (k == T);
    }
    sg[t] = gt; se[t] = eq;
    __syncthreads();
    for (int off = 1; off < 256; off <<= 1) {
        int a = (t >= off) ? sg[t - off] : 0;
        int c = (t >= off) ? se[t - off] : 0;
        __syncthreads();
        sg[t] += a; se[t] += c;
        __syncthreads();
    }
    int eg = sg[t] - gt, ee = se[t] - eq;
    int kp = 0;
    unsigned long long p = 0ULL;
    if (i < N_NODES) {
        int c = -1;
        if (gt) { kp = 1; c = gtStart[b] + eg; }
        else if (eq) {
            int r = eqStart[b] + ee;
            if (r < needEq) { kp = 1; c = totalGt + r; }
        }
        keep[i] = kp; cid[i] = c;
        if (kp) p = ((unsigned long long)(unsigned)degS[i] << 32) | k;
    }
    #pragma unroll
    for (int o = 32; o > 0; o >>= 1) {
        unsigned long long q = __shfl_xor((long long)p, o, 64);
        if (q > p) p = q;
    }
    if ((t & 63) == 0 && p) atomicMax(bestpack, p);
}

__global__ __launch_bounds__(256) void bg_node(const int* __restrict__ keep,
                                               const int* __restrict__ degS,
                                               const float* __restrict__ raw,
                                               const unsigned long long* bestpack, int* bgnode) {
    int i = blockIdx.x * blockDim.x + threadIdx.x;
    if (i < N_NODES && keep[i]) {
        unsigned long long p = ((unsigned long long)(unsigned)degS[i] << 32) | fkey(raw[i]);
        if (p == *bestpack) atomicMin(bgnode, i);
    }
}

// ---------------- neighbor attachment ----------------
__global__ __launch_bounds__(256) void neigh_edges(const int* __restrict__ src,
                                                   const int* __restrict__ dst,
                                                   const int* __restrict__ keep,
                                                   const int* __restrict__ degS,
                                                   unsigned long long* best_enc) {
    int e = blockIdx.x * blockDim.x + threadIdx.x;
    if (e >= 2 * E_EDGES) return;
    int s, t;
    if (e < E_EDGES) { s = src[e]; t = dst[e]; }
    else { s = dst[e - E_EDGES]; t = src[e - E_EDGES]; }
    if (!keep[s] && keep[t]) {
        unsigned long long enc =
            (unsigned long long)((long long)degS[t] * N_NODES + (N_NODES - 1 - t)) + 1ULL;
        atomicMax(&best_enc[s], enc);
    }
}

__global__ __launch_bounds__(256) void resolve_cid(const int* __restrict__ keep,
                                                   const unsigned long long* __restrict__ best_enc,
                                                   const int* __restrict__ bgnode, int* cid) {
    int i = blockIdx.x * blockDim.x + threadIdx.x;
    if (i >= N_NODES) return;
    if (keep[i]) return;
    unsigned long long v = best_enc[i];
    if (v > 0ULL) {
        long long enc = (long long)(v - 1ULL);
        int t = (N_NODES - 1) - (int)(enc % N_NODES);
        cid[i] = cid[t];
    } else {
        cid[i] = cid[*bgnode];
    }
}

// ---------------- LDS-aggregated counting sort by cluster ----------------
#define NPB 1024
__global__ __launch_bounds__(256) void ccount2(const int* __restrict__ cid, int* ccnt) {
    __shared__ int hist[K_CL];
    for (int t = threadIdx.x; t < K_CL; t += 256) hist[t] = 0;
    __syncthreads();
    int base = blockIdx.x * NPB;
    #pragma unroll
    for (int u = 0; u < NPB / 256; ++u) {
        int idx = base + u * 256 + threadIdx.x;
        if (idx < N_NODES) atomicAdd(&hist[cid[idx]], 1);
    }
    __syncthreads();
    for (int t = threadIdx.x; t < K_CL; t += 256) {
        int hh = hist[t];
        if (hh) atomicAdd(&ccnt[t], hh);
    }
}

__global__ __launch_bounds__(256) void cscatter2(const int* __restrict__ cid,
                                                 int* ccur, int* clist) {
    __shared__ int hist[K_CL];
    for (int t = threadIdx.x; t < K_CL; t += 256) hist[t] = 0;
    __syncthreads();
    int base = blockIdx.x * NPB;
    int myc[NPB / 256], myr[NPB / 256];
    #pragma unroll
    for (int u = 0; u < NPB / 256; ++u) {
        int idx = base + u * 256 + threadIdx.x;
        if (idx < N_NODES) { myc[u] = cid[idx]; myr[u] = atomicAdd(&hist[myc[u]], 1); }
        else myc[u] = -1;
    }
    __syncthreads();
    for (int t = threadIdx.x; t < K_CL; t += 256) {
        int hh = hist[t];
        if (hh) hist[t] = atomicAdd(&ccur[t], hh);
    }
    __syncthreads();
    #pragma unroll
    for (int u = 0; u < NPB / 256; ++u)
        if (myc[u] >= 0) clist[hist[myc[u]] + myr[u]] = base + u * 256 + threadIdx.x;
}

// ---------------- chunked segmented pooling ----------------
__global__ __launch_bounds__(256) void pool_chunk(const float* __restrict__ x1,
                                                  const float* __restrict__ raw,
                                                  const int* __restrict__ clist,
                                                  const int* __restrict__ cid,
                                                  float* xp) {
    __shared__ int s_node[PCH];
    __shared__ int s_c[PCH];
    __shared__ float s_g[PCH];
    int j = threadIdx.x;
    int base = blockIdx.x * PCH;
    int m = N_NODES - base; if (m > PCH) m = PCH;
    for (int t = j; t < m; t += 256) {
        int nd = clist[base + t];
        s_node[t] = nd;
        s_c[t] = cid[nd];
        s_g[t] = tanhf(raw[nd]);
    }
    __syncthreads();
    float acc = 0.f;
    int cprev = s_c[0];
    for (int t = 0; t < m; t += 4) {
        int mm = m - t; if (mm > 4) mm = 4;
        float v[4];
        #pragma unroll
        for (int u = 0; u < 4; ++u)
            if (u < mm) v[u] = x1[(long)s_node[t + u] * H_F + j];
        #pragma unroll
        for (int u = 0; u < 4; ++u) {
            if (u < mm) {
                int c = s_c[t + u];
                if (c != cprev) {
                    atomicAdd(&xp[(long)cprev * H_F + j], acc);
                    acc = 0.f;
                    cprev = c;
                }
                acc += s_g[t + u] * v[u];
            }
        }
    }
    atomicAdd(&xp[(long)cprev * H_F + j], acc);
}

// ---------------- bit-packed pooled adjacency ----------------
__global__ __launch_bounds__(256) void build_Abits(const int* __restrict__ src,
                                                   const int* __restrict__ dst,
                                                   const int* __restrict__ cid,
                                                   unsigned* Abits) {
    int e = blockIdx.x * blockDim.x + threadIdx.x;
    if (e >= E_EDGES) return;
    int cu = cid[src[e]], cv = cid[dst[e]];
    if (cu != cv) atomicOr(&Abits[(long)cv * KW + (cu >> 5)], 1u << (cu & 31));
}

// di, nnz, and heavy-row compaction
__global__ __launch_bounds__(256) void pop_di2(const unsigned* __restrict__ Abits, float* di,
                                               int* nnzA, int* heavy, int* heavycnt) {
    int i = blockIdx.x * blockDim.x + threadIdx.x;
    if (i >= K_CL) return;
    int c = 0;
    for (int w = 0; w < KW; ++w) c += __popc(Abits[(long)i * KW + w]);
    di[i] = rsqrtf((float)c + 1.0f);
    nnzA[i] = c;
    if (c > THRESH) {
        int p = atomicAdd(heavycnt, 1);
        if (p < MAXH) heavy[p] = i;
    }
}

// light rows (nnz<=THRESH)
__global__ __launch_bounds__(256) void spmm_light(const unsigned* __restrict__ Abits,
                                                  const float* __restrict__ xpW2,
                                                  const float* __restrict__ di,
                                                  const float* __restrict__ b2,
                                                  const int* __restrict__ nnzA,
                                                  float* xp2) {
    __shared__ unsigned s_row[KW];
    __shared__ float s_part[3][256];
    int cv = blockIdx.x;
    if (nnzA[cv] > THRESH) return;
    int tid = threadIdx.x;
    int w = tid >> 6, l = tid & 63;
    if (tid < KW) s_row[tid] = Abits[(long)cv * KW + tid];
    __syncthreads();
    float4 a0 = {0.f, 0.f, 0.f, 0.f}, a1 = {0.f, 0.f, 0.f, 0.f};
    const float4* Y4 = (const float4*)xpW2;
    for (int wi = w * 32; wi < w * 32 + 32; wi += 2) {
        unsigned w0 = s_row[wi], w1 = s_row[wi + 1];
        while (w0 | w1) {
            if (w0) {
                int b = __ffs(w0) - 1; w0 &= w0 - 1;
                int cu = wi * 32 + b;
                float d = di[cu];
                float4 y = Y4[(long)cu * 64 + l];
                a0.x += d * y.x; a0.y += d * y.y; a0.z += d * y.z; a0.w += d * y.w;
            }
            if (w1) {
                int b = __ffs(w1) - 1; w1 &= w1 - 1;
                int cu = (wi + 1) * 32 + b;
                float d = di[cu];
                float4 y = Y4[(long)cu * 64 + l];
                a1.x += d * y.x; a1.y += d * y.y; a1.z += d * y.z; a1.w += d * y.w;
            }
        }
    }
    float4 acc = {a0.x + a1.x, a0.y + a1.y, a0.z + a1.z, a0.w + a1.w};
    if (w > 0) *(float4*)&s_part[w - 1][l * 4] = acc;
    __syncthreads();
    if (w == 0) {
        #pragma unroll
        for (int ww = 0; ww < 3; ++ww) {
            float4 p = *(float4*)&s_part[ww][l * 4];
            acc.x += p.x; acc.y += p.y; acc.z += p.z; acc.w += p.w;
        }
        float dv = di[cv];
        float4 ys = Y4[(long)cv * 64 + l];
        float4 o;
        o.x = dv * (acc.x + dv * ys.x) + b2[l * 4 + 0];
        o.y = dv * (acc.y + dv * ys.y) + b2[l * 4 + 1];
        o.z = dv * (acc.z + dv * ys.z) + b2[l * 4 + 2];
        o.w = dv * (acc.w + dv * ys.w) + b2[l * 4 + 3];
        *(float4*)&xp2[(long)cv * H_F + l * 4] = o;
    }
}

// heavy rows: grid (MAXH, NSPL); block (hi, sp) handles 4 words (1 per wave)
__global__ __launch_bounds__(256) void spmm_heavy(const unsigned* __restrict__ Abits,
                                                  const float* __restrict__ xpW2,
                                                  const float* __restrict__ di,
                                                  const int* __restrict__ heavy,
                                                  const int* __restrict__ heavycnt,
                                                  float* Zacc) {
    __shared__ float s_part[3][256];
    int hi = blockIdx.x;
    int cnt = *heavycnt; if (cnt > MAXH) cnt = MAXH;
    if (hi >= cnt) return;
    int cv = heavy[hi];
    int sp = blockIdx.y;
    int tid = threadIdx.x;
    int w = tid >> 6, l = tid & 63;
    int wi = sp * (KW / NSPL) + w;
    unsigned word = Abits[(long)cv * KW + wi];
    float4 acc = {0.f, 0.f, 0.f, 0.f};
    const float4* Y4 = (const float4*)xpW2;
    while (word) {
        int b = __ffs(word) - 1; word &= word - 1;
        int cu = wi * 32 + b;
        float d = di[cu];
        float4 y = Y4[(long)cu * 64 + l];
        acc.x += d * y.x; acc.y += d * y.y; acc.z += d * y.z; acc.w += d * y.w;
    }
    if (w > 0) *(float4*)&s_part[w - 1][l * 4] = acc;
    __syncthreads();
    if (w == 0) {
        #pragma unroll
        for (int ww = 0; ww < 3; ++ww) {
            float4 p = *(float4*)&s_part[ww][l * 4];
            acc.x += p.x; acc.y += p.y; acc.z += p.z; acc.w += p.w;
        }
        float* zp = &Zacc[(long)cv * H_F + l * 4];
        atomicAdd(zp + 0, acc.x);
        atomicAdd(zp + 1, acc.y);
        atomicAdd(zp + 2, acc.z);
        atomicAdd(zp + 3, acc.w);
    }
}

__global__ __launch_bounds__(256) void heavy_epi(const float* __restrict__ Zacc,
                                                 const float* __restrict__ xpW2,
                                                 const float* __restrict__ di,
                                                 const float* __restrict__ b2,
                                                 const int* __restrict__ heavy,
                                                 const int* __restrict__ heavycnt,
                                                 float* xp2) {
    int hi = blockIdx.x;
    int cnt = *heavycnt; if (cnt > MAXH) cnt = MAXH;
    if (hi >= cnt) return;
    int cv = heavy[hi];
    int j = threadIdx.x;
    float dv = di[cv];
    xp2[(long)cv * H_F + j] =
        dv * (Zacc[(long)cv * H_F + j] + dv * xpW2[(long)cv * H_F + j]) + b2[j];
}

// ---------------- host launch ----------------
static inline size_t align256(size_t x) { return (x + 255) & ~(size_t)255; }

extern "C" void kernel_launch(void* const* d_in, const int* in_sizes, int n_in,
                              void* d_out, int out_size, void* d_ws, size_t ws_size,
                              hipStream_t stream) {
    const float* x      = (const float*)d_in[0];
    const int*   eidx   = (const int*)d_in[1];
    const float* W1     = (const float*)d_in[2];
    const float* b1     = (const float*)d_in[3];
    const float* W2     = (const float*)d_in[4];
    const float* b2     = (const float*)d_in[5];
    const float* wscore = (const float*)d_in[6];
    const float* Wskip  = (const float*)d_in[7];
    const float* bskip  = (const float*)d_in[8];
    float* out = (float*)d_out;

    const int* src = eidx;
    const int* dst = eidx + E_EDGES;

    char* ws = (char*)d_ws;
    size_t off = 0;
    auto alloc = [&](size_t bytes) { char* p = ws + off; off += align256(bytes); return p; };

    float* h     = (float*)alloc((size_t)N_NODES * H_F * 4);
    float* x1    = (float*)alloc((size_t)N_NODES * H_F * 4);
    u16*   x1b   = (u16*)alloc((size_t)N_NODES * H_F * 2);
    float* raw   = (float*)alloc((size_t)N_NODES * 4);
    float* dinv  = (float*)alloc((size_t)N_NODES * 4);
    int*   cntD  = (int*)alloc((size_t)N_NODES * 4);
    int*   degS  = (int*)alloc((size_t)N_NODES * 4);
    int*   keep  = (int*)alloc((size_t)N_NODES * 4);
    int*   cid   = (int*)alloc((size_t)N_NODES * 4);
    unsigned long long* best_enc = (unsigned long long*)alloc((size_t)N_NODES * 8);
    int*   rowptr= (int*)alloc((size_t)(N_NODES + 1) * 4);
    int*   cur   = (int*)alloc((size_t)N_NODES * 4);
    int*   csr   = (int*)alloc((size_t)E_EDGES * 4);
    int*   ccnt  = (int*)alloc((size_t)K_CL * 4);
    int*   cstart= (int*)alloc((size_t)(K_CL + 1) * 4);
    int*   ccur  = (int*)alloc((size_t)K_CL * 4);
    int*   clist = (int*)alloc((size_t)N_NODES * 4);
    int*   bGt   = (int*)alloc((size_t)NB2 * 4);
    int*   bEq   = (int*)alloc((size_t)NB2 * 4);
    int*   gtStart = (int*)alloc((size_t)(NB2 + 1) * 4);
    int*   eqStart = (int*)alloc((size_t)NB2 * 4);
    int*   bsum  = (int*)alloc((size_t)256 * 4);
    int*   bstart= (int*)alloc((size_t)256 * 4);
    char*  small = alloc(64);
    unsigned* selT = (unsigned*)(small + 0);
    int* needEq    = (int*)(small + 4);
    int* bgnode    = (int*)(small + 8);
    int* heavycnt  = (int*)(small + 12);
    unsigned long long* bestpack = (unsigned long long*)(small + 16);
    // xp, Abits, Zacc adjacent -> single memset covers all three
    float* xp    = (float*)alloc((size_t)K_CL * H_F * 4);        // 4 MB
    unsigned* Abits = (unsigned*)alloc((size_t)K_CL * KW * 4);   // 2 MB
    float* Zacc  = (float*)alloc((size_t)K_CL * H_F * 4);        // 4 MB
    float* di    = (float*)alloc((size_t)K_CL * 4);
    int*   nnzA  = (int*)alloc((size_t)K_CL * 4);
    int*   heavy = (int*)alloc((size_t)MAXH * 4);
    float* xpW2  = (float*)alloc((size_t)K_CL * H_F * 4);
    float* xp2   = (float*)alloc((size_t)K_CL * H_F * 4);
    u16*  BpS   = (u16*)alloc((size_t)H_F * OUT_F * 2);
    u16*  Bp2   = (u16*)alloc((size_t)H_F * H_F * 2);
    (void)ws_size; (void)n_in; (void)in_sizes; (void)out_size;

    int nb = NB2;
    int eb = (E_EDGES + 255) / 256;

    // degrees
    init_nodes<<<nb, 256, 0, stream>>>(cntD, degS, best_enc, bgnode, heavycnt, bestpack);
    deg_edges<<<eb, 256, 0, stream>>>(src, dst, cntD, degS);

    // weight packing (both in one launch)
    pack_W2<<<512, 256, 0, stream>>>(Wskip, BpS, W2, Bp2);

    // h = x @ W1 (fp32 — score path must stay exact; bit-identical accumulation order)
    {
        dim3 grid(H_F / SBN, (N_NODES + SBM - 1) / SBM);
        gemm_f32s<<<grid, 256, 0, stream>>>(x, W1, h, N_NODES, H_F, IN_F);
    }

    // CSR by dst: coalesced two-level scan (also emits dinv) + scatter, then aggregation
    scan_l1<<<NB2, 256, 0, stream>>>(cntD, bsum, N_NODES, dinv);
    scan_l2<<<1, 256, 0, stream>>>(bsum, bstart, NB2);
    scan_l3<<<NB2, 256, 0, stream>>>(cntD, bstart, rowptr, cur, N_NODES);
    csr_scatter<<<eb, 256, 0, stream>>>(src, dst, cur, csr);
    agg_fused<<<N_NODES, 256, 0, stream>>>(h, dinv, rowptr, csr, b1, wscore, x1, x1b, raw);

    // top-K: threshold -> multi-block coalesced count/scan/assign
    topk_select<<<1, 1024, 0, stream>>>(raw, selT, needEq);
    topk_count<<<NB2, 256, 0, stream>>>(raw, selT, bGt, bEq);
    scan_blocks<<<1, 256, 0, stream>>>(bGt, bEq, gtStart, eqStart);
    topk_assign<<<NB2, 256, 0, stream>>>(raw, selT, needEq, degS, gtStart, eqStart,
                                         keep, cid, bestpack);
    bg_node<<<nb, 256, 0, stream>>>(keep, degS, raw, bestpack, bgnode);

    // neighbor attachment
    neigh_edges<<<(2 * E_EDGES + 255) / 256, 256, 0, stream>>>(src, dst, keep, degS, best_enc);
    resolve_cid<<<nb, 256, 0, stream>>>(keep, best_enc, bgnode, cid);

    // single memset for xp (4MB) + Abits (2MB) + Zacc (4MB), adjacent in ws
    hipMemsetAsync(xp, 0, (size_t)K_CL * H_F * 4 * 2 + (size_t)K_CL * KW * 4, stream);

    // LDS-aggregated counting sort by cluster, then chunked segmented pooling
    hipMemsetAsync(ccnt, 0, (size_t)K_CL * 4, stream);
    {
        int cb = (N_NODES + NPB - 1) / NPB;
        ccount2<<<cb, 256, 0, stream>>>(cid, ccnt);
        scan_l1<<<K_CL / 256, 256, 0, stream>>>(ccnt, bsum, K_CL, nullptr);
        scan_l2<<<1, 256, 0, stream>>>(bsum, bstart, K_CL / 256);
        scan_l3<<<K_CL / 256, 256, 0, stream>>>(ccnt, bstart, cstart, ccur, K_CL);
        cscatter2<<<cb, 256, 0, stream>>>(cid, ccur, clist);
    }
    pool_chunk<<<(N_NODES + PCH - 1) / PCH, 256, 0, stream>>>(x1, raw, clist, cid, xp);

    // xpW2 = (xp/cnt) @ W2  (bf16 MFMA, in-kernel fp32->bf16 conversion)
    gemm_mfma<<<K_CL / 64, 256, 0, stream>>>(nullptr, xp, ccnt, Bp2, xpW2, K_CL,
                                             nullptr, nullptr, nullptr);

    // bit-packed pooled adjacency + split light/heavy normalized SpMM
    build_Abits<<<eb, 256, 0, stream>>>(src, dst, cid, Abits);
    pop_di2<<<(K_CL + 255) / 256, 256, 0, stream>>>(Abits, di, nnzA, heavy, heavycnt);
    spmm_light<<<K_CL, 256, 0, stream>>>(Abits, xpW2, di, b2, nnzA, xp2);
    {
        dim3 hgrid(MAXH, NSPL);
        spmm_heavy<<<hgrid, 256, 0, stream>>>(Abits, xpW2, di, heavy, heavycnt, Zacc);
    }
    heavy_epi<<<MAXH, 256, 0, stream>>>(Zacc, xpW2, di, b2, heavy, heavycnt, xp2);

    // out = x1@Wskip + xp2[cid] + b_skip  (bf16 MFMA, fused epilogue)
    gemm_mfma<<<(N_NODES + 63) / 64, 256, 0, stream>>>(x1b, nullptr, nullptr, BpS, out,
                                                       N_NODES, cid, xp2, bskip);
}

// Round 15
// 680.629 us; speedup vs baseline: 1.0934x; 1.0598x over previous
//
#include <hip/hip_runtime.h>
#include <hip/hip_bf16.h>

#define N_NODES 50000
#define E_EDGES 300000
#define IN_F 512
#define H_F 256
#define OUT_F 256
#define K_CL 4096
#define KW (K_CL / 32)
#define PCH 128
#define THRESH 192
#define MAXH 1024
#define NSPL 32
#define NB2 ((N_NODES + 255) / 256)
#define KBW ((N_NODES + 63) / 64 + 8)

typedef short bh8 __attribute__((ext_vector_type(8)));
typedef float f4 __attribute__((ext_vector_type(4)));
typedef unsigned short u16;
typedef unsigned long long u64;

__device__ __forceinline__ unsigned fkey(float f) {
    unsigned u = __float_as_uint(f);
    return (u & 0x80000000u) ? ~u : (u | 0x80000000u);
}

__device__ __forceinline__ u16 f2bf(float f) {
    __hip_bfloat16 b = __float2bfloat16(f);
    return *reinterpret_cast<u16*>(&b);
}

__device__ __forceinline__ float bf2f(u16 u) {
    return __uint_as_float(((unsigned)u) << 16);
}

__device__ __forceinline__ int getbit(const u64* __restrict__ bits, int i) {
    return (int)((bits[i >> 6] >> (i & 63)) & 1ULL);
}

// ---------------- init ----------------
__global__ __launch_bounds__(256) void init_nodes(int* cntD, int* degS,
                                                  unsigned long long* best_enc,
                                                  int* bgnode, int* heavycnt,
                                                  unsigned long long* bestpack) {
    int i = blockIdx.x * blockDim.x + threadIdx.x;
    if (i < N_NODES) { cntD[i] = 0; degS[i] = 0; best_enc[i] = 0ULL; }
    if (i == 0) { *heavycnt = 0; *bgnode = 0x7FFFFFFF; *bestpack = 0ULL; }
}

__global__ __launch_bounds__(256) void deg_edges(const int* __restrict__ src,
                                                 const int* __restrict__ dst,
                                                 int* cntD, int* degS) {
    int e = blockIdx.x * blockDim.x + threadIdx.x;
    if (e >= E_EDGES) return;
    atomicAdd(&cntD[dst[e]], 1);
    atomicAdd(&degS[src[e]], 1);
}

// ---- fp32 GEMM (score path): 64x128 tile, dbuf LDS, glds for BOTH A and B ----
#define SBM 64
#define SBN 128
#define SBK 16
__global__ __launch_bounds__(256) void gemm_f32s(const float* __restrict__ A,
                                                 const float* __restrict__ B,
                                                 float* __restrict__ C,
                                                 int M, int Nc, int Kd) {
    __shared__ float As[2][SBM][SBK];
    __shared__ float Bs[2][SBK][SBN];
    int tid = threadIdx.x;
    int tx = tid & 15;
    int ty = tid >> 4;
    int lane = tid & 63;
    int wave = tid >> 6;
    int row0 = blockIdx.y * SBM, col0 = blockIdx.x * SBN;
    float acc[4][8] = {};

    int arow = wave * 16 + (lane >> 2);
    int acolf = ((((lane & 3) * 16) ^ (((lane >> 4) & 1) << 5)) >> 2);

    auto stage_B = [&](int k0, int bb) {
        #pragma unroll
        for (int u = 0; u < 2; ++u) {
            int chunk = wave * 2 + u;
            int krow = chunk * 2 + (lane >> 5);
            const float* gsrc = &B[(long)(k0 + krow) * Nc + col0 + (lane & 31) * 4];
            __builtin_amdgcn_global_load_lds(
                (const __attribute__((address_space(1))) void*)gsrc,
                (__attribute__((address_space(3))) void*)&Bs[bb][chunk * 2][0],
                16, 0, 0);
        }
    };
    auto stage_A = [&](int k0, int bb) {
        int gr = row0 + arow;
        if (gr > M - 1) gr = M - 1;
        const float* gsrc = &A[(long)gr * Kd + k0 + acolf];
        __builtin_amdgcn_global_load_lds(
            (const __attribute__((address_space(1))) void*)gsrc,
            (__attribute__((address_space(3))) void*)&As[bb][wave * 16][0],
            16, 0, 0);
    };
    auto compute = [&](int bb) {
        #pragma unroll
        for (int kq = 0; kq < 4; ++kq) {
            float4 af[4];
            #pragma unroll
            for (int i = 0; i < 4; ++i) {
                int row = ty * 4 + i;
                int cb = ((kq * 16 ^ (((row >> 2) & 1) << 5)) >> 2);
                af[i] = *(const float4*)&As[bb][row][cb];
            }
            #pragma unroll
            for (int kk = 0; kk < 4; ++kk) {
                int k = kq * 4 + kk;
                float4 b0 = *(const float4*)&Bs[bb][k][tx * 4];
                float4 b1 = *(const float4*)&Bs[bb][k][tx * 4 + 64];
                float bv[8] = {b0.x, b0.y, b0.z, b0.w, b1.x, b1.y, b1.z, b1.w};
                float av[4] = {af[0][kk], af[1][kk], af[2][kk], af[3][kk]};
                #pragma unroll
                for (int i = 0; i < 4; ++i)
                    #pragma unroll
                    for (int j = 0; j < 8; ++j)
                        acc[i][j] += av[i] * bv[j];
            }
        }
    };

    stage_B(0, 0);
    stage_A(0, 0);
    __syncthreads();
    int nt = Kd / SBK;
    for (int t = 0; t < nt; ++t) {
        int cb = t & 1;
        if (t + 1 < nt) {
            stage_B(SBK * (t + 1), cb ^ 1);
            stage_A(SBK * (t + 1), cb ^ 1);
        }
        compute(cb);
        __syncthreads();
    }

    #pragma unroll
    for (int i = 0; i < 4; ++i) {
        int gr = row0 + ty * 4 + i;
        if (gr >= M) continue;
        float4 o0 = {acc[i][0], acc[i][1], acc[i][2], acc[i][3]};
        float4 o1 = {acc[i][4], acc[i][5], acc[i][6], acc[i][7]};
        *(float4*)&C[(long)gr * Nc + col0 + tx * 4] = o0;
        *(float4*)&C[(long)gr * Nc + col0 + 64 + tx * 4] = o1;
    }
}

// ---- pack two 256x256 fp32 weights into MFMA-fragment-ordered bf16 (one launch) ----
__global__ __launch_bounds__(256) void pack_W2(const float* __restrict__ Wa, u16* Bpa,
                                               const float* __restrict__ Wb, u16* Bpb) {
    int k = blockIdx.x & 255;
    const float* W = (blockIdx.x < 256) ? Wa : Wb;
    u16* Bp = (blockIdx.x < 256) ? Bpa : Bpb;
    int col = threadIdx.x;
    int kb = k >> 5, g = (k >> 3) & 3, j = k & 7;
    Bp[(((long)(kb * 4 + g) * 256) + col) * 8 + j] = f2bf(W[(long)k * 256 + col]);
}

// ---- bf16 MFMA GEMM: C(Mx256) = A(Mx256) @ Bp(packed) ----
__global__ __launch_bounds__(256) void gemm_mfma(const u16* __restrict__ Ab,
                                                 const float* __restrict__ Af32,
                                                 const int* __restrict__ cnt,
                                                 const u16* __restrict__ Bp,
                                                 float* __restrict__ C,
                                                 int M,
                                                 const int* __restrict__ cid,
                                                 const float* __restrict__ xp2,
                                                 const float* __restrict__ bskip) {
    int tid = threadIdx.x;
    int w = tid >> 6, l = tid & 63;
    int lo16 = l & 15, hi4 = l >> 4;
    int arow = blockIdx.x * 64 + w * 16 + lo16;
    f4 acc[16];
    #pragma unroll
    for (int n = 0; n < 16; ++n) acc[n] = (f4){0.f, 0.f, 0.f, 0.f};

    float s = 1.f;
    if (Af32 && arow < M) s = 1.f / fmaxf((float)cnt[arow], 1.f);

    #pragma unroll
    for (int kb = 0; kb < 8; ++kb) {
        bh8 a = {0, 0, 0, 0, 0, 0, 0, 0};
        if (arow < M) {
            if (Af32) {
                float4 v0 = *(const float4*)&Af32[(long)arow * 256 + kb * 32 + hi4 * 8];
                float4 v1 = *(const float4*)&Af32[(long)arow * 256 + kb * 32 + hi4 * 8 + 4];
                u16 tmp[8] = {f2bf(v0.x * s), f2bf(v0.y * s), f2bf(v0.z * s), f2bf(v0.w * s),
                              f2bf(v1.x * s), f2bf(v1.y * s), f2bf(v1.z * s), f2bf(v1.w * s)};
                a = *(const bh8*)tmp;
            } else {
                a = *(const bh8*)&Ab[(long)arow * 256 + kb * 32 + hi4 * 8];
            }
        }
        const u16* bbase = &Bp[(((long)(kb * 4 + hi4)) * 256 + lo16) * 8];
        #pragma unroll
        for (int n = 0; n < 16; ++n) {
            bh8 b = *(const bh8*)&bbase[(long)n * 128];
            acc[n] = __builtin_amdgcn_mfma_f32_16x16x32_bf16(a, b, acc[n], 0, 0, 0);
        }
    }

    int orow0 = blockIdx.x * 64 + w * 16 + hi4 * 4;
    #pragma unroll
    for (int r = 0; r < 4; ++r) {
        int gr = orow0 + r;
        if (gr >= M) continue;
        long rb = (long)gr * 256;
        const float* xrow = cid ? (xp2 + (long)cid[gr] * 256) : nullptr;
        #pragma unroll
        for (int n = 0; n < 16; ++n) {
            int gc = n * 16 + lo16;
            float v = acc[n][r];
            if (cid) v += xrow[gc] + bskip[gc];
            C[rb + gc] = v;
        }
    }
}

// --------- coalesced two-level exclusive scan (n <= 256*256) ---------
__global__ __launch_bounds__(256) void scan_l1(const int* __restrict__ cnt,
                                               int* bsum, int n, float* dinv) {
    __shared__ int s[256];
    int t = threadIdx.x;
    int i = blockIdx.x * 256 + t;
    int v = (i < n) ? cnt[i] : 0;
    if (dinv && i < n) dinv[i] = rsqrtf((float)v + 1.0f);
    s[t] = v;
    __syncthreads();
    for (int off = 128; off > 0; off >>= 1) {
        if (t < off) s[t] += s[t + off];
        __syncthreads();
    }
    if (t == 0) bsum[blockIdx.x] = s[0];
}

__global__ __launch_bounds__(256) void scan_l2(const int* __restrict__ bsum,
                                               int* bstart, int nb) {
    __shared__ int s[256];
    int t = threadIdx.x;
    int v = (t < nb) ? bsum[t] : 0;
    s[t] = v;
    __syncthreads();
    for (int off = 1; off < 256; off <<= 1) {
        int a = (t >= off) ? s[t - off] : 0;
        __syncthreads();
        s[t] += a;
        __syncthreads();
    }
    if (t < nb) bstart[t] = s[t] - v;
}

__global__ __launch_bounds__(256) void scan_l3(const int* __restrict__ cnt,
                                               const int* __restrict__ bstart,
                                               int* start, int* cur, int n) {
    __shared__ int s[256];
    int t = threadIdx.x;
    int i = blockIdx.x * 256 + t;
    int v = (i < n) ? cnt[i] : 0;
    s[t] = v;
    __syncthreads();
    for (int off = 1; off < 256; off <<= 1) {
        int a = (t >= off) ? s[t - off] : 0;
        __syncthreads();
        s[t] += a;
        __syncthreads();
    }
    int st = bstart[blockIdx.x] + s[t] - v;
    if (i < n) { start[i] = st; cur[i] = st; }
    if (i == n - 1) start[n] = st + v;
}

__global__ __launch_bounds__(256) void csr_scatter(const int* __restrict__ src,
                                                   const int* __restrict__ dst,
                                                   int* cur, int* csr) {
    int e = blockIdx.x * blockDim.x + threadIdx.x;
    if (e >= E_EDGES) return;
    int d = dst[e];
    int p = atomicAdd(&cur[d], 1);
    csr[p] = src[e];
}

// ---- wave-per-node conv1 aggregation + relu + score + bf16 emit (no LDS/barriers) ----
// lane l owns cols {l, l+64, l+128, l+192}. Score reduce reproduces the old LDS
// tree's pairing exactly (t1=r[l]+r[l+128], t2=r[l+64]+r[l+192], then XOR butterfly
// desc 32..1 whose pairs are value-identical by commutativity) -> raw unchanged.
__global__ __launch_bounds__(64) void agg_fused(const float* __restrict__ h,
                                                const float* __restrict__ dinv,
                                                const int* __restrict__ rowptr,
                                                const int* __restrict__ csr,
                                                const float* __restrict__ b1,
                                                const float* __restrict__ w_score,
                                                u16* __restrict__ x1b,
                                                float* __restrict__ raw) {
    int i = blockIdx.x;
    int l = threadIdx.x;
    float di_ = dinv[i];
    long hb = (long)i * H_F;
    float sc = di_ * di_;
    float a0 = sc * h[hb + l];
    float a1 = sc * h[hb + l + 64];
    float a2 = sc * h[hb + l + 128];
    float a3 = sc * h[hb + l + 192];
    int p0 = rowptr[i], p1 = rowptr[i + 1];
    for (int t = p0; t < p1; ++t) {
        int s = csr[t];
        float cf = dinv[s] * di_;
        long sb = (long)s * H_F;
        a0 += cf * h[sb + l];
        a1 += cf * h[sb + l + 64];
        a2 += cf * h[sb + l + 128];
        a3 += cf * h[sb + l + 192];
    }
    float v0 = fmaxf(a0 + b1[l], 0.f);
    float v1 = fmaxf(a1 + b1[l + 64], 0.f);
    float v2 = fmaxf(a2 + b1[l + 128], 0.f);
    float v3 = fmaxf(a3 + b1[l + 192], 0.f);
    x1b[hb + l] = f2bf(v0);
    x1b[hb + l + 64] = f2bf(v1);
    x1b[hb + l + 128] = f2bf(v2);
    x1b[hb + l + 192] = f2bf(v3);
    float r0 = v0 * w_score[l];
    float r1 = v1 * w_score[l + 64];
    float r2 = v2 * w_score[l + 128];
    float r3 = v3 * w_score[l + 192];
    float t1 = r0 + r2;
    float t2 = r1 + r3;
    float s2 = t1 + t2;
    #pragma unroll
    for (int off = 32; off > 0; off >>= 1)
        s2 += __shfl_xor(s2, off, 64);
    if (l == 0) raw[i] = s2;
}

// ---------------- top-K select (single block radix) ----------------
__global__ __launch_bounds__(1024) void topk_select(const float* __restrict__ raw,
                                                    unsigned* outT, int* outNeedEq) {
    __shared__ unsigned hist[256];
    __shared__ unsigned sh_prefix;
    __shared__ int sh_k;
    int tid = threadIdx.x;
    if (tid == 0) { sh_prefix = 0; sh_k = K_CL; }
    __syncthreads();
    for (int byte = 3; byte >= 0; --byte) {
        if (tid < 256) hist[tid] = 0;
        __syncthreads();
        unsigned prefix = sh_prefix;
        unsigned known_mask = (byte == 3) ? 0u : (0xFFFFFFFFu << ((byte + 1) * 8));
        for (int i = tid; i < N_NODES; i += 1024) {
            unsigned key = fkey(raw[i]);
            if ((key & known_mask) == prefix)
                atomicAdd(&hist[(key >> (byte * 8)) & 255], 1u);
        }
        __syncthreads();
        if (tid == 0) {
            int kk = sh_k;
            int cum = 0;
            int v = 255;
            for (; v > 0; --v) {
                int c = (int)hist[v];
                if (cum + c >= kk) break;
                cum += c;
            }
            sh_prefix = prefix | ((unsigned)v << (byte * 8));
            sh_k = kk - cum;
        }
        __syncthreads();
    }
    if (tid == 0) { *outT = sh_prefix; *outNeedEq = sh_k; }
}

// ---------------- multi-block compaction: count -> scan -> assign ----------------
__global__ __launch_bounds__(256) void topk_count(const float* __restrict__ raw,
                                                  const unsigned* pT,
                                                  int* bGt, int* bEq) {
    __shared__ int sg[256], se[256];
    unsigned T = *pT;
    int t = threadIdx.x;
    int i = blockIdx.x * 256 + t;
    int gt = 0, eq = 0;
    if (i < N_NODES) {
        unsigned k = fkey(raw[i]);
        gt = k > T; eq = (k == T);
    }
    sg[t] = gt; se[t] = eq;
    __syncthreads();
    for (int off = 128; off > 0; off >>= 1) {
        if (t < off) { sg[t] += sg[t + off]; se[t] += se[t + off]; }
        __syncthreads();
    }
    if (t == 0) { bGt[blockIdx.x] = sg[0]; bEq[blockIdx.x] = se[0]; }
}

__global__ __launch_bounds__(256) void scan_blocks(const int* __restrict__ bGt,
                                                   const int* __restrict__ bEq,
                                                   int* gtStart, int* eqStart) {
    __shared__ int sg[256], se[256];
    int t = threadIdx.x;
    int vg = (t < NB2) ? bGt[t] : 0;
    int ve = (t < NB2) ? bEq[t] : 0;
    sg[t] = vg; se[t] = ve;
    __syncthreads();
    for (int off = 1; off < 256; off <<= 1) {
        int a = (t >= off) ? sg[t - off] : 0;
        int b = (t >= off) ? se[t - off] : 0;
        __syncthreads();
        sg[t] += a; se[t] += b;
        __syncthreads();
    }
    if (t < NB2) { gtStart[t] = sg[t] - vg; eqStart[t] = se[t] - ve; }
    if (t == 255) gtStart[NB2] = sg[255];   // totalGt
}

__global__ __launch_bounds__(256) void topk_assign(const float* __restrict__ raw,
                                                   const unsigned* pT, const int* pNeedEq,
                                                   const int* __restrict__ degS,
                                                   const int* __restrict__ gtStart,
                                                   const int* __restrict__ eqStart,
                                                   u64* keep_bits, int* cid,
                                                   unsigned long long* bestpack) {
    __shared__ int sg[256], se[256];
    unsigned T = *pT;
    int needEq = *pNeedEq;
    int totalGt = gtStart[NB2];
    int b = blockIdx.x, t = threadIdx.x;
    int i = b * 256 + t;
    int gt = 0, eq = 0;
    unsigned k = 0;
    if (i < N_NODES) {
        k = fkey(raw[i]);
        gt = k > T; eq = (k == T);
    }
    sg[t] = gt; se[t] = eq;
    __syncthreads();
    for (int off = 1; off < 256; off <<= 1) {
        int a = (t >= off) ? sg[t - off] : 0;
        int c = (t >= off) ? se[t - off] : 0;
        __syncthreads();
        sg[t] += a; se[t] += c;
        __syncthreads();
    }
    int eg = sg[t] - gt, ee = se[t] - eq;
    int kp = 0;
    unsigned long long p = 0ULL;
    if (i < N_NODES) {
        int c = -1;
        if (gt) { kp = 1; c = gtStart[b] + eg; }
        else if (eq) {
            int r = eqStart[b] + ee;
            if (r < needEq) { kp = 1; c = totalGt + r; }
        }
        cid[i] = c;
        if (kp) p = ((unsigned long long)(unsigned)degS[i] << 32) | k;
    }
    u64 ball = __ballot(kp);
    if ((t & 63) == 0) keep_bits[(b * 256 + t) >> 6] = ball;
    #pragma unroll
    for (int o = 32; o > 0; o >>= 1) {
        unsigned long long q = __shfl_xor((long long)p, o, 64);
        if (q > p) p = q;
    }
    if ((t & 63) == 0 && p) atomicMax(bestpack, p);
}

__global__ __launch_bounds__(256) void bg_node(const u64* __restrict__ keep_bits,
                                               const int* __restrict__ degS,
                                               const float* __restrict__ raw,
                                               const unsigned long long* bestpack, int* bgnode) {
    int i = blockIdx.x * blockDim.x + threadIdx.x;
    if (i < N_NODES && getbit(keep_bits, i)) {
        unsigned long long p = ((unsigned long long)(unsigned)degS[i] << 32) | fkey(raw[i]);
        if (p == *bestpack) atomicMin(bgnode, i);
    }
}

// ---------------- neighbor attachment (bitmask keep probes, L1-resident) ----------------
__global__ __launch_bounds__(256) void neigh_edges(const int* __restrict__ src,
                                                   const int* __restrict__ dst,
                                                   const u64* __restrict__ keep_bits,
                                                   const int* __restrict__ degS,
                                                   unsigned long long* best_enc) {
    int e = blockIdx.x * blockDim.x + threadIdx.x;
    if (e >= 2 * E_EDGES) return;
    int s, t;
    if (e < E_EDGES) { s = src[e]; t = dst[e]; }
    else { s = dst[e - E_EDGES]; t = src[e - E_EDGES]; }
    if (!getbit(keep_bits, s) && getbit(keep_bits, t)) {
        unsigned long long enc =
            (unsigned long long)((long long)degS[t] * N_NODES + (N_NODES - 1 - t)) + 1ULL;
        atomicMax(&best_enc[s], enc);
    }
}

__global__ __launch_bounds__(256) void resolve_cid(const u64* __restrict__ keep_bits,
                                                   const unsigned long long* __restrict__ best_enc,
                                                   const int* __restrict__ bgnode, int* cid) {
    int i = blockIdx.x * blockDim.x + threadIdx.x;
    if (i >= N_NODES) return;
    if (getbit(keep_bits, i)) return;
    unsigned long long v = best_enc[i];
    if (v > 0ULL) {
        long long enc = (long long)(v - 1ULL);
        int t = (N_NODES - 1) - (int)(enc % N_NODES);
        cid[i] = cid[t];
    } else {
        cid[i] = cid[*bgnode];
    }
}

// ---------------- LDS-aggregated counting sort by cluster ----------------
#define NPB 1024
__global__ __launch_bounds__(256) void ccount2(const int* __restrict__ cid, int* ccnt) {
    __shared__ int hist[K_CL];
    for (int t = threadIdx.x; t < K_CL; t += 256) hist[t] = 0;
    __syncthreads();
    int base = blockIdx.x * NPB;
    #pragma unroll
    for (int u = 0; u < NPB / 256; ++u) {
        int idx = base + u * 256 + threadIdx.x;
        if (idx < N_NODES) atomicAdd(&hist[cid[idx]], 1);
    }
    __syncthreads();
    for (int t = threadIdx.x; t < K_CL; t += 256) {
        int hh = hist[t];
        if (hh) atomicAdd(&ccnt[t], hh);
    }
}

__global__ __launch_bounds__(256) void cscatter2(const int* __restrict__ cid,
                                                 int* ccur, int* clist) {
    __shared__ int hist[K_CL];
    for (int t = threadIdx.x; t < K_CL; t += 256) hist[t] = 0;
    __syncthreads();
    int base = blockIdx.x * NPB;
    int myc[NPB / 256], myr[NPB / 256];
    #pragma unroll
    for (int u = 0; u < NPB / 256; ++u) {
        int idx = base + u * 256 + threadIdx.x;
        if (idx < N_NODES) { myc[u] = cid[idx]; myr[u] = atomicAdd(&hist[myc[u]], 1); }
        else myc[u] = -1;
    }
    __syncthreads();
    for (int t = threadIdx.x; t < K_CL; t += 256) {
        int hh = hist[t];
        if (hh) hist[t] = atomicAdd(&ccur[t], hh);
    }
    __syncthreads();
    #pragma unroll
    for (int u = 0; u < NPB / 256; ++u)
        if (myc[u] >= 0) clist[hist[myc[u]] + myr[u]] = base + u * 256 + threadIdx.x;
}

// ---------------- chunked segmented pooling (bf16 inputs) ----------------
__global__ __launch_bounds__(256) void pool_chunk(const u16* __restrict__ x1b,
                                                  const float* __restrict__ raw,
                                                  const int* __restrict__ clist,
                                                  const int* __restrict__ cid,
                                                  float* xp) {
    __shared__ int s_node[PCH];
    __shared__ int s_c[PCH];
    __shared__ float s_g[PCH];
    int j = threadIdx.x;
    int base = blockIdx.x * PCH;
    int m = N_NODES - base; if (m > PCH) m = PCH;
    for (int t = j; t < m; t += 256) {
        int nd = clist[base + t];
        s_node[t] = nd;
        s_c[t] = cid[nd];
        s_g[t] = tanhf(raw[nd]);
    }
    __syncthreads();
    float acc = 0.f;
    int cprev = s_c[0];
    for (int t = 0; t < m; t += 4) {
        int mm = m - t; if (mm > 4) mm = 4;
        float v[4];
        #pragma unroll
        for (int u = 0; u < 4; ++u)
            if (u < mm) v[u] = bf2f(x1b[(long)s_node[t + u] * H_F + j]);
        #pragma unroll
        for (int u = 0; u < 4; ++u) {
            if (u < mm) {
                int c = s_c[t + u];
                if (c != cprev) {
                    atomicAdd(&xp[(long)cprev * H_F + j], acc);
                    acc = 0.f;
                    cprev = c;
                }
                acc += s_g[t + u] * v[u];
            }
        }
    }
    atomicAdd(&xp[(long)cprev * H_F + j], acc);
}

// ---------------- bit-packed pooled adjacency ----------------
__global__ __launch_bounds__(256) void build_Abits(const int* __restrict__ src,
                                                   const int* __restrict__ dst,
                                                   const int* __restrict__ cid,
                                                   unsigned* Abits) {
    int e = blockIdx.x * blockDim.x + threadIdx.x;
    if (e >= E_EDGES) return;
    int cu = cid[src[e]], cv = cid[dst[e]];
    if (cu != cv) atomicOr(&Abits[(long)cv * KW + (cu >> 5)], 1u << (cu & 31));
}

// di, nnz, and heavy-row compaction
__global__ __launch_bounds__(256) void pop_di2(const unsigned* __restrict__ Abits, float* di,
                                               int* nnzA, int* heavy, int* heavycnt) {
    int i = blockIdx.x * blockDim.x + threadIdx.x;
    if (i >= K_CL) return;
    int c = 0;
    for (int w = 0; w < KW; ++w) c += __popc(Abits[(long)i * KW + w]);
    di[i] = rsqrtf((float)c + 1.0f);
    nnzA[i] = c;
    if (c > THRESH) {
        int p = atomicAdd(heavycnt, 1);
        if (p < MAXH) heavy[p] = i;
    }
}

// light rows (nnz<=THRESH)
__global__ __launch_bounds__(256) void spmm_light(const unsigned* __restrict__ Abits,
                                                  const float* __restrict__ xpW2,
                                                  const float* __restrict__ di,
                                                  const float* __restrict__ b2,
                                                  const int* __restrict__ nnzA,
                                                  float* xp2) {
    __shared__ unsigned s_row[KW];
    __shared__ float s_part[3][256];
    int cv = blockIdx.x;
    if (nnzA[cv] > THRESH) return;
    int tid = threadIdx.x;
    int w = tid >> 6, l = tid & 63;
    if (tid < KW) s_row[tid] = Abits[(long)cv * KW + tid];
    __syncthreads();
    float4 a0 = {0.f, 0.f, 0.f, 0.f}, a1 = {0.f, 0.f, 0.f, 0.f};
    const float4* Y4 = (const float4*)xpW2;
    for (int wi = w * 32; wi < w * 32 + 32; wi += 2) {
        unsigned w0 = s_row[wi], w1 = s_row[wi + 1];
        while (w0 | w1) {
            if (w0) {
                int b = __ffs(w0) - 1; w0 &= w0 - 1;
                int cu = wi * 32 + b;
                float d = di[cu];
                float4 y = Y4[(long)cu * 64 + l];
                a0.x += d * y.x; a0.y += d * y.y; a0.z += d * y.z; a0.w += d * y.w;
            }
            if (w1) {
                int b = __ffs(w1) - 1; w1 &= w1 - 1;
                int cu = (wi + 1) * 32 + b;
                float d = di[cu];
                float4 y = Y4[(long)cu * 64 + l];
                a1.x += d * y.x; a1.y += d * y.y; a1.z += d * y.z; a1.w += d * y.w;
            }
        }
    }
    float4 acc = {a0.x + a1.x, a0.y + a1.y, a0.z + a1.z, a0.w + a1.w};
    if (w > 0) *(float4*)&s_part[w - 1][l * 4] = acc;
    __syncthreads();
    if (w == 0) {
        #pragma unroll
        for (int ww = 0; ww < 3; ++ww) {
            float4 p = *(float4*)&s_part[ww][l * 4];
            acc.x += p.x; acc.y += p.y; acc.z += p.z; acc.w += p.w;
        }
        float dv = di[cv];
        float4 ys = Y4[(long)cv * 64 + l];
        float4 o;
        o.x = dv * (acc.x + dv * ys.x) + b2[l * 4 + 0];
        o.y = dv * (acc.y + dv * ys.y) + b2[l * 4 + 1];
        o.z = dv * (acc.z + dv * ys.z) + b2[l * 4 + 2];
        o.w = dv * (acc.w + dv * ys.w) + b2[l * 4 + 3];
        *(float4*)&xp2[(long)cv * H_F + l * 4] = o;
    }
}

// heavy rows: grid (MAXH, NSPL); block (hi, sp) handles 4 words (1 per wave)
__global__ __launch_bounds__(256) void spmm_heavy(const unsigned* __restrict__ Abits,
                                                  const float* __restrict__ xpW2,
                                                  const float* __restrict__ di,
                                                  const int* __restrict__ heavy,
                                                  const int* __restrict__ heavycnt,
                                                  float* Zacc) {
    __shared__ float s_part[3][256];
    int hi = blockIdx.x;
    int cnt = *heavycnt; if (cnt > MAXH) cnt = MAXH;
    if (hi >= cnt) return;
    int cv = heavy[hi];
    int sp = blockIdx.y;
    int tid = threadIdx.x;
    int w = tid >> 6, l = tid & 63;
    int wi = sp * (KW / NSPL) + w;
    unsigned word = Abits[(long)cv * KW + wi];
    float4 acc = {0.f, 0.f, 0.f, 0.f};
    const float4* Y4 = (const float4*)xpW2;
    while (word) {
        int b = __ffs(word) - 1; word &= word - 1;
        int cu = wi * 32 + b;
        float d = di[cu];
        float4 y = Y4[(long)cu * 64 + l];
        acc.x += d * y.x; acc.y += d * y.y; acc.z += d * y.z; acc.w += d * y.w;
    }
    if (w > 0) *(float4*)&s_part[w - 1][l * 4] = acc;
    __syncthreads();
    if (w == 0) {
        #pragma unroll
        for (int ww = 0; ww < 3; ++ww) {
            float4 p = *(float4*)&s_part[ww][l * 4];
            acc.x += p.x; acc.y += p.y; acc.z += p.z; acc.w += p.w;
        }
        float* zp = &Zacc[(long)cv * H_F + l * 4];
        atomicAdd(zp + 0, acc.x);
        atomicAdd(zp + 1, acc.y);
        atomicAdd(zp + 2, acc.z);
        atomicAdd(zp + 3, acc.w);
    }
}

__global__ __launch_bounds__(256) void heavy_epi(const float* __restrict__ Zacc,
                                                 const float* __restrict__ xpW2,
                                                 const float* __restrict__ di,
                                                 const float* __restrict__ b2,
                                                 const int* __restrict__ heavy,
                                                 const int* __restrict__ heavycnt,
                                                 float* xp2) {
    int hi = blockIdx.x;
    int cnt = *heavycnt; if (cnt > MAXH) cnt = MAXH;
    if (hi >= cnt) return;
    int cv = heavy[hi];
    int j = threadIdx.x;
    float dv = di[cv];
    xp2[(long)cv * H_F + j] =
        dv * (Zacc[(long)cv * H_F + j] + dv * xpW2[(long)cv * H_F + j]) + b2[j];
}

// ---------------- host launch ----------------
static inline size_t align256(size_t x) { return (x + 255) & ~(size_t)255; }

extern "C" void kernel_launch(void* const* d_in, const int* in_sizes, int n_in,
                              void* d_out, int out_size, void* d_ws, size_t ws_size,
                              hipStream_t stream) {
    const float* x      = (const float*)d_in[0];
    const int*   eidx   = (const int*)d_in[1];
    const float* W1     = (const float*)d_in[2];
    const float* b1     = (const float*)d_in[3];
    const float* W2     = (const float*)d_in[4];
    const float* b2     = (const float*)d_in[5];
    const float* wscore = (const float*)d_in[6];
    const float* Wskip  = (const float*)d_in[7];
    const float* bskip  = (const float*)d_in[8];
    float* out = (float*)d_out;

    const int* src = eidx;
    const int* dst = eidx + E_EDGES;

    char* ws = (char*)d_ws;
    size_t off = 0;
    auto alloc = [&](size_t bytes) { char* p = ws + off; off += align256(bytes); return p; };

    float* h     = (float*)alloc((size_t)N_NODES * H_F * 4);
    u16*   x1b   = (u16*)alloc((size_t)N_NODES * H_F * 2);
    float* raw   = (float*)alloc((size_t)N_NODES * 4);
    float* dinv  = (float*)alloc((size_t)N_NODES * 4);
    int*   cntD  = (int*)alloc((size_t)N_NODES * 4);
    int*   degS  = (int*)alloc((size_t)N_NODES * 4);
    u64*   keep_bits = (u64*)alloc((size_t)KBW * 8);
    int*   cid   = (int*)alloc((size_t)N_NODES * 4);
    unsigned long long* best_enc = (unsigned long long*)alloc((size_t)N_NODES * 8);
    int*   rowptr= (int*)alloc((size_t)(N_NODES + 1) * 4);
    int*   cur   = (int*)alloc((size_t)N_NODES * 4);
    int*   csr   = (int*)alloc((size_t)E_EDGES * 4);
    int*   ccnt  = (int*)alloc((size_t)K_CL * 4);
    int*   cstart= (int*)alloc((size_t)(K_CL + 1) * 4);
    int*   ccur  = (int*)alloc((size_t)K_CL * 4);
    int*   clist = (int*)alloc((size_t)N_NODES * 4);
    int*   bGt   = (int*)alloc((size_t)NB2 * 4);
    int*   bEq   = (int*)alloc((size_t)NB2 * 4);
    int*   gtStart = (int*)alloc((size_t)(NB2 + 1) * 4);
    int*   eqStart = (int*)alloc((size_t)NB2 * 4);
    int*   bsum  = (int*)alloc((size_t)256 * 4);
    int*   bstart= (int*)alloc((size_t)256 * 4);
    char*  small = alloc(64);
    unsigned* selT = (unsigned*)(small + 0);
    int* needEq    = (int*)(small + 4);
    int* bgnode    = (int*)(small + 8);
    int* heavycnt  = (int*)(small + 12);
    unsigned long long* bestpack = (unsigned long long*)(small + 16);
    // xp, Abits, Zacc adjacent -> single memset covers all three
    float* xp    = (float*)alloc((size_t)K_CL * H_F * 4);
    unsigned* Abits = (unsigned*)alloc((size_t)K_CL * KW * 4);
    float* Zacc  = (float*)alloc((size_t)K_CL * H_F * 4);
    float* di    = (float*)alloc((size_t)K_CL * 4);
    int*   nnzA  = (int*)alloc((size_t)K_CL * 4);
    int*   heavy = (int*)alloc((size_t)MAXH * 4);
    float* xpW2  = (float*)alloc((size_t)K_CL * H_F * 4);
    float* xp2   = (float*)alloc((size_t)K_CL * H_F * 4);
    u16*  BpS   = (u16*)alloc((size_t)H_F * OUT_F * 2);
    u16*  Bp2   = (u16*)alloc((size_t)H_F * H_F * 2);
    (void)ws_size; (void)n_in; (void)in_sizes; (void)out_size;

    int nb = NB2;
    int eb = (E_EDGES + 255) / 256;

    // degrees
    init_nodes<<<nb, 256, 0, stream>>>(cntD, degS, best_enc, bgnode, heavycnt, bestpack);
    deg_edges<<<eb, 256, 0, stream>>>(src, dst, cntD, degS);

    // weight packing (both in one launch)
    pack_W2<<<512, 256, 0, stream>>>(Wskip, BpS, W2, Bp2);

    // h = x @ W1 (fp32 — score path must stay exact)
    {
        dim3 grid(H_F / SBN, (N_NODES + SBM - 1) / SBM);
        gemm_f32s<<<grid, 256, 0, stream>>>(x, W1, h, N_NODES, H_F, IN_F);
    }

    // CSR by dst: coalesced two-level scan (also emits dinv) + scatter, then aggregation
    scan_l1<<<NB2, 256, 0, stream>>>(cntD, bsum, N_NODES, dinv);
    scan_l2<<<1, 256, 0, stream>>>(bsum, bstart, NB2);
    scan_l3<<<NB2, 256, 0, stream>>>(cntD, bstart, rowptr, cur, N_NODES);
    csr_scatter<<<eb, 256, 0, stream>>>(src, dst, cur, csr);
    agg_fused<<<N_NODES, 64, 0, stream>>>(h, dinv, rowptr, csr, b1, wscore, x1b, raw);

    // top-K: threshold -> multi-block coalesced count/scan/assign (emits keep bitmask)
    topk_select<<<1, 1024, 0, stream>>>(raw, selT, needEq);
    topk_count<<<NB2, 256, 0, stream>>>(raw, selT, bGt, bEq);
    scan_blocks<<<1, 256, 0, stream>>>(bGt, bEq, gtStart, eqStart);
    topk_assign<<<NB2, 256, 0, stream>>>(raw, selT, needEq, degS, gtStart, eqStart,
                                         keep_bits, cid, bestpack);
    bg_node<<<nb, 256, 0, stream>>>(keep_bits, degS, raw, bestpack, bgnode);

    // neighbor attachment
    neigh_edges<<<(2 * E_EDGES + 255) / 256, 256, 0, stream>>>(src, dst, keep_bits, degS,
                                                               best_enc);
    resolve_cid<<<nb, 256, 0, stream>>>(keep_bits, best_enc, bgnode, cid);

    // single memset for xp (4MB) + Abits (2MB) + Zacc (4MB), adjacent in ws
    hipMemsetAsync(xp, 0, (size_t)K_CL * H_F * 4 * 2 + (size_t)K_CL * KW * 4, stream);

    // LDS-aggregated counting sort by cluster, then chunked segmented pooling
    hipMemsetAsync(ccnt, 0, (size_t)K_CL * 4, stream);
    {
        int cb = (N_NODES + NPB - 1) / NPB;
        ccount2<<<cb, 256, 0, stream>>>(cid, ccnt);
        scan_l1<<<K_CL / 256, 256, 0, stream>>>(ccnt, bsum, K_CL, nullptr);
        scan_l2<<<1, 256, 0, stream>>>(bsum, bstart, K_CL / 256);
        scan_l3<<<K_CL / 256, 256, 0, stream>>>(ccnt, bstart, cstart, ccur, K_CL);
        cscatter2<<<cb, 256, 0, stream>>>(cid, ccur, clist);
    }
    pool_chunk<<<(N_NODES + PCH - 1) / PCH, 256, 0, stream>>>(x1b, raw, clist, cid, xp);

    // xpW2 = (xp/cnt) @ W2  (bf16 MFMA, in-kernel fp32->bf16 conversion)
    gemm_mfma<<<K_CL / 64, 256, 0, stream>>>(nullptr, xp, ccnt, Bp2, xpW2, K_CL,
                                             nullptr, nullptr, nullptr);

    // bit-packed pooled adjacency + split light/heavy normalized SpMM
    build_Abits<<<eb, 256, 0, stream>>>(src, dst, cid, Abits);
    pop_di2<<<(K_CL + 255) / 256, 256, 0, stream>>>(Abits, di, nnzA, heavy, heavycnt);
    spmm_light<<<K_CL, 256, 0, stream>>>(Abits, xpW2, di, b2, nnzA, xp2);
    {
        dim3 hgrid(MAXH, NSPL);
        spmm_heavy<<<hgrid, 256, 0, stream>>>(Abits, xpW2, di, heavy, heavycnt, Zacc);
    }
    heavy_epi<<<MAXH, 256, 0, stream>>>(Zacc, xpW2, di, b2, heavy, heavycnt, xp2);

    // out = x1@Wskip + xp2[cid] + b_skip  (bf16 MFMA, fused epilogue)
    gemm_mfma<<<(N_NODES + 63) / 64, 256, 0, stream>>>(x1b, nullptr, nullptr, BpS, out,
                                                       N_NODES, cid, xp2, bskip);
}

// Round 16
// 659.462 us; speedup vs baseline: 1.1285x; 1.0321x over previous
//
#include <hip/hip_runtime.h>
#include <hip/hip_bf16.h>

#define N_NODES 50000
#define E_EDGES 300000
#define IN_F 512
#define H_F 256
#define OUT_F 256
#define K_CL 4096
#define KW (K_CL / 32)
#define PCH 128
#define THRESH 192
#define MAXH 1024
#define NSPL 32
#define NB2 ((N_NODES + 255) / 256)
#define KBW ((N_NODES + 63) / 64 + 8)

typedef short bh8 __attribute__((ext_vector_type(8)));
typedef float f4 __attribute__((ext_vector_type(4)));
typedef unsigned short u16;
typedef unsigned long long u64;

__device__ __forceinline__ unsigned fkey(float f) {
    unsigned u = __float_as_uint(f);
    return (u & 0x80000000u) ? ~u : (u | 0x80000000u);
}

__device__ __forceinline__ u16 f2bf(float f) {
    __hip_bfloat16 b = __float2bfloat16(f);
    return *reinterpret_cast<u16*>(&b);
}

__device__ __forceinline__ float bf2f(u16 u) {
    return __uint_as_float(((unsigned)u) << 16);
}

__device__ __forceinline__ int getbit(const u64* __restrict__ bits, int i) {
    return (int)((bits[i >> 6] >> (i & 63)) & 1ULL);
}

// ---------------- init ----------------
__global__ __launch_bounds__(256) void init_nodes(int* cntD, int* degS,
                                                  unsigned long long* best_enc,
                                                  int* bgnode, int* heavycnt,
                                                  unsigned long long* bestpack,
                                                  unsigned* selT, int* curk) {
    int i = blockIdx.x * blockDim.x + threadIdx.x;
    if (i < N_NODES) { cntD[i] = 0; degS[i] = 0; best_enc[i] = 0ULL; }
    if (i == 0) {
        *heavycnt = 0; *bgnode = 0x7FFFFFFF; *bestpack = 0ULL;
        *selT = 0u; *curk = K_CL;
    }
}

__global__ __launch_bounds__(256) void deg_edges(const int* __restrict__ src,
                                                 const int* __restrict__ dst,
                                                 int* cntD, int* degS) {
    int e = blockIdx.x * blockDim.x + threadIdx.x;
    if (e >= E_EDGES) return;
    atomicAdd(&cntD[dst[e]], 1);
    atomicAdd(&degS[src[e]], 1);
}

// ---- fp32 GEMM (score path): 64x128 tile, dbuf LDS, glds for BOTH A and B ----
#define SBM 64
#define SBN 128
#define SBK 16
__global__ __launch_bounds__(256) void gemm_f32s(const float* __restrict__ A,
                                                 const float* __restrict__ B,
                                                 float* __restrict__ C,
                                                 int M, int Nc, int Kd) {
    __shared__ float As[2][SBM][SBK];
    __shared__ float Bs[2][SBK][SBN];
    int tid = threadIdx.x;
    int tx = tid & 15;
    int ty = tid >> 4;
    int lane = tid & 63;
    int wave = tid >> 6;
    int row0 = blockIdx.y * SBM, col0 = blockIdx.x * SBN;
    float acc[4][8] = {};

    int arow = wave * 16 + (lane >> 2);
    int acolf = ((((lane & 3) * 16) ^ (((lane >> 4) & 1) << 5)) >> 2);

    auto stage_B = [&](int k0, int bb) {
        #pragma unroll
        for (int u = 0; u < 2; ++u) {
            int chunk = wave * 2 + u;
            int krow = chunk * 2 + (lane >> 5);
            const float* gsrc = &B[(long)(k0 + krow) * Nc + col0 + (lane & 31) * 4];
            __builtin_amdgcn_global_load_lds(
                (const __attribute__((address_space(1))) void*)gsrc,
                (__attribute__((address_space(3))) void*)&Bs[bb][chunk * 2][0],
                16, 0, 0);
        }
    };
    auto stage_A = [&](int k0, int bb) {
        int gr = row0 + arow;
        if (gr > M - 1) gr = M - 1;
        const float* gsrc = &A[(long)gr * Kd + k0 + acolf];
        __builtin_amdgcn_global_load_lds(
            (const __attribute__((address_space(1))) void*)gsrc,
            (__attribute__((address_space(3))) void*)&As[bb][wave * 16][0],
            16, 0, 0);
    };
    auto compute = [&](int bb) {
        #pragma unroll
        for (int kq = 0; kq < 4; ++kq) {
            float4 af[4];
            #pragma unroll
            for (int i = 0; i < 4; ++i) {
                int row = ty * 4 + i;
                int cb = ((kq * 16 ^ (((row >> 2) & 1) << 5)) >> 2);
                af[i] = *(const float4*)&As[bb][row][cb];
            }
            #pragma unroll
            for (int kk = 0; kk < 4; ++kk) {
                int k = kq * 4 + kk;
                float4 b0 = *(const float4*)&Bs[bb][k][tx * 4];
                float4 b1 = *(const float4*)&Bs[bb][k][tx * 4 + 64];
                float bv[8] = {b0.x, b0.y, b0.z, b0.w, b1.x, b1.y, b1.z, b1.w};
                float av[4] = {af[0][kk], af[1][kk], af[2][kk], af[3][kk]};
                #pragma unroll
                for (int i = 0; i < 4; ++i)
                    #pragma unroll
                    for (int j = 0; j < 8; ++j)
                        acc[i][j] += av[i] * bv[j];
            }
        }
    };

    stage_B(0, 0);
    stage_A(0, 0);
    __syncthreads();
    int nt = Kd / SBK;
    for (int t = 0; t < nt; ++t) {
        int cb = t & 1;
        if (t + 1 < nt) {
            stage_B(SBK * (t + 1), cb ^ 1);
            stage_A(SBK * (t + 1), cb ^ 1);
        }
        compute(cb);
        __syncthreads();
    }

    #pragma unroll
    for (int i = 0; i < 4; ++i) {
        int gr = row0 + ty * 4 + i;
        if (gr >= M) continue;
        float4 o0 = {acc[i][0], acc[i][1], acc[i][2], acc[i][3]};
        float4 o1 = {acc[i][4], acc[i][5], acc[i][6], acc[i][7]};
        *(float4*)&C[(long)gr * Nc + col0 + tx * 4] = o0;
        *(float4*)&C[(long)gr * Nc + col0 + 64 + tx * 4] = o1;
    }
}

// ---- pack two 256x256 fp32 weights into MFMA-fragment-ordered bf16 (one launch) ----
__global__ __launch_bounds__(256) void pack_W2(const float* __restrict__ Wa, u16* Bpa,
                                               const float* __restrict__ Wb, u16* Bpb) {
    int k = blockIdx.x & 255;
    const float* W = (blockIdx.x < 256) ? Wa : Wb;
    u16* Bp = (blockIdx.x < 256) ? Bpa : Bpb;
    int col = threadIdx.x;
    int kb = k >> 5, g = (k >> 3) & 3, j = k & 7;
    Bp[(((long)(kb * 4 + g) * 256) + col) * 8 + j] = f2bf(W[(long)k * 256 + col]);
}

// ---- bf16 MFMA GEMM: C(Mx256) = A(Mx256) @ Bp(packed) ----
__global__ __launch_bounds__(256) void gemm_mfma(const u16* __restrict__ Ab,
                                                 const float* __restrict__ Af32,
                                                 const int* __restrict__ cnt,
                                                 const u16* __restrict__ Bp,
                                                 float* __restrict__ C,
                                                 int M,
                                                 const int* __restrict__ cid,
                                                 const float* __restrict__ xp2,
                                                 const float* __restrict__ bskip) {
    int tid = threadIdx.x;
    int w = tid >> 6, l = tid & 63;
    int lo16 = l & 15, hi4 = l >> 4;
    int arow = blockIdx.x * 64 + w * 16 + lo16;
    f4 acc[16];
    #pragma unroll
    for (int n = 0; n < 16; ++n) acc[n] = (f4){0.f, 0.f, 0.f, 0.f};

    float s = 1.f;
    if (Af32 && arow < M) s = 1.f / fmaxf((float)cnt[arow], 1.f);

    #pragma unroll
    for (int kb = 0; kb < 8; ++kb) {
        bh8 a = {0, 0, 0, 0, 0, 0, 0, 0};
        if (arow < M) {
            if (Af32) {
                float4 v0 = *(const float4*)&Af32[(long)arow * 256 + kb * 32 + hi4 * 8];
                float4 v1 = *(const float4*)&Af32[(long)arow * 256 + kb * 32 + hi4 * 8 + 4];
                u16 tmp[8] = {f2bf(v0.x * s), f2bf(v0.y * s), f2bf(v0.z * s), f2bf(v0.w * s),
                              f2bf(v1.x * s), f2bf(v1.y * s), f2bf(v1.z * s), f2bf(v1.w * s)};
                a = *(const bh8*)tmp;
            } else {
                a = *(const bh8*)&Ab[(long)arow * 256 + kb * 32 + hi4 * 8];
            }
        }
        const u16* bbase = &Bp[(((long)(kb * 4 + hi4)) * 256 + lo16) * 8];
        #pragma unroll
        for (int n = 0; n < 16; ++n) {
            bh8 b = *(const bh8*)&bbase[(long)n * 128];
            acc[n] = __builtin_amdgcn_mfma_f32_16x16x32_bf16(a, b, acc[n], 0, 0, 0);
        }
    }

    int orow0 = blockIdx.x * 64 + w * 16 + hi4 * 4;
    #pragma unroll
    for (int r = 0; r < 4; ++r) {
        int gr = orow0 + r;
        if (gr >= M) continue;
        long rb = (long)gr * 256;
        const float* xrow = cid ? (xp2 + (long)cid[gr] * 256) : nullptr;
        #pragma unroll
        for (int n = 0; n < 16; ++n) {
            int gc = n * 16 + lo16;
            float v = acc[n][r];
            if (cid) v += xrow[gc] + bskip[gc];
            C[rb + gc] = v;
        }
    }
}

// --------- coalesced two-level exclusive scan (n <= 256*256) ---------
__global__ __launch_bounds__(256) void scan_l1(const int* __restrict__ cnt,
                                               int* bsum, int n, float* dinv) {
    __shared__ int s[256];
    int t = threadIdx.x;
    int i = blockIdx.x * 256 + t;
    int v = (i < n) ? cnt[i] : 0;
    if (dinv && i < n) dinv[i] = rsqrtf((float)v + 1.0f);
    s[t] = v;
    __syncthreads();
    for (int off = 128; off > 0; off >>= 1) {
        if (t < off) s[t] += s[t + off];
        __syncthreads();
    }
    if (t == 0) bsum[blockIdx.x] = s[0];
}

__global__ __launch_bounds__(256) void scan_l2(const int* __restrict__ bsum,
                                               int* bstart, int nb) {
    __shared__ int s[256];
    int t = threadIdx.x;
    int v = (t < nb) ? bsum[t] : 0;
    s[t] = v;
    __syncthreads();
    for (int off = 1; off < 256; off <<= 1) {
        int a = (t >= off) ? s[t - off] : 0;
        __syncthreads();
        s[t] += a;
        __syncthreads();
    }
    if (t < nb) bstart[t] = s[t] - v;
}

__global__ __launch_bounds__(256) void scan_l3(const int* __restrict__ cnt,
                                               const int* __restrict__ bstart,
                                               int* start, int* cur, int n) {
    __shared__ int s[256];
    int t = threadIdx.x;
    int i = blockIdx.x * 256 + t;
    int v = (i < n) ? cnt[i] : 0;
    s[t] = v;
    __syncthreads();
    for (int off = 1; off < 256; off <<= 1) {
        int a = (t >= off) ? s[t - off] : 0;
        __syncthreads();
        s[t] += a;
        __syncthreads();
    }
    int st = bstart[blockIdx.x] + s[t] - v;
    if (i < n) { start[i] = st; cur[i] = st; }
    if (i == n - 1) start[n] = st + v;
}

__global__ __launch_bounds__(256) void csr_scatter(const int* __restrict__ src,
                                                   const int* __restrict__ dst,
                                                   int* cur, int* csr) {
    int e = blockIdx.x * blockDim.x + threadIdx.x;
    if (e >= E_EDGES) return;
    int d = dst[e];
    int p = atomicAdd(&cur[d], 1);
    csr[p] = src[e];
}

// ---- wave-per-node conv1 aggregation + relu + score + bf16 emit (no LDS/barriers) ----
__global__ __launch_bounds__(64) void agg_fused(const float* __restrict__ h,
                                                const float* __restrict__ dinv,
                                                const int* __restrict__ rowptr,
                                                const int* __restrict__ csr,
                                                const float* __restrict__ b1,
                                                const float* __restrict__ w_score,
                                                u16* __restrict__ x1b,
                                                float* __restrict__ raw) {
    int i = blockIdx.x;
    int l = threadIdx.x;
    float di_ = dinv[i];
    long hb = (long)i * H_F;
    float sc = di_ * di_;
    float a0 = sc * h[hb + l];
    float a1 = sc * h[hb + l + 64];
    float a2 = sc * h[hb + l + 128];
    float a3 = sc * h[hb + l + 192];
    int p0 = rowptr[i], p1 = rowptr[i + 1];
    for (int t = p0; t < p1; ++t) {
        int s = csr[t];
        float cf = dinv[s] * di_;
        long sb = (long)s * H_F;
        a0 += cf * h[sb + l];
        a1 += cf * h[sb + l + 64];
        a2 += cf * h[sb + l + 128];
        a3 += cf * h[sb + l + 192];
    }
    float v0 = fmaxf(a0 + b1[l], 0.f);
    float v1 = fmaxf(a1 + b1[l + 64], 0.f);
    float v2 = fmaxf(a2 + b1[l + 128], 0.f);
    float v3 = fmaxf(a3 + b1[l + 192], 0.f);
    x1b[hb + l] = f2bf(v0);
    x1b[hb + l + 64] = f2bf(v1);
    x1b[hb + l + 128] = f2bf(v2);
    x1b[hb + l + 192] = f2bf(v3);
    float r0 = v0 * w_score[l];
    float r1 = v1 * w_score[l + 64];
    float r2 = v2 * w_score[l + 128];
    float r3 = v3 * w_score[l + 192];
    float t1 = r0 + r2;
    float t2 = r1 + r3;
    float s2 = t1 + t2;
    #pragma unroll
    for (int off = 32; off > 0; off >>= 1)
        s2 += __shfl_xor(s2, off, 64);
    if (l == 0) raw[i] = s2;
}

// ------- multi-block radix select: per-pass hist (196 blocks) + tiny pick -------
// Same integer counting as the old single-block topk_select -> bit-identical T/needEq.
__global__ __launch_bounds__(256) void radix_hist(const float* __restrict__ raw,
                                                  const unsigned* __restrict__ pPrefix,
                                                  int byte, int* hist) {
    __shared__ int lh[256];
    int t = threadIdx.x;
    lh[t] = 0;
    __syncthreads();
    int i = blockIdx.x * 256 + t;
    if (i < N_NODES) {
        unsigned key = fkey(raw[i]);
        unsigned known_mask = (byte == 3) ? 0u : (0xFFFFFFFFu << ((byte + 1) * 8));
        if ((key & known_mask) == *pPrefix)
            atomicAdd(&lh[(key >> (byte * 8)) & 255], 1);
    }
    __syncthreads();
    int hh = lh[t];
    if (hh) atomicAdd(&hist[t], hh);
}

__global__ __launch_bounds__(64) void radix_pick(const int* __restrict__ hist,
                                                 unsigned* pPrefix, int* pK, int byte) {
    if (threadIdx.x != 0) return;
    int kk = *pK;
    int cum = 0;
    int v = 255;
    for (; v > 0; --v) {
        int c = hist[v];
        if (cum + c >= kk) break;
        cum += c;
    }
    *pPrefix |= ((unsigned)v) << (byte * 8);
    *pK = kk - cum;
}

// ---------------- multi-block compaction: count -> scan -> assign ----------------
__global__ __launch_bounds__(256) void topk_count(const float* __restrict__ raw,
                                                  const unsigned* pT,
                                                  int* bGt, int* bEq) {
    __shared__ int sg[256], se[256];
    unsigned T = *pT;
    int t = threadIdx.x;
    int i = blockIdx.x * 256 + t;
    int gt = 0, eq = 0;
    if (i < N_NODES) {
        unsigned k = fkey(raw[i]);
        gt = k > T; eq = (k == T);
    }
    sg[t] = gt; se[t] = eq;
    __syncthreads();
    for (int off = 128; off > 0; off >>= 1) {
        if (t < off) { sg[t] += sg[t + off]; se[t] += se[t + off]; }
        __syncthreads();
    }
    if (t == 0) { bGt[blockIdx.x] = sg[0]; bEq[blockIdx.x] = se[0]; }
}

__global__ __launch_bounds__(256) void scan_blocks(const int* __restrict__ bGt,
                                                   const int* __restrict__ bEq,
                                                   int* gtStart, int* eqStart) {
    __shared__ int sg[256], se[256];
    int t = threadIdx.x;
    int vg = (t < NB2) ? bGt[t] : 0;
    int ve = (t < NB2) ? bEq[t] : 0;
    sg[t] = vg; se[t] = ve;
    __syncthreads();
    for (int off = 1; off < 256; off <<= 1) {
        int a = (t >= off) ? sg[t - off] : 0;
        int b = (t >= off) ? se[t - off] : 0;
        __syncthreads();
        sg[t] += a; se[t] += b;
        __syncthreads();
    }
    if (t < NB2) { gtStart[t] = sg[t] - vg; eqStart[t] = se[t] - ve; }
    if (t == 255) gtStart[NB2] = sg[255];   // totalGt
}

__global__ __launch_bounds__(256) void topk_assign(const float* __restrict__ raw,
                                                   const unsigned* pT, const int* pNeedEq,
                                                   const int* __restrict__ degS,
                                                   const int* __restrict__ gtStart,
                                                   const int* __restrict__ eqStart,
                                                   u64* keep_bits, int* cid,
                                                   unsigned long long* bestpack) {
    __shared__ int sg[256], se[256];
    unsigned T = *pT;
    int needEq = *pNeedEq;
    int totalGt = gtStart[NB2];
    int b = blockIdx.x, t = threadIdx.x;
    int i = b * 256 + t;
    int gt = 0, eq = 0;
    unsigned k = 0;
    if (i < N_NODES) {
        k = fkey(raw[i]);
        gt = k > T; eq = (k == T);
    }
    sg[t] = gt; se[t] = eq;
    __syncthreads();
    for (int off = 1; off < 256; off <<= 1) {
        int a = (t >= off) ? sg[t - off] : 0;
        int c = (t >= off) ? se[t - off] : 0;
        __syncthreads();
        sg[t] += a; se[t] += c;
        __syncthreads();
    }
    int eg = sg[t] - gt, ee = se[t] - eq;
    int kp = 0;
    unsigned long long p = 0ULL;
    if (i < N_NODES) {
        int c = -1;
        if (gt) { kp = 1; c = gtStart[b] + eg; }
        else if (eq) {
            int r = eqStart[b] + ee;
            if (r < needEq) { kp = 1; c = totalGt + r; }
        }
        cid[i] = c;
        if (kp) p = ((unsigned long long)(unsigned)degS[i] << 32) | k;
    }
    u64 ball = __ballot(kp);
    if ((t & 63) == 0) keep_bits[(b * 256 + t) >> 6] = ball;
    #pragma unroll
    for (int o = 32; o > 0; o >>= 1) {
        unsigned long long q = __shfl_xor((long long)p, o, 64);
        if (q > p) p = q;
    }
    if ((t & 63) == 0 && p) atomicMax(bestpack, p);
}

__global__ __launch_bounds__(256) void bg_node(const u64* __restrict__ keep_bits,
                                               const int* __restrict__ degS,
                                               const float* __restrict__ raw,
                                               const unsigned long long* bestpack, int* bgnode) {
    int i = blockIdx.x * blockDim.x + threadIdx.x;
    if (i < N_NODES && getbit(keep_bits, i)) {
        unsigned long long p = ((unsigned long long)(unsigned)degS[i] << 32) | fkey(raw[i]);
        if (p == *bestpack) atomicMin(bgnode, i);
    }
}

// ---------------- neighbor attachment (bitmask keep probes) ----------------
__global__ __launch_bounds__(256) void neigh_edges(const int* __restrict__ src,
                                                   const int* __restrict__ dst,
                                                   const u64* __restrict__ keep_bits,
                                                   const int* __restrict__ degS,
                                                   unsigned long long* best_enc) {
    int e = blockIdx.x * blockDim.x + threadIdx.x;
    if (e >= 2 * E_EDGES) return;
    int s, t;
    if (e < E_EDGES) { s = src[e]; t = dst[e]; }
    else { s = dst[e - E_EDGES]; t = src[e - E_EDGES]; }
    if (!getbit(keep_bits, s) && getbit(keep_bits, t)) {
        unsigned long long enc =
            (unsigned long long)((long long)degS[t] * N_NODES + (N_NODES - 1 - t)) + 1ULL;
        atomicMax(&best_enc[s], enc);
    }
}

__global__ __launch_bounds__(256) void resolve_cid(const u64* __restrict__ keep_bits,
                                                   const unsigned long long* __restrict__ best_enc,
                                                   const int* __restrict__ bgnode, int* cid) {
    int i = blockIdx.x * blockDim.x + threadIdx.x;
    if (i >= N_NODES) return;
    if (getbit(keep_bits, i)) return;
    unsigned long long v = best_enc[i];
    if (v > 0ULL) {
        long long enc = (long long)(v - 1ULL);
        int t = (N_NODES - 1) - (int)(enc % N_NODES);
        cid[i] = cid[t];
    } else {
        cid[i] = cid[*bgnode];
    }
}

// ---------------- LDS-aggregated counting sort by cluster ----------------
#define NPB 1024
__global__ __launch_bounds__(256) void ccount2(const int* __restrict__ cid, int* ccnt) {
    __shared__ int hist[K_CL];
    for (int t = threadIdx.x; t < K_CL; t += 256) hist[t] = 0;
    __syncthreads();
    int base = blockIdx.x * NPB;
    #pragma unroll
    for (int u = 0; u < NPB / 256; ++u) {
        int idx = base + u * 256 + threadIdx.x;
        if (idx < N_NODES) atomicAdd(&hist[cid[idx]], 1);
    }
    __syncthreads();
    for (int t = threadIdx.x; t < K_CL; t += 256) {
        int hh = hist[t];
        if (hh) atomicAdd(&ccnt[t], hh);
    }
}

__global__ __launch_bounds__(256) void cscatter2(const int* __restrict__ cid,
                                                 int* ccur, int* clist) {
    __shared__ int hist[K_CL];
    for (int t = threadIdx.x; t < K_CL; t += 256) hist[t] = 0;
    __syncthreads();
    int base = blockIdx.x * NPB;
    int myc[NPB / 256], myr[NPB / 256];
    #pragma unroll
    for (int u = 0; u < NPB / 256; ++u) {
        int idx = base + u * 256 + threadIdx.x;
        if (idx < N_NODES) { myc[u] = cid[idx]; myr[u] = atomicAdd(&hist[myc[u]], 1); }
        else myc[u] = -1;
    }
    __syncthreads();
    for (int t = threadIdx.x; t < K_CL; t += 256) {
        int hh = hist[t];
        if (hh) hist[t] = atomicAdd(&ccur[t], hh);
    }
    __syncthreads();
    #pragma unroll
    for (int u = 0; u < NPB / 256; ++u)
        if (myc[u] >= 0) clist[hist[myc[u]] + myr[u]] = base + u * 256 + threadIdx.x;
}

// ---------------- chunked segmented pooling (bf16 inputs) ----------------
__global__ __launch_bounds__(256) void pool_chunk(const u16* __restrict__ x1b,
                                                  const float* __restrict__ raw,
                                                  const int* __restrict__ clist,
                                                  const int* __restrict__ cid,
                                                  float* xp) {
    __shared__ int s_node[PCH];
    __shared__ int s_c[PCH];
    __shared__ float s_g[PCH];
    int j = threadIdx.x;
    int base = blockIdx.x * PCH;
    int m = N_NODES - base; if (m > PCH) m = PCH;
    for (int t = j; t < m; t += 256) {
        int nd = clist[base + t];
        s_node[t] = nd;
        s_c[t] = cid[nd];
        s_g[t] = tanhf(raw[nd]);
    }
    __syncthreads();
    float acc = 0.f;
    int cprev = s_c[0];
    for (int t = 0; t < m; t += 4) {
        int mm = m - t; if (mm > 4) mm = 4;
        float v[4];
        #pragma unroll
        for (int u = 0; u < 4; ++u)
            if (u < mm) v[u] = bf2f(x1b[(long)s_node[t + u] * H_F + j]);
        #pragma unroll
        for (int u = 0; u < 4; ++u) {
            if (u < mm) {
                int c = s_c[t + u];
                if (c != cprev) {
                    atomicAdd(&xp[(long)cprev * H_F + j], acc);
                    acc = 0.f;
                    cprev = c;
                }
                acc += s_g[t + u] * v[u];
            }
        }
    }
    atomicAdd(&xp[(long)cprev * H_F + j], acc);
}

// ---------------- bit-packed pooled adjacency ----------------
__global__ __launch_bounds__(256) void build_Abits(const int* __restrict__ src,
                                                   const int* __restrict__ dst,
                                                   const int* __restrict__ cid,
                                                   unsigned* Abits) {
    int e = blockIdx.x * blockDim.x + threadIdx.x;
    if (e >= E_EDGES) return;
    int cu = cid[src[e]], cv = cid[dst[e]];
    if (cu != cv) atomicOr(&Abits[(long)cv * KW + (cu >> 5)], 1u << (cu & 31));
}

// di, nnz, and heavy-row compaction
__global__ __launch_bounds__(256) void pop_di2(const unsigned* __restrict__ Abits, float* di,
                                               int* nnzA, int* heavy, int* heavycnt) {
    int i = blockIdx.x * blockDim.x + threadIdx.x;
    if (i >= K_CL) return;
    int c = 0;
    for (int w = 0; w < KW; ++w) c += __popc(Abits[(long)i * KW + w]);
    di[i] = rsqrtf((float)c + 1.0f);
    nnzA[i] = c;
    if (c > THRESH) {
        int p = atomicAdd(heavycnt, 1);
        if (p < MAXH) heavy[p] = i;
    }
}

// light rows (nnz<=THRESH)
__global__ __launch_bounds__(256) void spmm_light(const unsigned* __restrict__ Abits,
                                                  const float* __restrict__ xpW2,
                                                  const float* __restrict__ di,
                                                  const float* __restrict__ b2,
                                                  const int* __restrict__ nnzA,
                                                  float* xp2) {
    __shared__ unsigned s_row[KW];
    __shared__ float s_part[3][256];
    int cv = blockIdx.x;
    if (nnzA[cv] > THRESH) return;
    int tid = threadIdx.x;
    int w = tid >> 6, l = tid & 63;
    if (tid < KW) s_row[tid] = Abits[(long)cv * KW + tid];
    __syncthreads();
    float4 a0 = {0.f, 0.f, 0.f, 0.f}, a1 = {0.f, 0.f, 0.f, 0.f};
    const float4* Y4 = (const float4*)xpW2;
    for (int wi = w * 32; wi < w * 32 + 32; wi += 2) {
        unsigned w0 = s_row[wi], w1 = s_row[wi + 1];
        while (w0 | w1) {
            if (w0) {
                int b = __ffs(w0) - 1; w0 &= w0 - 1;
                int cu = wi * 32 + b;
                float d = di[cu];
                float4 y = Y4[(long)cu * 64 + l];
                a0.x += d * y.x; a0.y += d * y.y; a0.z += d * y.z; a0.w += d * y.w;
            }
            if (w1) {
                int b = __ffs(w1) - 1; w1 &= w1 - 1;
                int cu = (wi + 1) * 32 + b;
                float d = di[cu];
                float4 y = Y4[(long)cu * 64 + l];
                a1.x += d * y.x; a1.y += d * y.y; a1.z += d * y.z; a1.w += d * y.w;
            }
        }
    }
    float4 acc = {a0.x + a1.x, a0.y + a1.y, a0.z + a1.z, a0.w + a1.w};
    if (w > 0) *(float4*)&s_part[w - 1][l * 4] = acc;
    __syncthreads();
    if (w == 0) {
        #pragma unroll
        for (int ww = 0; ww < 3; ++ww) {
            float4 p = *(float4*)&s_part[ww][l * 4];
            acc.x += p.x; acc.y += p.y; acc.z += p.z; acc.w += p.w;
        }
        float dv = di[cv];
        float4 ys = Y4[(long)cv * 64 + l];
        float4 o;
        o.x = dv * (acc.x + dv * ys.x) + b2[l * 4 + 0];
        o.y = dv * (acc.y + dv * ys.y) + b2[l * 4 + 1];
        o.z = dv * (acc.z + dv * ys.z) + b2[l * 4 + 2];
        o.w = dv * (acc.w + dv * ys.w) + b2[l * 4 + 3];
        *(float4*)&xp2[(long)cv * H_F + l * 4] = o;
    }
}

// heavy rows: grid (MAXH, NSPL); block (hi, sp) handles 4 words (1 per wave)
__global__ __launch_bounds__(256) void spmm_heavy(const unsigned* __restrict__ Abits,
                                                  const float* __restrict__ xpW2,
                                                  const float* __restrict__ di,
                                                  const int* __restrict__ heavy,
                                                  const int* __restrict__ heavycnt,
                                                  float* Zacc) {
    __shared__ float s_part[3][256];
    int hi = blockIdx.x;
    int cnt = *heavycnt; if (cnt > MAXH) cnt = MAXH;
    if (hi >= cnt) return;
    int cv = heavy[hi];
    int sp = blockIdx.y;
    int tid = threadIdx.x;
    int w = tid >> 6, l = tid & 63;
    int wi = sp * (KW / NSPL) + w;
    unsigned word = Abits[(long)cv * KW + wi];
    float4 acc = {0.f, 0.f, 0.f, 0.f};
    const float4* Y4 = (const float4*)xpW2;
    while (word) {
        int b = __ffs(word) - 1; word &= word - 1;
        int cu = wi * 32 + b;
        float d = di[cu];
        float4 y = Y4[(long)cu * 64 + l];
        acc.x += d * y.x; acc.y += d * y.y; acc.z += d * y.z; acc.w += d * y.w;
    }
    if (w > 0) *(float4*)&s_part[w - 1][l * 4] = acc;
    __syncthreads();
    if (w == 0) {
        #pragma unroll
        for (int ww = 0; ww < 3; ++ww) {
            float4 p = *(float4*)&s_part[ww][l * 4];
            acc.x += p.x; acc.y += p.y; acc.z += p.z; acc.w += p.w;
        }
        float* zp = &Zacc[(long)cv * H_F + l * 4];
        atomicAdd(zp + 0, acc.x);
        atomicAdd(zp + 1, acc.y);
        atomicAdd(zp + 2, acc.z);
        atomicAdd(zp + 3, acc.w);
    }
}

__global__ __launch_bounds__(256) void heavy_epi(const float* __restrict__ Zacc,
                                                 const float* __restrict__ xpW2,
                                                 const float* __restrict__ di,
                                                 const float* __restrict__ b2,
                                                 const int* __restrict__ heavy,
                                                 const int* __restrict__ heavycnt,
                                                 float* xp2) {
    int hi = blockIdx.x;
    int cnt = *heavycnt; if (cnt > MAXH) cnt = MAXH;
    if (hi >= cnt) return;
    int cv = heavy[hi];
    int j = threadIdx.x;
    float dv = di[cv];
    xp2[(long)cv * H_F + j] =
        dv * (Zacc[(long)cv * H_F + j] + dv * xpW2[(long)cv * H_F + j]) + b2[j];
}

// ---------------- host launch ----------------
static inline size_t align256(size_t x) { return (x + 255) & ~(size_t)255; }

extern "C" void kernel_launch(void* const* d_in, const int* in_sizes, int n_in,
                              void* d_out, int out_size, void* d_ws, size_t ws_size,
                              hipStream_t stream) {
    const float* x      = (const float*)d_in[0];
    const int*   eidx   = (const int*)d_in[1];
    const float* W1     = (const float*)d_in[2];
    const float* b1     = (const float*)d_in[3];
    const float* W2     = (const float*)d_in[4];
    const float* b2     = (const float*)d_in[5];
    const float* wscore = (const float*)d_in[6];
    const float* Wskip  = (const float*)d_in[7];
    const float* bskip  = (const float*)d_in[8];
    float* out = (float*)d_out;

    const int* src = eidx;
    const int* dst = eidx + E_EDGES;

    char* ws = (char*)d_ws;
    size_t off = 0;
    auto alloc = [&](size_t bytes) { char* p = ws + off; off += align256(bytes); return p; };

    float* h     = (float*)alloc((size_t)N_NODES * H_F * 4);
    u16*   x1b   = (u16*)alloc((size_t)N_NODES * H_F * 2);
    float* raw   = (float*)alloc((size_t)N_NODES * 4);
    float* dinv  = (float*)alloc((size_t)N_NODES * 4);
    int*   cntD  = (int*)alloc((size_t)N_NODES * 4);
    int*   degS  = (int*)alloc((size_t)N_NODES * 4);
    u64*   keep_bits = (u64*)alloc((size_t)KBW * 8);
    int*   cid   = (int*)alloc((size_t)N_NODES * 4);
    unsigned long long* best_enc = (unsigned long long*)alloc((size_t)N_NODES * 8);
    int*   rowptr= (int*)alloc((size_t)(N_NODES + 1) * 4);
    int*   cur   = (int*)alloc((size_t)N_NODES * 4);
    int*   csr   = (int*)alloc((size_t)E_EDGES * 4);
    int*   ccnt  = (int*)alloc((size_t)K_CL * 4);
    int*   cstart= (int*)alloc((size_t)(K_CL + 1) * 4);
    int*   ccur  = (int*)alloc((size_t)K_CL * 4);
    int*   clist = (int*)alloc((size_t)N_NODES * 4);
    int*   bGt   = (int*)alloc((size_t)NB2 * 4);
    int*   bEq   = (int*)alloc((size_t)NB2 * 4);
    int*   gtStart = (int*)alloc((size_t)(NB2 + 1) * 4);
    int*   eqStart = (int*)alloc((size_t)NB2 * 4);
    int*   bsum  = (int*)alloc((size_t)256 * 4);
    int*   bstart= (int*)alloc((size_t)256 * 4);
    int*   hist4 = (int*)alloc((size_t)4 * 256 * 4);
    char*  small = alloc(64);
    unsigned* selT = (unsigned*)(small + 0);
    int* needEq    = (int*)(small + 4);
    int* bgnode    = (int*)(small + 8);
    int* heavycnt  = (int*)(small + 12);
    unsigned long long* bestpack = (unsigned long long*)(small + 16);
    // xp, Abits, Zacc adjacent -> single memset covers all three
    float* xp    = (float*)alloc((size_t)K_CL * H_F * 4);
    unsigned* Abits = (unsigned*)alloc((size_t)K_CL * KW * 4);
    float* Zacc  = (float*)alloc((size_t)K_CL * H_F * 4);
    float* di    = (float*)alloc((size_t)K_CL * 4);
    int*   nnzA  = (int*)alloc((size_t)K_CL * 4);
    int*   heavy = (int*)alloc((size_t)MAXH * 4);
    float* xpW2  = (float*)alloc((size_t)K_CL * H_F * 4);
    float* xp2   = (float*)alloc((size_t)K_CL * H_F * 4);
    u16*  BpS   = (u16*)alloc((size_t)H_F * OUT_F * 2);
    u16*  Bp2   = (u16*)alloc((size_t)H_F * H_F * 2);
    (void)ws_size; (void)n_in; (void)in_sizes; (void)out_size;

    int nb = NB2;
    int eb = (E_EDGES + 255) / 256;

    // degrees + small-state init
    init_nodes<<<nb, 256, 0, stream>>>(cntD, degS, best_enc, bgnode, heavycnt, bestpack,
                                       selT, needEq);
    deg_edges<<<eb, 256, 0, stream>>>(src, dst, cntD, degS);
    hipMemsetAsync(hist4, 0, 4 * 256 * 4, stream);

    // weight packing (both in one launch)
    pack_W2<<<512, 256, 0, stream>>>(Wskip, BpS, W2, Bp2);

    // h = x @ W1 (fp32 — score path must stay exact)
    {
        dim3 grid(H_F / SBN, (N_NODES + SBM - 1) / SBM);
        gemm_f32s<<<grid, 256, 0, stream>>>(x, W1, h, N_NODES, H_F, IN_F);
    }

    // CSR by dst: coalesced two-level scan (also emits dinv) + scatter, then aggregation
    scan_l1<<<NB2, 256, 0, stream>>>(cntD, bsum, N_NODES, dinv);
    scan_l2<<<1, 256, 0, stream>>>(bsum, bstart, NB2);
    scan_l3<<<NB2, 256, 0, stream>>>(cntD, bstart, rowptr, cur, N_NODES);
    csr_scatter<<<eb, 256, 0, stream>>>(src, dst, cur, csr);
    agg_fused<<<N_NODES, 64, 0, stream>>>(h, dinv, rowptr, csr, b1, wscore, x1b, raw);

    // top-K threshold: multi-block radix (4 passes, bit-identical to old topk_select)
    for (int b = 3; b >= 0; --b) {
        radix_hist<<<NB2, 256, 0, stream>>>(raw, selT, b, hist4 + b * 256);
        radix_pick<<<1, 64, 0, stream>>>(hist4 + b * 256, selT, needEq, b);
    }
    topk_count<<<NB2, 256, 0, stream>>>(raw, selT, bGt, bEq);
    scan_blocks<<<1, 256, 0, stream>>>(bGt, bEq, gtStart, eqStart);
    topk_assign<<<NB2, 256, 0, stream>>>(raw, selT, needEq, degS, gtStart, eqStart,
                                         keep_bits, cid, bestpack);
    bg_node<<<nb, 256, 0, stream>>>(keep_bits, degS, raw, bestpack, bgnode);

    // neighbor attachment
    neigh_edges<<<(2 * E_EDGES + 255) / 256, 256, 0, stream>>>(src, dst, keep_bits, degS,
                                                               best_enc);
    resolve_cid<<<nb, 256, 0, stream>>>(keep_bits, best_enc, bgnode, cid);

    // single memset for xp (4MB) + Abits (2MB) + Zacc (4MB), adjacent in ws
    hipMemsetAsync(xp, 0, (size_t)K_CL * H_F * 4 * 2 + (size_t)K_CL * KW * 4, stream);

    // LDS-aggregated counting sort by cluster, then chunked segmented pooling
    hipMemsetAsync(ccnt, 0, (size_t)K_CL * 4, stream);
    {
        int cb = (N_NODES + NPB - 1) / NPB;
        ccount2<<<cb, 256, 0, stream>>>(cid, ccnt);
        scan_l1<<<K_CL / 256, 256, 0, stream>>>(ccnt, bsum, K_CL, nullptr);
        scan_l2<<<1, 256, 0, stream>>>(bsum, bstart, K_CL / 256);
        scan_l3<<<K_CL / 256, 256, 0, stream>>>(ccnt, bstart, cstart, ccur, K_CL);
        cscatter2<<<cb, 256, 0, stream>>>(cid, ccur, clist);
    }
    pool_chunk<<<(N_NODES + PCH - 1) / PCH, 256, 0, stream>>>(x1b, raw, clist, cid, xp);

    // xpW2 = (xp/cnt) @ W2  (bf16 MFMA, in-kernel fp32->bf16 conversion)
    gemm_mfma<<<K_CL / 64, 256, 0, stream>>>(nullptr, xp, ccnt, Bp2, xpW2, K_CL,
                                             nullptr, nullptr, nullptr);

    // bit-packed pooled adjacency + split light/heavy normalized SpMM
    build_Abits<<<eb, 256, 0, stream>>>(src, dst, cid, Abits);
    pop_di2<<<(K_CL + 255) / 256, 256, 0, stream>>>(Abits, di, nnzA, heavy, heavycnt);
    spmm_light<<<K_CL, 256, 0, stream>>>(Abits, xpW2, di, b2, nnzA, xp2);
    {
        dim3 hgrid(MAXH, NSPL);
        spmm_heavy<<<hgrid, 256, 0, stream>>>(Abits, xpW2, di, heavy, heavycnt, Zacc);
    }
    heavy_epi<<<MAXH, 256, 0, stream>>>(Zacc, xpW2, di, b2, heavy, heavycnt, xp2);

    // out = x1@Wskip + xp2[cid] + b_skip  (bf16 MFMA, fused epilogue)
    gemm_mfma<<<(N_NODES + 63) / 64, 256, 0, stream>>>(x1b, nullptr, nullptr, BpS, out,
                                                       N_NODES, cid, xp2, bskip);
}

// Round 17
// 657.413 us; speedup vs baseline: 1.1320x; 1.0031x over previous
//
#include <hip/hip_runtime.h>
#include <hip/hip_bf16.h>

#define N_NODES 50000
#define E_EDGES 300000
#define IN_F 512
#define H_F 256
#define OUT_F 256
#define K_CL 4096
#define KW (K_CL / 32)
#define PCH 128
#define THRESH 192
#define MAXH 1024
#define NSPL 32
#define NB2 ((N_NODES + 255) / 256)
#define KBW ((N_NODES + 63) / 64 + 8)

typedef short bh8 __attribute__((ext_vector_type(8)));
typedef float f4 __attribute__((ext_vector_type(4)));
typedef unsigned short u16;
typedef unsigned long long u64;

__device__ __forceinline__ unsigned fkey(float f) {
    unsigned u = __float_as_uint(f);
    return (u & 0x80000000u) ? ~u : (u | 0x80000000u);
}

__device__ __forceinline__ u16 f2bf(float f) {
    __hip_bfloat16 b = __float2bfloat16(f);
    return *reinterpret_cast<u16*>(&b);
}

__device__ __forceinline__ float bf2f(u16 u) {
    return __uint_as_float(((unsigned)u) << 16);
}

__device__ __forceinline__ int getbit(const u64* __restrict__ bits, int i) {
    return (int)((bits[i >> 6] >> (i & 63)) & 1ULL);
}

// ---------------- init ----------------
__global__ __launch_bounds__(256) void init_nodes(int* cntD, int* degS,
                                                  unsigned long long* best_enc,
                                                  int* bgnode, int* heavycnt,
                                                  unsigned long long* bestpack,
                                                  unsigned* selT, int* curk, int* hist4) {
    int i = blockIdx.x * blockDim.x + threadIdx.x;
    if (i < N_NODES) { cntD[i] = 0; degS[i] = 0; best_enc[i] = 0ULL; }
    if (i < 1024) hist4[i] = 0;
    if (i == 0) {
        *heavycnt = 0; *bgnode = 0x7FFFFFFF; *bestpack = 0ULL;
        *selT = 0u; *curk = K_CL;
    }
}

__global__ __launch_bounds__(256) void deg_edges(const int* __restrict__ src,
                                                 const int* __restrict__ dst,
                                                 int* cntD, int* degS) {
    int e = blockIdx.x * blockDim.x + threadIdx.x;
    if (e >= E_EDGES) return;
    atomicAdd(&cntD[dst[e]], 1);
    atomicAdd(&degS[src[e]], 1);
}

// ---- fp32 GEMM (score path): 64x128 tile, dbuf LDS, glds for BOTH A and B ----
#define SBM 64
#define SBN 128
#define SBK 16
__global__ __launch_bounds__(256) void gemm_f32s(const float* __restrict__ A,
                                                 const float* __restrict__ B,
                                                 float* __restrict__ C,
                                                 int M, int Nc, int Kd) {
    __shared__ float As[2][SBM][SBK];
    __shared__ float Bs[2][SBK][SBN];
    int tid = threadIdx.x;
    int tx = tid & 15;
    int ty = tid >> 4;
    int lane = tid & 63;
    int wave = tid >> 6;
    int row0 = blockIdx.y * SBM, col0 = blockIdx.x * SBN;
    float acc[4][8] = {};

    int arow = wave * 16 + (lane >> 2);
    int acolf = ((((lane & 3) * 16) ^ (((lane >> 4) & 1) << 5)) >> 2);

    auto stage_B = [&](int k0, int bb) {
        #pragma unroll
        for (int u = 0; u < 2; ++u) {
            int chunk = wave * 2 + u;
            int krow = chunk * 2 + (lane >> 5);
            const float* gsrc = &B[(long)(k0 + krow) * Nc + col0 + (lane & 31) * 4];
            __builtin_amdgcn_global_load_lds(
                (const __attribute__((address_space(1))) void*)gsrc,
                (__attribute__((address_space(3))) void*)&Bs[bb][chunk * 2][0],
                16, 0, 0);
        }
    };
    auto stage_A = [&](int k0, int bb) {
        int gr = row0 + arow;
        if (gr > M - 1) gr = M - 1;
        const float* gsrc = &A[(long)gr * Kd + k0 + acolf];
        __builtin_amdgcn_global_load_lds(
            (const __attribute__((address_space(1))) void*)gsrc,
            (__attribute__((address_space(3))) void*)&As[bb][wave * 16][0],
            16, 0, 0);
    };
    auto compute = [&](int bb) {
        #pragma unroll
        for (int kq = 0; kq < 4; ++kq) {
            float4 af[4];
            #pragma unroll
            for (int i = 0; i < 4; ++i) {
                int row = ty * 4 + i;
                int cb = ((kq * 16 ^ (((row >> 2) & 1) << 5)) >> 2);
                af[i] = *(const float4*)&As[bb][row][cb];
            }
            #pragma unroll
            for (int kk = 0; kk < 4; ++kk) {
                int k = kq * 4 + kk;
                float4 b0 = *(const float4*)&Bs[bb][k][tx * 4];
                float4 b1 = *(const float4*)&Bs[bb][k][tx * 4 + 64];
                float bv[8] = {b0.x, b0.y, b0.z, b0.w, b1.x, b1.y, b1.z, b1.w};
                float av[4] = {af[0][kk], af[1][kk], af[2][kk], af[3][kk]};
                #pragma unroll
                for (int i = 0; i < 4; ++i)
                    #pragma unroll
                    for (int j = 0; j < 8; ++j)
                        acc[i][j] += av[i] * bv[j];
            }
        }
    };

    stage_B(0, 0);
    stage_A(0, 0);
    __syncthreads();
    int nt = Kd / SBK;
    for (int t = 0; t < nt; ++t) {
        int cb = t & 1;
        if (t + 1 < nt) {
            stage_B(SBK * (t + 1), cb ^ 1);
            stage_A(SBK * (t + 1), cb ^ 1);
        }
        compute(cb);
        __syncthreads();
    }

    #pragma unroll
    for (int i = 0; i < 4; ++i) {
        int gr = row0 + ty * 4 + i;
        if (gr >= M) continue;
        float4 o0 = {acc[i][0], acc[i][1], acc[i][2], acc[i][3]};
        float4 o1 = {acc[i][4], acc[i][5], acc[i][6], acc[i][7]};
        *(float4*)&C[(long)gr * Nc + col0 + tx * 4] = o0;
        *(float4*)&C[(long)gr * Nc + col0 + 64 + tx * 4] = o1;
    }
}

// ---- pack two 256x256 fp32 weights into MFMA-fragment-ordered bf16 (one launch) ----
__global__ __launch_bounds__(256) void pack_W2(const float* __restrict__ Wa, u16* Bpa,
                                               const float* __restrict__ Wb, u16* Bpb) {
    int k = blockIdx.x & 255;
    const float* W = (blockIdx.x < 256) ? Wa : Wb;
    u16* Bp = (blockIdx.x < 256) ? Bpa : Bpb;
    int col = threadIdx.x;
    int kb = k >> 5, g = (k >> 3) & 3, j = k & 7;
    Bp[(((long)(kb * 4 + g) * 256) + col) * 8 + j] = f2bf(W[(long)k * 256 + col]);
}

// ---- bf16 MFMA GEMM: C(Mx256) = A(Mx256) @ Bp(packed) ----
__global__ __launch_bounds__(256) void gemm_mfma(const u16* __restrict__ Ab,
                                                 const float* __restrict__ Af32,
                                                 const int* __restrict__ cnt,
                                                 const u16* __restrict__ Bp,
                                                 float* __restrict__ C,
                                                 int M,
                                                 const int* __restrict__ cid,
                                                 const float* __restrict__ xp2,
                                                 const float* __restrict__ bskip) {
    int tid = threadIdx.x;
    int w = tid >> 6, l = tid & 63;
    int lo16 = l & 15, hi4 = l >> 4;
    int arow = blockIdx.x * 64 + w * 16 + lo16;
    f4 acc[16];
    #pragma unroll
    for (int n = 0; n < 16; ++n) acc[n] = (f4){0.f, 0.f, 0.f, 0.f};

    float s = 1.f;
    if (Af32 && arow < M) s = 1.f / fmaxf((float)cnt[arow], 1.f);

    #pragma unroll
    for (int kb = 0; kb < 8; ++kb) {
        bh8 a = {0, 0, 0, 0, 0, 0, 0, 0};
        if (arow < M) {
            if (Af32) {
                float4 v0 = *(const float4*)&Af32[(long)arow * 256 + kb * 32 + hi4 * 8];
                float4 v1 = *(const float4*)&Af32[(long)arow * 256 + kb * 32 + hi4 * 8 + 4];
                u16 tmp[8] = {f2bf(v0.x * s), f2bf(v0.y * s), f2bf(v0.z * s), f2bf(v0.w * s),
                              f2bf(v1.x * s), f2bf(v1.y * s), f2bf(v1.z * s), f2bf(v1.w * s)};
                a = *(const bh8*)tmp;
            } else {
                a = *(const bh8*)&Ab[(long)arow * 256 + kb * 32 + hi4 * 8];
            }
        }
        const u16* bbase = &Bp[(((long)(kb * 4 + hi4)) * 256 + lo16) * 8];
        #pragma unroll
        for (int n = 0; n < 16; ++n) {
            bh8 b = *(const bh8*)&bbase[(long)n * 128];
            acc[n] = __builtin_amdgcn_mfma_f32_16x16x32_bf16(a, b, acc[n], 0, 0, 0);
        }
    }

    int orow0 = blockIdx.x * 64 + w * 16 + hi4 * 4;
    #pragma unroll
    for (int r = 0; r < 4; ++r) {
        int gr = orow0 + r;
        if (gr >= M) continue;
        long rb = (long)gr * 256;
        const float* xrow = cid ? (xp2 + (long)cid[gr] * 256) : nullptr;
        #pragma unroll
        for (int n = 0; n < 16; ++n) {
            int gc = n * 16 + lo16;
            float v = acc[n][r];
            if (cid) v += xrow[gc] + bskip[gc];
            C[rb + gc] = v;
        }
    }
}

// --------- coalesced two-level exclusive scan (n <= 256*256) ---------
__global__ __launch_bounds__(256) void scan_l1(const int* __restrict__ cnt,
                                               int* bsum, int n, float* dinv) {
    __shared__ int s[256];
    int t = threadIdx.x;
    int i = blockIdx.x * 256 + t;
    int v = (i < n) ? cnt[i] : 0;
    if (dinv && i < n) dinv[i] = rsqrtf((float)v + 1.0f);
    s[t] = v;
    __syncthreads();
    for (int off = 128; off > 0; off >>= 1) {
        if (t < off) s[t] += s[t + off];
        __syncthreads();
    }
    if (t == 0) bsum[blockIdx.x] = s[0];
}

__global__ __launch_bounds__(256) void scan_l2(const int* __restrict__ bsum,
                                               int* bstart, int nb) {
    __shared__ int s[256];
    int t = threadIdx.x;
    int v = (t < nb) ? bsum[t] : 0;
    s[t] = v;
    __syncthreads();
    for (int off = 1; off < 256; off <<= 1) {
        int a = (t >= off) ? s[t - off] : 0;
        __syncthreads();
        s[t] += a;
        __syncthreads();
    }
    if (t < nb) bstart[t] = s[t] - v;
}

__global__ __launch_bounds__(256) void scan_l3(const int* __restrict__ cnt,
                                               const int* __restrict__ bstart,
                                               int* start, int* cur, int n) {
    __shared__ int s[256];
    int t = threadIdx.x;
    int i = blockIdx.x * 256 + t;
    int v = (i < n) ? cnt[i] : 0;
    s[t] = v;
    __syncthreads();
    for (int off = 1; off < 256; off <<= 1) {
        int a = (t >= off) ? s[t - off] : 0;
        __syncthreads();
        s[t] += a;
        __syncthreads();
    }
    int st = bstart[blockIdx.x] + s[t] - v;
    if (i < n) { start[i] = st; cur[i] = st; }
    if (i == n - 1) start[n] = st + v;
}

__global__ __launch_bounds__(256) void csr_scatter(const int* __restrict__ src,
                                                   const int* __restrict__ dst,
                                                   int* cur, int* csr) {
    int e = blockIdx.x * blockDim.x + threadIdx.x;
    if (e >= E_EDGES) return;
    int d = dst[e];
    int p = atomicAdd(&cur[d], 1);
    csr[p] = src[e];
}

// ---- wave-per-node conv1 aggregation: float4 per lane (cols 4l..4l+3) ----
// Per-column accumulation order identical to prior version (self then csr order)
// -> x1b bitwise identical; only the score-reduce grouping changes (ulp-level).
__global__ __launch_bounds__(64) void agg_fused(const float* __restrict__ h,
                                                const float* __restrict__ dinv,
                                                const int* __restrict__ rowptr,
                                                const int* __restrict__ csr,
                                                const float* __restrict__ b1,
                                                const float* __restrict__ w_score,
                                                u16* __restrict__ x1b,
                                                float* __restrict__ raw) {
    int i = blockIdx.x;
    int l = threadIdx.x;
    float di_ = dinv[i];
    const float4* H4 = (const float4*)h;
    long q = (long)i * 64 + l;
    float4 a = H4[q];
    float sc = di_ * di_;
    a.x *= sc; a.y *= sc; a.z *= sc; a.w *= sc;
    int p0 = rowptr[i], p1 = rowptr[i + 1];
    int t = p0;
    for (; t + 1 < p1; t += 2) {
        int s0 = csr[t], s1 = csr[t + 1];
        float c0 = dinv[s0] * di_;
        float c1 = dinv[s1] * di_;
        float4 h0 = H4[(long)s0 * 64 + l];
        float4 h1 = H4[(long)s1 * 64 + l];
        a.x += c0 * h0.x; a.y += c0 * h0.y; a.z += c0 * h0.z; a.w += c0 * h0.w;
        a.x += c1 * h1.x; a.y += c1 * h1.y; a.z += c1 * h1.z; a.w += c1 * h1.w;
    }
    if (t < p1) {
        int s0 = csr[t];
        float c0 = dinv[s0] * di_;
        float4 h0 = H4[(long)s0 * 64 + l];
        a.x += c0 * h0.x; a.y += c0 * h0.y; a.z += c0 * h0.z; a.w += c0 * h0.w;
    }
    float4 bb = ((const float4*)b1)[l];
    float v0 = fmaxf(a.x + bb.x, 0.f);
    float v1 = fmaxf(a.y + bb.y, 0.f);
    float v2 = fmaxf(a.z + bb.z, 0.f);
    float v3 = fmaxf(a.w + bb.w, 0.f);
    ushort4 o;
    o.x = f2bf(v0); o.y = f2bf(v1); o.z = f2bf(v2); o.w = f2bf(v3);
    ((ushort4*)x1b)[q] = o;
    float4 wv = ((const float4*)w_score)[l];
    float s2 = (v0 * wv.x + v2 * wv.z) + (v1 * wv.y + v3 * wv.w);
    #pragma unroll
    for (int off = 32; off > 0; off >>= 1)
        s2 += __shfl_xor(s2, off, 64);
    if (l == 0) raw[i] = s2;
}

// ------- multi-block radix select: per-pass hist (196 blocks) + tiny pick -------
__global__ __launch_bounds__(256) void radix_hist(const float* __restrict__ raw,
                                                  const unsigned* __restrict__ pPrefix,
                                                  int byte, int* hist) {
    __shared__ int lh[256];
    int t = threadIdx.x;
    lh[t] = 0;
    __syncthreads();
    int i = blockIdx.x * 256 + t;
    if (i < N_NODES) {
        unsigned key = fkey(raw[i]);
        unsigned known_mask = (byte == 3) ? 0u : (0xFFFFFFFFu << ((byte + 1) * 8));
        if ((key & known_mask) == *pPrefix)
            atomicAdd(&lh[(key >> (byte * 8)) & 255], 1);
    }
    __syncthreads();
    int hh = lh[t];
    if (hh) atomicAdd(&hist[t], hh);
}

__global__ __launch_bounds__(64) void radix_pick(const int* __restrict__ hist,
                                                 unsigned* pPrefix, int* pK, int byte) {
    if (threadIdx.x != 0) return;
    int kk = *pK;
    int cum = 0;
    int v = 255;
    for (; v > 0; --v) {
        int c = hist[v];
        if (cum + c >= kk) break;
        cum += c;
    }
    *pPrefix |= ((unsigned)v) << (byte * 8);
    *pK = kk - cum;
}

// ---------------- multi-block compaction: count -> scan -> assign ----------------
__global__ __launch_bounds__(256) void topk_count(const float* __restrict__ raw,
                                                  const unsigned* pT,
                                                  int* bGt, int* bEq) {
    __shared__ int sg[256], se[256];
    unsigned T = *pT;
    int t = threadIdx.x;
    int i = blockIdx.x * 256 + t;
    int gt = 0, eq = 0;
    if (i < N_NODES) {
        unsigned k = fkey(raw[i]);
        gt = k > T; eq = (k == T);
    }
    sg[t] = gt; se[t] = eq;
    __syncthreads();
    for (int off = 128; off > 0; off >>= 1) {
        if (t < off) { sg[t] += sg[t + off]; se[t] += se[t + off]; }
        __syncthreads();
    }
    if (t == 0) { bGt[blockIdx.x] = sg[0]; bEq[blockIdx.x] = se[0]; }
}

__global__ __launch_bounds__(256) void scan_blocks(const int* __restrict__ bGt,
                                                   const int* __restrict__ bEq,
                                                   int* gtStart, int* eqStart) {
    __shared__ int sg[256], se[256];
    int t = threadIdx.x;
    int vg = (t < NB2) ? bGt[t] : 0;
    int ve = (t < NB2) ? bEq[t] : 0;
    sg[t] = vg; se[t] = ve;
    __syncthreads();
    for (int off = 1; off < 256; off <<= 1) {
        int a = (t >= off) ? sg[t - off] : 0;
        int b = (t >= off) ? se[t - off] : 0;
        __syncthreads();
        sg[t] += a; se[t] += b;
        __syncthreads();
    }
    if (t < NB2) { gtStart[t] = sg[t] - vg; eqStart[t] = se[t] - ve; }
    if (t == 255) gtStart[NB2] = sg[255];   // totalGt
}

__global__ __launch_bounds__(256) void topk_assign(const float* __restrict__ raw,
                                                   const unsigned* pT, const int* pNeedEq,
                                                   const int* __restrict__ degS,
                                                   const int* __restrict__ gtStart,
                                                   const int* __restrict__ eqStart,
                                                   u64* keep_bits, int* cid,
                                                   unsigned long long* bestpack) {
    __shared__ int sg[256], se[256];
    unsigned T = *pT;
    int needEq = *pNeedEq;
    int totalGt = gtStart[NB2];
    int b = blockIdx.x, t = threadIdx.x;
    int i = b * 256 + t;
    int gt = 0, eq = 0;
    unsigned k = 0;
    if (i < N_NODES) {
        k = fkey(raw[i]);
        gt = k > T; eq = (k == T);
    }
    sg[t] = gt; se[t] = eq;
    __syncthreads();
    for (int off = 1; off < 256; off <<= 1) {
        int a = (t >= off) ? sg[t - off] : 0;
        int c = (t >= off) ? se[t - off] : 0;
        __syncthreads();
        sg[t] += a; se[t] += c;
        __syncthreads();
    }
    int eg = sg[t] - gt, ee = se[t] - eq;
    int kp = 0;
    unsigned long long p = 0ULL;
    if (i < N_NODES) {
        int c = -1;
        if (gt) { kp = 1; c = gtStart[b] + eg; }
        else if (eq) {
            int r = eqStart[b] + ee;
            if (r < needEq) { kp = 1; c = totalGt + r; }
        }
        cid[i] = c;
        if (kp) p = ((unsigned long long)(unsigned)degS[i] << 32) | k;
    }
    u64 ball = __ballot(kp);
    if ((t & 63) == 0) keep_bits[(b * 256 + t) >> 6] = ball;
    #pragma unroll
    for (int o = 32; o > 0; o >>= 1) {
        unsigned long long q = __shfl_xor((long long)p, o, 64);
        if (q > p) p = q;
    }
    if ((t & 63) == 0 && p) atomicMax(bestpack, p);
}

__global__ __launch_bounds__(256) void bg_node(const u64* __restrict__ keep_bits,
                                               const int* __restrict__ degS,
                                               const float* __restrict__ raw,
                                               const unsigned long long* bestpack, int* bgnode) {
    int i = blockIdx.x * blockDim.x + threadIdx.x;
    if (i < N_NODES && getbit(keep_bits, i)) {
        unsigned long long p = ((unsigned long long)(unsigned)degS[i] << 32) | fkey(raw[i]);
        if (p == *bestpack) atomicMin(bgnode, i);
    }
}

// ---------------- neighbor attachment (bitmask keep probes) ----------------
__global__ __launch_bounds__(256) void neigh_edges(const int* __restrict__ src,
                                                   const int* __restrict__ dst,
                                                   const u64* __restrict__ keep_bits,
                                                   const int* __restrict__ degS,
                                                   unsigned long long* best_enc) {
    int e = blockIdx.x * blockDim.x + threadIdx.x;
    if (e >= 2 * E_EDGES) return;
    int s, t;
    if (e < E_EDGES) { s = src[e]; t = dst[e]; }
    else { s = dst[e - E_EDGES]; t = src[e - E_EDGES]; }
    if (!getbit(keep_bits, s) && getbit(keep_bits, t)) {
        unsigned long long enc =
            (unsigned long long)((long long)degS[t] * N_NODES + (N_NODES - 1 - t)) + 1ULL;
        atomicMax(&best_enc[s], enc);
    }
}

__global__ __launch_bounds__(256) void resolve_cid(const u64* __restrict__ keep_bits,
                                                   const unsigned long long* __restrict__ best_enc,
                                                   const int* __restrict__ bgnode, int* cid) {
    int i = blockIdx.x * blockDim.x + threadIdx.x;
    if (i >= N_NODES) return;
    if (getbit(keep_bits, i)) return;
    unsigned long long v = best_enc[i];
    if (v > 0ULL) {
        long long enc = (long long)(v - 1ULL);
        int t = (N_NODES - 1) - (int)(enc % N_NODES);
        cid[i] = cid[t];
    } else {
        cid[i] = cid[*bgnode];
    }
}

// ---------------- LDS-aggregated counting sort by cluster ----------------
#define NPB 1024
__global__ __launch_bounds__(256) void ccount2(const int* __restrict__ cid, int* ccnt) {
    __shared__ int hist[K_CL];
    for (int t = threadIdx.x; t < K_CL; t += 256) hist[t] = 0;
    __syncthreads();
    int base = blockIdx.x * NPB;
    #pragma unroll
    for (int u = 0; u < NPB / 256; ++u) {
        int idx = base + u * 256 + threadIdx.x;
        if (idx < N_NODES) atomicAdd(&hist[cid[idx]], 1);
    }
    __syncthreads();
    for (int t = threadIdx.x; t < K_CL; t += 256) {
        int hh = hist[t];
        if (hh) atomicAdd(&ccnt[t], hh);
    }
}

__global__ __launch_bounds__(256) void cscatter2(const int* __restrict__ cid,
                                                 int* ccur, int* clist) {
    __shared__ int hist[K_CL];
    for (int t = threadIdx.x; t < K_CL; t += 256) hist[t] = 0;
    __syncthreads();
    int base = blockIdx.x * NPB;
    int myc[NPB / 256], myr[NPB / 256];
    #pragma unroll
    for (int u = 0; u < NPB / 256; ++u) {
        int idx = base + u * 256 + threadIdx.x;
        if (idx < N_NODES) { myc[u] = cid[idx]; myr[u] = atomicAdd(&hist[myc[u]], 1); }
        else myc[u] = -1;
    }
    __syncthreads();
    for (int t = threadIdx.x; t < K_CL; t += 256) {
        int hh = hist[t];
        if (hh) hist[t] = atomicAdd(&ccur[t], hh);
    }
    __syncthreads();
    #pragma unroll
    for (int u = 0; u < NPB / 256; ++u)
        if (myc[u] >= 0) clist[hist[myc[u]] + myr[u]] = base + u * 256 + threadIdx.x;
}

// ---------------- chunked segmented pooling (bf16 inputs) ----------------
__global__ __launch_bounds__(256) void pool_chunk(const u16* __restrict__ x1b,
                                                  const float* __restrict__ raw,
                                                  const int* __restrict__ clist,
                                                  const int* __restrict__ cid,
                                                  float* xp) {
    __shared__ int s_node[PCH];
    __shared__ int s_c[PCH];
    __shared__ float s_g[PCH];
    int j = threadIdx.x;
    int base = blockIdx.x * PCH;
    int m = N_NODES - base; if (m > PCH) m = PCH;
    for (int t = j; t < m; t += 256) {
        int nd = clist[base + t];
        s_node[t] = nd;
        s_c[t] = cid[nd];
        s_g[t] = tanhf(raw[nd]);
    }
    __syncthreads();
    float acc = 0.f;
    int cprev = s_c[0];
    for (int t = 0; t < m; t += 4) {
        int mm = m - t; if (mm > 4) mm = 4;
        float v[4];
        #pragma unroll
        for (int u = 0; u < 4; ++u)
            if (u < mm) v[u] = bf2f(x1b[(long)s_node[t + u] * H_F + j]);
        #pragma unroll
        for (int u = 0; u < 4; ++u) {
            if (u < mm) {
                int c = s_c[t + u];
                if (c != cprev) {
                    atomicAdd(&xp[(long)cprev * H_F + j], acc);
                    acc = 0.f;
                    cprev = c;
                }
                acc += s_g[t + u] * v[u];
            }
        }
    }
    atomicAdd(&xp[(long)cprev * H_F + j], acc);
}

// ---------------- bit-packed pooled adjacency ----------------
__global__ __launch_bounds__(256) void build_Abits(const int* __restrict__ src,
                                                   const int* __restrict__ dst,
                                                   const int* __restrict__ cid,
                                                   unsigned* Abits) {
    int e = blockIdx.x * blockDim.x + threadIdx.x;
    if (e >= E_EDGES) return;
    int cu = cid[src[e]], cv = cid[dst[e]];
    if (cu != cv) atomicOr(&Abits[(long)cv * KW + (cu >> 5)], 1u << (cu & 31));
}

// di, nnz, and heavy-row compaction
__global__ __launch_bounds__(256) void pop_di2(const unsigned* __restrict__ Abits, float* di,
                                               int* nnzA, int* heavy, int* heavycnt) {
    int i = blockIdx.x * blockDim.x + threadIdx.x;
    if (i >= K_CL) return;
    int c = 0;
    for (int w = 0; w < KW; ++w) c += __popc(Abits[(long)i * KW + w]);
    di[i] = rsqrtf((float)c + 1.0f);
    nnzA[i] = c;
    if (c > THRESH) {
        int p = atomicAdd(heavycnt, 1);
        if (p < MAXH) heavy[p] = i;
    }
}

// light rows (nnz<=THRESH)
__global__ __launch_bounds__(256) void spmm_light(const unsigned* __restrict__ Abits,
                                                  const float* __restrict__ xpW2,
                                                  const float* __restrict__ di,
                                                  const float* __restrict__ b2,
                                                  const int* __restrict__ nnzA,
                                                  float* xp2) {
    __shared__ unsigned s_row[KW];
    __shared__ float s_part[3][256];
    int cv = blockIdx.x;
    if (nnzA[cv] > THRESH) return;
    int tid = threadIdx.x;
    int w = tid >> 6, l = tid & 63;
    if (tid < KW) s_row[tid] = Abits[(long)cv * KW + tid];
    __syncthreads();
    float4 a0 = {0.f, 0.f, 0.f, 0.f}, a1 = {0.f, 0.f, 0.f, 0.f};
    const float4* Y4 = (const float4*)xpW2;
    for (int wi = w * 32; wi < w * 32 + 32; wi += 2) {
        unsigned w0 = s_row[wi], w1 = s_row[wi + 1];
        while (w0 | w1) {
            if (w0) {
                int b = __ffs(w0) - 1; w0 &= w0 - 1;
                int cu = wi * 32 + b;
                float d = di[cu];
                float4 y = Y4[(long)cu * 64 + l];
                a0.x += d * y.x; a0.y += d * y.y; a0.z += d * y.z; a0.w += d * y.w;
            }
            if (w1) {
                int b = __ffs(w1) - 1; w1 &= w1 - 1;
                int cu = (wi + 1) * 32 + b;
                float d = di[cu];
                float4 y = Y4[(long)cu * 64 + l];
                a1.x += d * y.x; a1.y += d * y.y; a1.z += d * y.z; a1.w += d * y.w;
            }
        }
    }
    float4 acc = {a0.x + a1.x, a0.y + a1.y, a0.z + a1.z, a0.w + a1.w};
    if (w > 0) *(float4*)&s_part[w - 1][l * 4] = acc;
    __syncthreads();
    if (w == 0) {
        #pragma unroll
        for (int ww = 0; ww < 3; ++ww) {
            float4 p = *(float4*)&s_part[ww][l * 4];
            acc.x += p.x; acc.y += p.y; acc.z += p.z; acc.w += p.w;
        }
        float dv = di[cv];
        float4 ys = Y4[(long)cv * 64 + l];
        float4 o;
        o.x = dv * (acc.x + dv * ys.x) + b2[l * 4 + 0];
        o.y = dv * (acc.y + dv * ys.y) + b2[l * 4 + 1];
        o.z = dv * (acc.z + dv * ys.z) + b2[l * 4 + 2];
        o.w = dv * (acc.w + dv * ys.w) + b2[l * 4 + 3];
        *(float4*)&xp2[(long)cv * H_F + l * 4] = o;
    }
}

// heavy rows: grid (MAXH, NSPL); block (hi, sp) handles 4 words (1 per wave)
__global__ __launch_bounds__(256) void spmm_heavy(const unsigned* __restrict__ Abits,
                                                  const float* __restrict__ xpW2,
                                                  const float* __restrict__ di,
                                                  const int* __restrict__ heavy,
                                                  const int* __restrict__ heavycnt,
                                                  float* Zacc) {
    __shared__ float s_part[3][256];
    int hi = blockIdx.x;
    int cnt = *heavycnt; if (cnt > MAXH) cnt = MAXH;
    if (hi >= cnt) return;
    int cv = heavy[hi];
    int sp = blockIdx.y;
    int tid = threadIdx.x;
    int w = tid >> 6, l = tid & 63;
    int wi = sp * (KW / NSPL) + w;
    unsigned word = Abits[(long)cv * KW + wi];
    float4 acc = {0.f, 0.f, 0.f, 0.f};
    const float4* Y4 = (const float4*)xpW2;
    while (word) {
        int b = __ffs(word) - 1; word &= word - 1;
        int cu = wi * 32 + b;
        float d = di[cu];
        float4 y = Y4[(long)cu * 64 + l];
        acc.x += d * y.x; acc.y += d * y.y; acc.z += d * y.z; acc.w += d * y.w;
    }
    if (w > 0) *(float4*)&s_part[w - 1][l * 4] = acc;
    __syncthreads();
    if (w == 0) {
        #pragma unroll
        for (int ww = 0; ww < 3; ++ww) {
            float4 p = *(float4*)&s_part[ww][l * 4];
            acc.x += p.x; acc.y += p.y; acc.z += p.z; acc.w += p.w;
        }
        float* zp = &Zacc[(long)cv * H_F + l * 4];
        atomicAdd(zp + 0, acc.x);
        atomicAdd(zp + 1, acc.y);
        atomicAdd(zp + 2, acc.z);
        atomicAdd(zp + 3, acc.w);
    }
}

__global__ __launch_bounds__(256) void heavy_epi(const float* __restrict__ Zacc,
                                                 const float* __restrict__ xpW2,
                                                 const float* __restrict__ di,
                                                 const float* __restrict__ b2,
                                                 const int* __restrict__ heavy,
                                                 const int* __restrict__ heavycnt,
                                                 float* xp2) {
    int hi = blockIdx.x;
    int cnt = *heavycnt; if (cnt > MAXH) cnt = MAXH;
    if (hi >= cnt) return;
    int cv = heavy[hi];
    int j = threadIdx.x;
    float dv = di[cv];
    xp2[(long)cv * H_F + j] =
        dv * (Zacc[(long)cv * H_F + j] + dv * xpW2[(long)cv * H_F + j]) + b2[j];
}

// ---------------- host launch ----------------
static inline size_t align256(size_t x) { return (x + 255) & ~(size_t)255; }

extern "C" void kernel_launch(void* const* d_in, const int* in_sizes, int n_in,
                              void* d_out, int out_size, void* d_ws, size_t ws_size,
                              hipStream_t stream) {
    const float* x      = (const float*)d_in[0];
    const int*   eidx   = (const int*)d_in[1];
    const float* W1     = (const float*)d_in[2];
    const float* b1     = (const float*)d_in[3];
    const float* W2     = (const float*)d_in[4];
    const float* b2     = (const float*)d_in[5];
    const float* wscore = (const float*)d_in[6];
    const float* Wskip  = (const float*)d_in[7];
    const float* bskip  = (const float*)d_in[8];
    float* out = (float*)d_out;

    const int* src = eidx;
    const int* dst = eidx + E_EDGES;

    char* ws = (char*)d_ws;
    size_t off = 0;
    auto alloc = [&](size_t bytes) { char* p = ws + off; off += align256(bytes); return p; };

    float* h     = (float*)alloc((size_t)N_NODES * H_F * 4);
    u16*   x1b   = (u16*)alloc((size_t)N_NODES * H_F * 2);
    float* raw   = (float*)alloc((size_t)N_NODES * 4);
    float* dinv  = (float*)alloc((size_t)N_NODES * 4);
    int*   cntD  = (int*)alloc((size_t)N_NODES * 4);
    int*   degS  = (int*)alloc((size_t)N_NODES * 4);
    u64*   keep_bits = (u64*)alloc((size_t)KBW * 8);
    int*   cid   = (int*)alloc((size_t)N_NODES * 4);
    unsigned long long* best_enc = (unsigned long long*)alloc((size_t)N_NODES * 8);
    int*   rowptr= (int*)alloc((size_t)(N_NODES + 1) * 4);
    int*   cur   = (int*)alloc((size_t)N_NODES * 4);
    int*   csr   = (int*)alloc((size_t)E_EDGES * 4);
    int*   ccnt  = (int*)alloc((size_t)K_CL * 4);
    int*   cstart= (int*)alloc((size_t)(K_CL + 1) * 4);
    int*   ccur  = (int*)alloc((size_t)K_CL * 4);
    int*   clist = (int*)alloc((size_t)N_NODES * 4);
    int*   bGt   = (int*)alloc((size_t)NB2 * 4);
    int*   bEq   = (int*)alloc((size_t)NB2 * 4);
    int*   gtStart = (int*)alloc((size_t)(NB2 + 1) * 4);
    int*   eqStart = (int*)alloc((size_t)NB2 * 4);
    int*   bsum  = (int*)alloc((size_t)256 * 4);
    int*   bstart= (int*)alloc((size_t)256 * 4);
    int*   hist4 = (int*)alloc((size_t)4 * 256 * 4);
    char*  small = alloc(64);
    unsigned* selT = (unsigned*)(small + 0);
    int* needEq    = (int*)(small + 4);
    int* bgnode    = (int*)(small + 8);
    int* heavycnt  = (int*)(small + 12);
    unsigned long long* bestpack = (unsigned long long*)(small + 16);
    // xp, Abits, Zacc adjacent -> single memset covers all three
    float* xp    = (float*)alloc((size_t)K_CL * H_F * 4);
    unsigned* Abits = (unsigned*)alloc((size_t)K_CL * KW * 4);
    float* Zacc  = (float*)alloc((size_t)K_CL * H_F * 4);
    float* di    = (float*)alloc((size_t)K_CL * 4);
    int*   nnzA  = (int*)alloc((size_t)K_CL * 4);
    int*   heavy = (int*)alloc((size_t)MAXH * 4);
    float* xpW2  = (float*)alloc((size_t)K_CL * H_F * 4);
    float* xp2   = (float*)alloc((size_t)K_CL * H_F * 4);
    u16*  BpS   = (u16*)alloc((size_t)H_F * OUT_F * 2);
    u16*  Bp2   = (u16*)alloc((size_t)H_F * H_F * 2);
    (void)ws_size; (void)n_in; (void)in_sizes; (void)out_size;

    int nb = NB2;
    int eb = (E_EDGES + 255) / 256;

    // degrees + small-state init (also zeroes hist4)
    init_nodes<<<nb, 256, 0, stream>>>(cntD, degS, best_enc, bgnode, heavycnt, bestpack,
                                       selT, needEq, hist4);
    deg_edges<<<eb, 256, 0, stream>>>(src, dst, cntD, degS);

    // weight packing (both in one launch)
    pack_W2<<<512, 256, 0, stream>>>(Wskip, BpS, W2, Bp2);

    // h = x @ W1 (fp32 — score path must stay exact)
    {
        dim3 grid(H_F / SBN, (N_NODES + SBM - 1) / SBM);
        gemm_f32s<<<grid, 256, 0, stream>>>(x, W1, h, N_NODES, H_F, IN_F);
    }

    // CSR by dst: coalesced two-level scan (also emits dinv) + scatter, then aggregation
    scan_l1<<<NB2, 256, 0, stream>>>(cntD, bsum, N_NODES, dinv);
    scan_l2<<<1, 256, 0, stream>>>(bsum, bstart, NB2);
    scan_l3<<<NB2, 256, 0, stream>>>(cntD, bstart, rowptr, cur, N_NODES);
    csr_scatter<<<eb, 256, 0, stream>>>(src, dst, cur, csr);
    agg_fused<<<N_NODES, 64, 0, stream>>>(h, dinv, rowptr, csr, b1, wscore, x1b, raw);

    // top-K threshold: multi-block radix (4 passes)
    for (int b = 3; b >= 0; --b) {
        radix_hist<<<NB2, 256, 0, stream>>>(raw, selT, b, hist4 + b * 256);
        radix_pick<<<1, 64, 0, stream>>>(hist4 + b * 256, selT, needEq, b);
    }
    topk_count<<<NB2, 256, 0, stream>>>(raw, selT, bGt, bEq);
    scan_blocks<<<1, 256, 0, stream>>>(bGt, bEq, gtStart, eqStart);
    topk_assign<<<NB2, 256, 0, stream>>>(raw, selT, needEq, degS, gtStart, eqStart,
                                         keep_bits, cid, bestpack);
    bg_node<<<nb, 256, 0, stream>>>(keep_bits, degS, raw, bestpack, bgnode);

    // neighbor attachment
    neigh_edges<<<(2 * E_EDGES + 255) / 256, 256, 0, stream>>>(src, dst, keep_bits, degS,
                                                               best_enc);
    resolve_cid<<<nb, 256, 0, stream>>>(keep_bits, best_enc, bgnode, cid);

    // single memset for xp (4MB) + Abits (2MB) + Zacc (4MB), adjacent in ws
    hipMemsetAsync(xp, 0, (size_t)K_CL * H_F * 4 * 2 + (size_t)K_CL * KW * 4, stream);

    // LDS-aggregated counting sort by cluster, then chunked segmented pooling
    hipMemsetAsync(ccnt, 0, (size_t)K_CL * 4, stream);
    {
        int cb = (N_NODES + NPB - 1) / NPB;
        ccount2<<<cb, 256, 0, stream>>>(cid, ccnt);
        scan_l1<<<K_CL / 256, 256, 0, stream>>>(ccnt, bsum, K_CL, nullptr);
        scan_l2<<<1, 256, 0, stream>>>(bsum, bstart, K_CL / 256);
        scan_l3<<<K_CL / 256, 256, 0, stream>>>(ccnt, bstart, cstart, ccur, K_CL);
        cscatter2<<<cb, 256, 0, stream>>>(cid, ccur, clist);
    }
    pool_chunk<<<(N_NODES + PCH - 1) / PCH, 256, 0, stream>>>(x1b, raw, clist, cid, xp);

    // xpW2 = (xp/cnt) @ W2  (bf16 MFMA, in-kernel fp32->bf16 conversion)
    gemm_mfma<<<K_CL / 64, 256, 0, stream>>>(nullptr, xp, ccnt, Bp2, xpW2, K_CL,
                                             nullptr, nullptr, nullptr);

    // bit-packed pooled adjacency + split light/heavy normalized SpMM
    build_Abits<<<eb, 256, 0, stream>>>(src, dst, cid, Abits);
    pop_di2<<<(K_CL + 255) / 256, 256, 0, stream>>>(Abits, di, nnzA, heavy, heavycnt);
    spmm_light<<<K_CL, 256, 0, stream>>>(Abits, xpW2, di, b2, nnzA, xp2);
    {
        dim3 hgrid(MAXH, NSPL);
        spmm_heavy<<<hgrid, 256, 0, stream>>>(Abits, xpW2, di, heavy, heavycnt, Zacc);
    }
    heavy_epi<<<MAXH, 256, 0, stream>>>(Zacc, xpW2, di, b2, heavy, heavycnt, xp2);

    // out = x1@Wskip + xp2[cid] + b_skip  (bf16 MFMA, fused epilogue)
    gemm_mfma<<<(N_NODES + 63) / 64, 256, 0, stream>>>(x1b, nullptr, nullptr, BpS, out,
                                                       N_NODES, cid, xp2, bskip);
}

// Round 18
// 654.329 us; speedup vs baseline: 1.1373x; 1.0047x over previous
//
#include <hip/hip_runtime.h>
#include <hip/hip_bf16.h>

#define N_NODES 50000
#define E_EDGES 300000
#define IN_F 512
#define H_F 256
#define OUT_F 256
#define K_CL 4096
#define KW (K_CL / 32)
#define PCH 128
#define THRESH 192
#define MAXH 1024
#define NSPL 32
#define NB2 ((N_NODES + 255) / 256)
#define KBW ((N_NODES + 63) / 64 + 8)

typedef short bh8 __attribute__((ext_vector_type(8)));
typedef float f4 __attribute__((ext_vector_type(4)));
typedef unsigned short u16;
typedef unsigned long long u64;

__device__ __forceinline__ unsigned fkey(float f) {
    unsigned u = __float_as_uint(f);
    return (u & 0x80000000u) ? ~u : (u | 0x80000000u);
}

__device__ __forceinline__ u16 f2bf(float f) {
    __hip_bfloat16 b = __float2bfloat16(f);
    return *reinterpret_cast<u16*>(&b);
}

__device__ __forceinline__ float bf2f(u16 u) {
    return __uint_as_float(((unsigned)u) << 16);
}

__device__ __forceinline__ int getbit(const u64* __restrict__ bits, int i) {
    return (int)((bits[i >> 6] >> (i & 63)) & 1ULL);
}

// ---------------- init ----------------
__global__ __launch_bounds__(256) void init_nodes(int* cntD, int* degS,
                                                  unsigned long long* best_enc,
                                                  int* bgnode, int* heavycnt,
                                                  unsigned long long* bestpack,
                                                  unsigned* selT, int* curk,
                                                  int* hist4, int* ccnt) {
    int i = blockIdx.x * blockDim.x + threadIdx.x;
    if (i < N_NODES) { cntD[i] = 0; degS[i] = 0; best_enc[i] = 0ULL; }
    if (i < 1024) hist4[i] = 0;
    if (i < K_CL) ccnt[i] = 0;
    if (i == 0) {
        *heavycnt = 0; *bgnode = 0x7FFFFFFF; *bestpack = 0ULL;
        *selT = 0u; *curk = K_CL;
    }
}

__global__ __launch_bounds__(256) void deg_edges(const int* __restrict__ src,
                                                 const int* __restrict__ dst,
                                                 int* cntD, int* degS) {
    int e = blockIdx.x * blockDim.x + threadIdx.x;
    if (e >= E_EDGES) return;
    atomicAdd(&cntD[dst[e]], 1);
    atomicAdd(&degS[src[e]], 1);
}

// ---- fp32 GEMM (score path): 64x128 tile, dbuf LDS, glds for BOTH A and B ----
#define SBM 64
#define SBN 128
#define SBK 16
__global__ __launch_bounds__(256) void gemm_f32s(const float* __restrict__ A,
                                                 const float* __restrict__ B,
                                                 float* __restrict__ C,
                                                 int M, int Nc, int Kd) {
    __shared__ float As[2][SBM][SBK];
    __shared__ float Bs[2][SBK][SBN];
    int tid = threadIdx.x;
    int tx = tid & 15;
    int ty = tid >> 4;
    int lane = tid & 63;
    int wave = tid >> 6;
    int row0 = blockIdx.y * SBM, col0 = blockIdx.x * SBN;
    float acc[4][8] = {};

    int arow = wave * 16 + (lane >> 2);
    int acolf = ((((lane & 3) * 16) ^ (((lane >> 4) & 1) << 5)) >> 2);

    auto stage_B = [&](int k0, int bb) {
        #pragma unroll
        for (int u = 0; u < 2; ++u) {
            int chunk = wave * 2 + u;
            int krow = chunk * 2 + (lane >> 5);
            const float* gsrc = &B[(long)(k0 + krow) * Nc + col0 + (lane & 31) * 4];
            __builtin_amdgcn_global_load_lds(
                (const __attribute__((address_space(1))) void*)gsrc,
                (__attribute__((address_space(3))) void*)&Bs[bb][chunk * 2][0],
                16, 0, 0);
        }
    };
    auto stage_A = [&](int k0, int bb) {
        int gr = row0 + arow;
        if (gr > M - 1) gr = M - 1;
        const float* gsrc = &A[(long)gr * Kd + k0 + acolf];
        __builtin_amdgcn_global_load_lds(
            (const __attribute__((address_space(1))) void*)gsrc,
            (__attribute__((address_space(3))) void*)&As[bb][wave * 16][0],
            16, 0, 0);
    };
    auto compute = [&](int bb) {
        #pragma unroll
        for (int kq = 0; kq < 4; ++kq) {
            float4 af[4];
            #pragma unroll
            for (int i = 0; i < 4; ++i) {
                int row = ty * 4 + i;
                int cb = ((kq * 16 ^ (((row >> 2) & 1) << 5)) >> 2);
                af[i] = *(const float4*)&As[bb][row][cb];
            }
            #pragma unroll
            for (int kk = 0; kk < 4; ++kk) {
                int k = kq * 4 + kk;
                float4 b0 = *(const float4*)&Bs[bb][k][tx * 4];
                float4 b1 = *(const float4*)&Bs[bb][k][tx * 4 + 64];
                float bv[8] = {b0.x, b0.y, b0.z, b0.w, b1.x, b1.y, b1.z, b1.w};
                float av[4] = {af[0][kk], af[1][kk], af[2][kk], af[3][kk]};
                #pragma unroll
                for (int i = 0; i < 4; ++i)
                    #pragma unroll
                    for (int j = 0; j < 8; ++j)
                        acc[i][j] += av[i] * bv[j];
            }
        }
    };

    stage_B(0, 0);
    stage_A(0, 0);
    __syncthreads();
    int nt = Kd / SBK;
    for (int t = 0; t < nt; ++t) {
        int cb = t & 1;
        if (t + 1 < nt) {
            stage_B(SBK * (t + 1), cb ^ 1);
            stage_A(SBK * (t + 1), cb ^ 1);
        }
        compute(cb);
        __syncthreads();
    }

    #pragma unroll
    for (int i = 0; i < 4; ++i) {
        int gr = row0 + ty * 4 + i;
        if (gr >= M) continue;
        float4 o0 = {acc[i][0], acc[i][1], acc[i][2], acc[i][3]};
        float4 o1 = {acc[i][4], acc[i][5], acc[i][6], acc[i][7]};
        *(float4*)&C[(long)gr * Nc + col0 + tx * 4] = o0;
        *(float4*)&C[(long)gr * Nc + col0 + 64 + tx * 4] = o1;
    }
}

// ---- pack two 256x256 fp32 weights into MFMA-fragment-ordered bf16 (one launch) ----
__global__ __launch_bounds__(256) void pack_W2(const float* __restrict__ Wa, u16* Bpa,
                                               const float* __restrict__ Wb, u16* Bpb) {
    int k = blockIdx.x & 255;
    const float* W = (blockIdx.x < 256) ? Wa : Wb;
    u16* Bp = (blockIdx.x < 256) ? Bpa : Bpb;
    int col = threadIdx.x;
    int kb = k >> 5, g = (k >> 3) & 3, j = k & 7;
    Bp[(((long)(kb * 4 + g) * 256) + col) * 8 + j] = f2bf(W[(long)k * 256 + col]);
}

// ---- bf16 MFMA GEMM: C(Mx256) = A(Mx256) @ Bp(packed) ----
__global__ __launch_bounds__(256) void gemm_mfma(const u16* __restrict__ Ab,
                                                 const float* __restrict__ Af32,
                                                 const int* __restrict__ cnt,
                                                 const u16* __restrict__ Bp,
                                                 float* __restrict__ C,
                                                 int M,
                                                 const int* __restrict__ cid,
                                                 const float* __restrict__ xp2,
                                                 const float* __restrict__ bskip) {
    int tid = threadIdx.x;
    int w = tid >> 6, l = tid & 63;
    int lo16 = l & 15, hi4 = l >> 4;
    int arow = blockIdx.x * 64 + w * 16 + lo16;
    f4 acc[16];
    #pragma unroll
    for (int n = 0; n < 16; ++n) acc[n] = (f4){0.f, 0.f, 0.f, 0.f};

    float s = 1.f;
    if (Af32 && arow < M) s = 1.f / fmaxf((float)cnt[arow], 1.f);

    #pragma unroll
    for (int kb = 0; kb < 8; ++kb) {
        bh8 a = {0, 0, 0, 0, 0, 0, 0, 0};
        if (arow < M) {
            if (Af32) {
                float4 v0 = *(const float4*)&Af32[(long)arow * 256 + kb * 32 + hi4 * 8];
                float4 v1 = *(const float4*)&Af32[(long)arow * 256 + kb * 32 + hi4 * 8 + 4];
                u16 tmp[8] = {f2bf(v0.x * s), f2bf(v0.y * s), f2bf(v0.z * s), f2bf(v0.w * s),
                              f2bf(v1.x * s), f2bf(v1.y * s), f2bf(v1.z * s), f2bf(v1.w * s)};
                a = *(const bh8*)tmp;
            } else {
                a = *(const bh8*)&Ab[(long)arow * 256 + kb * 32 + hi4 * 8];
            }
        }
        const u16* bbase = &Bp[(((long)(kb * 4 + hi4)) * 256 + lo16) * 8];
        #pragma unroll
        for (int n = 0; n < 16; ++n) {
            bh8 b = *(const bh8*)&bbase[(long)n * 128];
            acc[n] = __builtin_amdgcn_mfma_f32_16x16x32_bf16(a, b, acc[n], 0, 0, 0);
        }
    }

    int orow0 = blockIdx.x * 64 + w * 16 + hi4 * 4;
    #pragma unroll
    for (int r = 0; r < 4; ++r) {
        int gr = orow0 + r;
        if (gr >= M) continue;
        long rb = (long)gr * 256;
        const float* xrow = cid ? (xp2 + (long)cid[gr] * 256) : nullptr;
        #pragma unroll
        for (int n = 0; n < 16; ++n) {
            int gc = n * 16 + lo16;
            float v = acc[n][r];
            if (cid) v += xrow[gc] + bskip[gc];
            C[rb + gc] = v;
        }
    }
}

// --------- coalesced two-level exclusive scan (n <= 256*256) ---------
__global__ __launch_bounds__(256) void scan_l1(const int* __restrict__ cnt,
                                               int* bsum, int n, float* dinv) {
    __shared__ int s[256];
    int t = threadIdx.x;
    int i = blockIdx.x * 256 + t;
    int v = (i < n) ? cnt[i] : 0;
    if (dinv && i < n) dinv[i] = rsqrtf((float)v + 1.0f);
    s[t] = v;
    __syncthreads();
    for (int off = 128; off > 0; off >>= 1) {
        if (t < off) s[t] += s[t + off];
        __syncthreads();
    }
    if (t == 0) bsum[blockIdx.x] = s[0];
}

__global__ __launch_bounds__(256) void scan_l2(const int* __restrict__ bsum,
                                               int* bstart, int nb) {
    __shared__ int s[256];
    int t = threadIdx.x;
    int v = (t < nb) ? bsum[t] : 0;
    s[t] = v;
    __syncthreads();
    for (int off = 1; off < 256; off <<= 1) {
        int a = (t >= off) ? s[t - off] : 0;
        __syncthreads();
        s[t] += a;
        __syncthreads();
    }
    if (t < nb) bstart[t] = s[t] - v;
}

__global__ __launch_bounds__(256) void scan_l3(const int* __restrict__ cnt,
                                               const int* __restrict__ bstart,
                                               int* start, int* cur, int n) {
    __shared__ int s[256];
    int t = threadIdx.x;
    int i = blockIdx.x * 256 + t;
    int v = (i < n) ? cnt[i] : 0;
    s[t] = v;
    __syncthreads();
    for (int off = 1; off < 256; off <<= 1) {
        int a = (t >= off) ? s[t - off] : 0;
        __syncthreads();
        s[t] += a;
        __syncthreads();
    }
    int st = bstart[blockIdx.x] + s[t] - v;
    if (i < n) { start[i] = st; cur[i] = st; }
    if (i == n - 1) start[n] = st + v;
}

__global__ __launch_bounds__(256) void csr_scatter(const int* __restrict__ src,
                                                   const int* __restrict__ dst,
                                                   int* cur, int* csr) {
    int e = blockIdx.x * blockDim.x + threadIdx.x;
    if (e >= E_EDGES) return;
    int d = dst[e];
    int p = atomicAdd(&cur[d], 1);
    csr[p] = src[e];
}

// ---- wave-per-node conv1 aggregation: float4 per lane (cols 4l..4l+3) ----
__global__ __launch_bounds__(64) void agg_fused(const float* __restrict__ h,
                                                const float* __restrict__ dinv,
                                                const int* __restrict__ rowptr,
                                                const int* __restrict__ csr,
                                                const float* __restrict__ b1,
                                                const float* __restrict__ w_score,
                                                u16* __restrict__ x1b,
                                                float* __restrict__ raw) {
    int i = blockIdx.x;
    int l = threadIdx.x;
    float di_ = dinv[i];
    const float4* H4 = (const float4*)h;
    long q = (long)i * 64 + l;
    float4 a = H4[q];
    float sc = di_ * di_;
    a.x *= sc; a.y *= sc; a.z *= sc; a.w *= sc;
    int p0 = rowptr[i], p1 = rowptr[i + 1];
    int t = p0;
    for (; t + 1 < p1; t += 2) {
        int s0 = csr[t], s1 = csr[t + 1];
        float c0 = dinv[s0] * di_;
        float c1 = dinv[s1] * di_;
        float4 h0 = H4[(long)s0 * 64 + l];
        float4 h1 = H4[(long)s1 * 64 + l];
        a.x += c0 * h0.x; a.y += c0 * h0.y; a.z += c0 * h0.z; a.w += c0 * h0.w;
        a.x += c1 * h1.x; a.y += c1 * h1.y; a.z += c1 * h1.z; a.w += c1 * h1.w;
    }
    if (t < p1) {
        int s0 = csr[t];
        float c0 = dinv[s0] * di_;
        float4 h0 = H4[(long)s0 * 64 + l];
        a.x += c0 * h0.x; a.y += c0 * h0.y; a.z += c0 * h0.z; a.w += c0 * h0.w;
    }
    float4 bb = ((const float4*)b1)[l];
    float v0 = fmaxf(a.x + bb.x, 0.f);
    float v1 = fmaxf(a.y + bb.y, 0.f);
    float v2 = fmaxf(a.z + bb.z, 0.f);
    float v3 = fmaxf(a.w + bb.w, 0.f);
    ushort4 o;
    o.x = f2bf(v0); o.y = f2bf(v1); o.z = f2bf(v2); o.w = f2bf(v3);
    ((ushort4*)x1b)[q] = o;
    float4 wv = ((const float4*)w_score)[l];
    float s2 = (v0 * wv.x + v2 * wv.z) + (v1 * wv.y + v3 * wv.w);
    #pragma unroll
    for (int off = 32; off > 0; off >>= 1)
        s2 += __shfl_xor(s2, off, 64);
    if (l == 0) raw[i] = s2;
}

// ------- multi-block radix select -------
__global__ __launch_bounds__(256) void radix_hist(const float* __restrict__ raw,
                                                  const unsigned* __restrict__ pPrefix,
                                                  int byte, int* hist) {
    __shared__ int lh[256];
    int t = threadIdx.x;
    lh[t] = 0;
    __syncthreads();
    int i = blockIdx.x * 256 + t;
    if (i < N_NODES) {
        unsigned key = fkey(raw[i]);
        unsigned known_mask = (byte == 3) ? 0u : (0xFFFFFFFFu << ((byte + 1) * 8));
        if ((key & known_mask) == *pPrefix)
            atomicAdd(&lh[(key >> (byte * 8)) & 255], 1);
    }
    __syncthreads();
    int hh = lh[t];
    if (hh) atomicAdd(&hist[t], hh);
}

__global__ __launch_bounds__(64) void radix_pick(const int* __restrict__ hist,
                                                 unsigned* pPrefix, int* pK, int byte) {
    if (threadIdx.x != 0) return;
    int kk = *pK;
    int cum = 0;
    int v = 255;
    for (; v > 0; --v) {
        int c = hist[v];
        if (cum + c >= kk) break;
        cum += c;
    }
    *pPrefix |= ((unsigned)v) << (byte * 8);
    *pK = kk - cum;
}

// ---------------- multi-block compaction: count -> scan -> assign ----------------
__global__ __launch_bounds__(256) void topk_count(const float* __restrict__ raw,
                                                  const unsigned* pT,
                                                  int* bGt, int* bEq) {
    __shared__ int sg[256], se[256];
    unsigned T = *pT;
    int t = threadIdx.x;
    int i = blockIdx.x * 256 + t;
    int gt = 0, eq = 0;
    if (i < N_NODES) {
        unsigned k = fkey(raw[i]);
        gt = k > T; eq = (k == T);
    }
    sg[t] = gt; se[t] = eq;
    __syncthreads();
    for (int off = 128; off > 0; off >>= 1) {
        if (t < off) { sg[t] += sg[t + off]; se[t] += se[t + off]; }
        __syncthreads();
    }
    if (t == 0) { bGt[blockIdx.x] = sg[0]; bEq[blockIdx.x] = se[0]; }
}

__global__ __launch_bounds__(256) void scan_blocks(const int* __restrict__ bGt,
                                                   const int* __restrict__ bEq,
                                                   int* gtStart, int* eqStart) {
    __shared__ int sg[256], se[256];
    int t = threadIdx.x;
    int vg = (t < NB2) ? bGt[t] : 0;
    int ve = (t < NB2) ? bEq[t] : 0;
    sg[t] = vg; se[t] = ve;
    __syncthreads();
    for (int off = 1; off < 256; off <<= 1) {
        int a = (t >= off) ? sg[t - off] : 0;
        int b = (t >= off) ? se[t - off] : 0;
        __syncthreads();
        sg[t] += a; se[t] += b;
        __syncthreads();
    }
    if (t < NB2) { gtStart[t] = sg[t] - vg; eqStart[t] = se[t] - ve; }
    if (t == 255) gtStart[NB2] = sg[255];   // totalGt
}

__global__ __launch_bounds__(256) void topk_assign(const float* __restrict__ raw,
                                                   const unsigned* pT, const int* pNeedEq,
                                                   const int* __restrict__ degS,
                                                   const int* __restrict__ gtStart,
                                                   const int* __restrict__ eqStart,
                                                   u64* keep_bits, int* cid,
                                                   unsigned long long* bestpack) {
    __shared__ int sg[256], se[256];
    unsigned T = *pT;
    int needEq = *pNeedEq;
    int totalGt = gtStart[NB2];
    int b = blockIdx.x, t = threadIdx.x;
    int i = b * 256 + t;
    int gt = 0, eq = 0;
    unsigned k = 0;
    if (i < N_NODES) {
        k = fkey(raw[i]);
        gt = k > T; eq = (k == T);
    }
    sg[t] = gt; se[t] = eq;
    __syncthreads();
    for (int off = 1; off < 256; off <<= 1) {
        int a = (t >= off) ? sg[t - off] : 0;
        int c = (t >= off) ? se[t - off] : 0;
        __syncthreads();
        sg[t] += a; se[t] += c;
        __syncthreads();
    }
    int eg = sg[t] - gt, ee = se[t] - eq;
    int kp = 0;
    unsigned long long p = 0ULL;
    if (i < N_NODES) {
        int c = -1;
        if (gt) { kp = 1; c = gtStart[b] + eg; }
        else if (eq) {
            int r = eqStart[b] + ee;
            if (r < needEq) { kp = 1; c = totalGt + r; }
        }
        cid[i] = c;
        if (kp) p = ((unsigned long long)(unsigned)degS[i] << 32) | k;
    }
    u64 ball = __ballot(kp);
    if ((t & 63) == 0) keep_bits[(b * 256 + t) >> 6] = ball;
    #pragma unroll
    for (int o = 32; o > 0; o >>= 1) {
        unsigned long long q = __shfl_xor((long long)p, o, 64);
        if (q > p) p = q;
    }
    if ((t & 63) == 0 && p) atomicMax(bestpack, p);
}

// ---- neighbor attachment + fused bg_node (same grid covers both index spaces) ----
__global__ __launch_bounds__(256) void neigh_bg(const int* __restrict__ src,
                                                const int* __restrict__ dst,
                                                const u64* __restrict__ keep_bits,
                                                const int* __restrict__ degS,
                                                const float* __restrict__ raw,
                                                const unsigned long long* __restrict__ bestpack,
                                                int* bgnode,
                                                unsigned long long* best_enc) {
    int e = blockIdx.x * blockDim.x + threadIdx.x;
    if (e < N_NODES && getbit(keep_bits, e)) {
        unsigned long long p = ((unsigned long long)(unsigned)degS[e] << 32) | fkey(raw[e]);
        if (p == *bestpack) atomicMin(bgnode, e);
    }
    if (e >= 2 * E_EDGES) return;
    int s, t;
    if (e < E_EDGES) { s = src[e]; t = dst[e]; }
    else { s = dst[e - E_EDGES]; t = src[e - E_EDGES]; }
    if (!getbit(keep_bits, s) && getbit(keep_bits, t)) {
        unsigned long long enc =
            (unsigned long long)((long long)degS[t] * N_NODES + (N_NODES - 1 - t)) + 1ULL;
        atomicMax(&best_enc[s], enc);
    }
}

// ---- resolve final cid AND histogram it (fuses old ccount2) ----
// cid[t] reads target only kept nodes (written by topk_assign) -> no intra-kernel race.
__global__ __launch_bounds__(256) void resolve_cid_count(const u64* __restrict__ keep_bits,
                                                         const unsigned long long* __restrict__ best_enc,
                                                         const int* __restrict__ bgnode,
                                                         int* cid, int* ccnt) {
    __shared__ int hist[K_CL];
    int tid = threadIdx.x;
    for (int t = tid; t < K_CL; t += 256) hist[t] = 0;
    __syncthreads();
    int i = blockIdx.x * 256 + tid;
    if (i < N_NODES) {
        int c;
        if (getbit(keep_bits, i)) {
            c = cid[i];
        } else {
            unsigned long long v = best_enc[i];
            if (v > 0ULL) {
                long long enc = (long long)(v - 1ULL);
                int t = (N_NODES - 1) - (int)(enc % N_NODES);
                c = cid[t];
            } else {
                c = cid[*bgnode];
            }
            cid[i] = c;
        }
        atomicAdd(&hist[c], 1);
    }
    __syncthreads();
    for (int t = tid; t < K_CL; t += 256) {
        int hh = hist[t];
        if (hh) atomicAdd(&ccnt[t], hh);
    }
}

// ---------------- LDS-aggregated counting-sort scatter ----------------
#define NPB 1024
__global__ __launch_bounds__(256) void cscatter2(const int* __restrict__ cid,
                                                 int* ccur, int* clist) {
    __shared__ int hist[K_CL];
    for (int t = threadIdx.x; t < K_CL; t += 256) hist[t] = 0;
    __syncthreads();
    int base = blockIdx.x * NPB;
    int myc[NPB / 256], myr[NPB / 256];
    #pragma unroll
    for (int u = 0; u < NPB / 256; ++u) {
        int idx = base + u * 256 + threadIdx.x;
        if (idx < N_NODES) { myc[u] = cid[idx]; myr[u] = atomicAdd(&hist[myc[u]], 1); }
        else myc[u] = -1;
    }
    __syncthreads();
    for (int t = threadIdx.x; t < K_CL; t += 256) {
        int hh = hist[t];
        if (hh) hist[t] = atomicAdd(&ccur[t], hh);
    }
    __syncthreads();
    #pragma unroll
    for (int u = 0; u < NPB / 256; ++u)
        if (myc[u] >= 0) clist[hist[myc[u]] + myr[u]] = base + u * 256 + threadIdx.x;
}

// ---------------- chunked segmented pooling (bf16 inputs) ----------------
__global__ __launch_bounds__(256) void pool_chunk(const u16* __restrict__ x1b,
                                                  const float* __restrict__ raw,
                                                  const int* __restrict__ clist,
                                                  const int* __restrict__ cid,
                                                  float* xp) {
    __shared__ int s_node[PCH];
    __shared__ int s_c[PCH];
    __shared__ float s_g[PCH];
    int j = threadIdx.x;
    int base = blockIdx.x * PCH;
    int m = N_NODES - base; if (m > PCH) m = PCH;
    for (int t = j; t < m; t += 256) {
        int nd = clist[base + t];
        s_node[t] = nd;
        s_c[t] = cid[nd];
        s_g[t] = tanhf(raw[nd]);
    }
    __syncthreads();
    float acc = 0.f;
    int cprev = s_c[0];
    for (int t = 0; t < m; t += 4) {
        int mm = m - t; if (mm > 4) mm = 4;
        float v[4];
        #pragma unroll
        for (int u = 0; u < 4; ++u)
            if (u < mm) v[u] = bf2f(x1b[(long)s_node[t + u] * H_F + j]);
        #pragma unroll
        for (int u = 0; u < 4; ++u) {
            if (u < mm) {
                int c = s_c[t + u];
                if (c != cprev) {
                    atomicAdd(&xp[(long)cprev * H_F + j], acc);
                    acc = 0.f;
                    cprev = c;
                }
                acc += s_g[t + u] * v[u];
            }
        }
    }
    atomicAdd(&xp[(long)cprev * H_F + j], acc);
}

// ---------------- bit-packed pooled adjacency ----------------
__global__ __launch_bounds__(256) void build_Abits(const int* __restrict__ src,
                                                   const int* __restrict__ dst,
                                                   const int* __restrict__ cid,
                                                   unsigned* Abits) {
    int e = blockIdx.x * blockDim.x + threadIdx.x;
    if (e >= E_EDGES) return;
    int cu = cid[src[e]], cv = cid[dst[e]];
    if (cu != cv) atomicOr(&Abits[(long)cv * KW + (cu >> 5)], 1u << (cu & 31));
}

// di, nnz, and heavy-row compaction
__global__ __launch_bounds__(256) void pop_di2(const unsigned* __restrict__ Abits, float* di,
                                               int* nnzA, int* heavy, int* heavycnt) {
    int i = blockIdx.x * blockDim.x + threadIdx.x;
    if (i >= K_CL) return;
    int c = 0;
    for (int w = 0; w < KW; ++w) c += __popc(Abits[(long)i * KW + w]);
    di[i] = rsqrtf((float)c + 1.0f);
    nnzA[i] = c;
    if (c > THRESH) {
        int p = atomicAdd(heavycnt, 1);
        if (p < MAXH) heavy[p] = i;
    }
}

// light rows compute fully; heavy rows get their base term written here
// (spmm_heavy then atomicAdds dv*acc on top, in stream order).
__global__ __launch_bounds__(256) void spmm_light(const unsigned* __restrict__ Abits,
                                                  const float* __restrict__ xpW2,
                                                  const float* __restrict__ di,
                                                  const float* __restrict__ b2,
                                                  const int* __restrict__ nnzA,
                                                  float* xp2) {
    __shared__ unsigned s_row[KW];
    __shared__ float s_part[3][256];
    int cv = blockIdx.x;
    int tid = threadIdx.x;
    if (nnzA[cv] > THRESH) {
        float dv = di[cv];
        xp2[(long)cv * H_F + tid] =
            dv * dv * xpW2[(long)cv * H_F + tid] + b2[tid];
        return;
    }
    int w = tid >> 6, l = tid & 63;
    if (tid < KW) s_row[tid] = Abits[(long)cv * KW + tid];
    __syncthreads();
    float4 a0 = {0.f, 0.f, 0.f, 0.f}, a1 = {0.f, 0.f, 0.f, 0.f};
    const float4* Y4 = (const float4*)xpW2;
    for (int wi = w * 32; wi < w * 32 + 32; wi += 2) {
        unsigned w0 = s_row[wi], w1 = s_row[wi + 1];
        while (w0 | w1) {
            if (w0) {
                int b = __ffs(w0) - 1; w0 &= w0 - 1;
                int cu = wi * 32 + b;
                float d = di[cu];
                float4 y = Y4[(long)cu * 64 + l];
                a0.x += d * y.x; a0.y += d * y.y; a0.z += d * y.z; a0.w += d * y.w;
            }
            if (w1) {
                int b = __ffs(w1) - 1; w1 &= w1 - 1;
                int cu = (wi + 1) * 32 + b;
                float d = di[cu];
                float4 y = Y4[(long)cu * 64 + l];
                a1.x += d * y.x; a1.y += d * y.y; a1.z += d * y.z; a1.w += d * y.w;
            }
        }
    }
    float4 acc = {a0.x + a1.x, a0.y + a1.y, a0.z + a1.z, a0.w + a1.w};
    if (w > 0) *(float4*)&s_part[w - 1][l * 4] = acc;
    __syncthreads();
    if (w == 0) {
        #pragma unroll
        for (int ww = 0; ww < 3; ++ww) {
            float4 p = *(float4*)&s_part[ww][l * 4];
            acc.x += p.x; acc.y += p.y; acc.z += p.z; acc.w += p.w;
        }
        float dv = di[cv];
        float4 ys = Y4[(long)cv * 64 + l];
        float4 o;
        o.x = dv * (acc.x + dv * ys.x) + b2[l * 4 + 0];
        o.y = dv * (acc.y + dv * ys.y) + b2[l * 4 + 1];
        o.z = dv * (acc.z + dv * ys.z) + b2[l * 4 + 2];
        o.w = dv * (acc.w + dv * ys.w) + b2[l * 4 + 3];
        *(float4*)&xp2[(long)cv * H_F + l * 4] = o;
    }
}

// heavy rows: grid (MAXH, NSPL); atomicAdd dv*partial straight into xp2 (base
// already written by spmm_light, which ran earlier in the stream).
__global__ __launch_bounds__(256) void spmm_heavy(const unsigned* __restrict__ Abits,
                                                  const float* __restrict__ xpW2,
                                                  const float* __restrict__ di,
                                                  const int* __restrict__ heavy,
                                                  const int* __restrict__ heavycnt,
                                                  float* xp2) {
    __shared__ float s_part[3][256];
    int hi = blockIdx.x;
    int cnt = *heavycnt; if (cnt > MAXH) cnt = MAXH;
    if (hi >= cnt) return;
    int cv = heavy[hi];
    int sp = blockIdx.y;
    int tid = threadIdx.x;
    int w = tid >> 6, l = tid & 63;
    int wi = sp * (KW / NSPL) + w;
    unsigned word = Abits[(long)cv * KW + wi];
    float4 acc = {0.f, 0.f, 0.f, 0.f};
    const float4* Y4 = (const float4*)xpW2;
    while (word) {
        int b = __ffs(word) - 1; word &= word - 1;
        int cu = wi * 32 + b;
        float d = di[cu];
        float4 y = Y4[(long)cu * 64 + l];
        acc.x += d * y.x; acc.y += d * y.y; acc.z += d * y.z; acc.w += d * y.w;
    }
    if (w > 0) *(float4*)&s_part[w - 1][l * 4] = acc;
    __syncthreads();
    if (w == 0) {
        #pragma unroll
        for (int ww = 0; ww < 3; ++ww) {
            float4 p = *(float4*)&s_part[ww][l * 4];
            acc.x += p.x; acc.y += p.y; acc.z += p.z; acc.w += p.w;
        }
        float dv = di[cv];
        float* zp = &xp2[(long)cv * H_F + l * 4];
        atomicAdd(zp + 0, dv * acc.x);
        atomicAdd(zp + 1, dv * acc.y);
        atomicAdd(zp + 2, dv * acc.z);
        atomicAdd(zp + 3, dv * acc.w);
    }
}

// ---------------- host launch ----------------
static inline size_t align256(size_t x) { return (x + 255) & ~(size_t)255; }

extern "C" void kernel_launch(void* const* d_in, const int* in_sizes, int n_in,
                              void* d_out, int out_size, void* d_ws, size_t ws_size,
                              hipStream_t stream) {
    const float* x      = (const float*)d_in[0];
    const int*   eidx   = (const int*)d_in[1];
    const float* W1     = (const float*)d_in[2];
    const float* b1     = (const float*)d_in[3];
    const float* W2     = (const float*)d_in[4];
    const float* b2     = (const float*)d_in[5];
    const float* wscore = (const float*)d_in[6];
    const float* Wskip  = (const float*)d_in[7];
    const float* bskip  = (const float*)d_in[8];
    float* out = (float*)d_out;

    const int* src = eidx;
    const int* dst = eidx + E_EDGES;

    char* ws = (char*)d_ws;
    size_t off = 0;
    auto alloc = [&](size_t bytes) { char* p = ws + off; off += align256(bytes); return p; };

    float* h     = (float*)alloc((size_t)N_NODES * H_F * 4);
    u16*   x1b   = (u16*)alloc((size_t)N_NODES * H_F * 2);
    float* raw   = (float*)alloc((size_t)N_NODES * 4);
    float* dinv  = (float*)alloc((size_t)N_NODES * 4);
    int*   cntD  = (int*)alloc((size_t)N_NODES * 4);
    int*   degS  = (int*)alloc((size_t)N_NODES * 4);
    u64*   keep_bits = (u64*)alloc((size_t)KBW * 8);
    int*   cid   = (int*)alloc((size_t)N_NODES * 4);
    unsigned long long* best_enc = (unsigned long long*)alloc((size_t)N_NODES * 8);
    int*   rowptr= (int*)alloc((size_t)(N_NODES + 1) * 4);
    int*   cur   = (int*)alloc((size_t)N_NODES * 4);
    int*   csr   = (int*)alloc((size_t)E_EDGES * 4);
    int*   ccnt  = (int*)alloc((size_t)K_CL * 4);
    int*   cstart= (int*)alloc((size_t)(K_CL + 1) * 4);
    int*   ccur  = (int*)alloc((size_t)K_CL * 4);
    int*   clist = (int*)alloc((size_t)N_NODES * 4);
    int*   bGt   = (int*)alloc((size_t)NB2 * 4);
    int*   bEq   = (int*)alloc((size_t)NB2 * 4);
    int*   gtStart = (int*)alloc((size_t)(NB2 + 1) * 4);
    int*   eqStart = (int*)alloc((size_t)NB2 * 4);
    int*   bsum  = (int*)alloc((size_t)256 * 4);
    int*   bstart= (int*)alloc((size_t)256 * 4);
    int*   hist4 = (int*)alloc((size_t)4 * 256 * 4);
    char*  small = alloc(64);
    unsigned* selT = (unsigned*)(small + 0);
    int* needEq    = (int*)(small + 4);
    int* bgnode    = (int*)(small + 8);
    int* heavycnt  = (int*)(small + 12);
    unsigned long long* bestpack = (unsigned long long*)(small + 16);
    // xp, Abits adjacent -> single memset covers both
    float* xp    = (float*)alloc((size_t)K_CL * H_F * 4);
    unsigned* Abits = (unsigned*)alloc((size_t)K_CL * KW * 4);
    float* di    = (float*)alloc((size_t)K_CL * 4);
    int*   nnzA  = (int*)alloc((size_t)K_CL * 4);
    int*   heavy = (int*)alloc((size_t)MAXH * 4);
    float* xpW2  = (float*)alloc((size_t)K_CL * H_F * 4);
    float* xp2   = (float*)alloc((size_t)K_CL * H_F * 4);
    u16*  BpS   = (u16*)alloc((size_t)H_F * OUT_F * 2);
    u16*  Bp2   = (u16*)alloc((size_t)H_F * H_F * 2);
    (void)ws_size; (void)n_in; (void)in_sizes; (void)out_size;

    int eb = (E_EDGES + 255) / 256;

    // degrees + small-state init (also zeroes hist4 and ccnt)
    init_nodes<<<NB2, 256, 0, stream>>>(cntD, degS, best_enc, bgnode, heavycnt, bestpack,
                                        selT, needEq, hist4, ccnt);
    deg_edges<<<eb, 256, 0, stream>>>(src, dst, cntD, degS);

    // weight packing (both in one launch)
    pack_W2<<<512, 256, 0, stream>>>(Wskip, BpS, W2, Bp2);

    // h = x @ W1 (fp32 — score path must stay exact)
    {
        dim3 grid(H_F / SBN, (N_NODES + SBM - 1) / SBM);
        gemm_f32s<<<grid, 256, 0, stream>>>(x, W1, h, N_NODES, H_F, IN_F);
    }

    // CSR by dst: coalesced two-level scan (also emits dinv) + scatter, then aggregation
    scan_l1<<<NB2, 256, 0, stream>>>(cntD, bsum, N_NODES, dinv);
    scan_l2<<<1, 256, 0, stream>>>(bsum, bstart, NB2);
    scan_l3<<<NB2, 256, 0, stream>>>(cntD, bstart, rowptr, cur, N_NODES);
    csr_scatter<<<eb, 256, 0, stream>>>(src, dst, cur, csr);
    agg_fused<<<N_NODES, 64, 0, stream>>>(h, dinv, rowptr, csr, b1, wscore, x1b, raw);

    // top-K threshold: multi-block radix (4 passes)
    for (int b = 3; b >= 0; --b) {
        radix_hist<<<NB2, 256, 0, stream>>>(raw, selT, b, hist4 + b * 256);
        radix_pick<<<1, 64, 0, stream>>>(hist4 + b * 256, selT, needEq, b);
    }
    topk_count<<<NB2, 256, 0, stream>>>(raw, selT, bGt, bEq);
    scan_blocks<<<1, 256, 0, stream>>>(bGt, bEq, gtStart, eqStart);
    topk_assign<<<NB2, 256, 0, stream>>>(raw, selT, needEq, degS, gtStart, eqStart,
                                         keep_bits, cid, bestpack);

    // neighbor attachment + fused bg_node
    neigh_bg<<<(2 * E_EDGES + 255) / 256, 256, 0, stream>>>(src, dst, keep_bits, degS,
                                                            raw, bestpack, bgnode, best_enc);
    // resolve final cid + cluster counts in one pass
    resolve_cid_count<<<NB2, 256, 0, stream>>>(keep_bits, best_enc, bgnode, cid, ccnt);

    // single memset for xp (4MB) + Abits (2MB), adjacent in ws
    hipMemsetAsync(xp, 0, (size_t)K_CL * H_F * 4 + (size_t)K_CL * KW * 4, stream);

    // counting-sort scatter + chunked segmented pooling
    {
        int cb = (N_NODES + NPB - 1) / NPB;
        scan_l1<<<K_CL / 256, 256, 0, stream>>>(ccnt, bsum, K_CL, nullptr);
        scan_l2<<<1, 256, 0, stream>>>(bsum, bstart, K_CL / 256);
        scan_l3<<<K_CL / 256, 256, 0, stream>>>(ccnt, bstart, cstart, ccur, K_CL);
        cscatter2<<<cb, 256, 0, stream>>>(cid, ccur, clist);
    }
    pool_chunk<<<(N_NODES + PCH - 1) / PCH, 256, 0, stream>>>(x1b, raw, clist, cid, xp);

    // xpW2 = (xp/cnt) @ W2  (bf16 MFMA, in-kernel fp32->bf16 conversion)
    gemm_mfma<<<K_CL / 64, 256, 0, stream>>>(nullptr, xp, ccnt, Bp2, xpW2, K_CL,
                                             nullptr, nullptr, nullptr);

    // bit-packed pooled adjacency + split light/heavy normalized SpMM
    build_Abits<<<eb, 256, 0, stream>>>(src, dst, cid, Abits);
    pop_di2<<<(K_CL + 255) / 256, 256, 0, stream>>>(Abits, di, nnzA, heavy, heavycnt);
    spmm_light<<<K_CL, 256, 0, stream>>>(Abits, xpW2, di, b2, nnzA, xp2);
    {
        dim3 hgrid(MAXH, NSPL);
        spmm_heavy<<<hgrid, 256, 0, stream>>>(Abits, xpW2, di, heavy, heavycnt, xp2);
    }

    // out = x1@Wskip + xp2[cid] + b_skip  (bf16 MFMA, fused epilogue)
    gemm_mfma<<<(N_NODES + 63) / 64, 256, 0, stream>>>(x1b, nullptr, nullptr, BpS, out,
                                                       N_NODES, cid, xp2, bskip);
}